// Round 2
// baseline (1303.417 us; speedup 1.0000x reference)
//
#include <hip/hip_runtime.h>

// ---------------- CSR build (dst-indexed), reused by both GAT layers ----------
__global__ __launch_bounds__(256) void hist_kernel(const int* __restrict__ ei, int E, int N,
                                                   int* __restrict__ counts) {
    int i = blockIdx.x * 256 + threadIdx.x;
    if (i < E) atomicAdd(&counts[ei[E + i]], 1);          // dst row of edge_index
    else if (i < E + N) atomicAdd(&counts[i - E], 1);     // self-loop
}

__global__ __launch_bounds__(1024) void scan_kernel(const int* __restrict__ counts, int N,
                                                    int* __restrict__ offs, int* __restrict__ cursor) {
    __shared__ int tot[1024];
    int t = threadIdx.x;
    int chunk = (N + 1023) / 1024;
    int b = t * chunk, e = min(b + chunk, N);
    int s = 0;
    for (int i = b; i < e; i++) s += counts[i];
    tot[t] = s;
    __syncthreads();
    for (int off = 1; off < 1024; off <<= 1) {
        int v = (t >= off) ? tot[t - off] : 0;
        __syncthreads();
        tot[t] += v;
        __syncthreads();
    }
    int run = (t > 0) ? tot[t - 1] : 0;
    for (int i = b; i < e; i++) {
        offs[i] = run; cursor[i] = run; run += counts[i];
    }
    if (t == 1023) offs[N] = tot[1023];
}

__global__ __launch_bounds__(256) void scatter_kernel(const int* __restrict__ ei, int E, int N,
                                                      int* __restrict__ cursor, int* __restrict__ csr) {
    int i = blockIdx.x * 256 + threadIdx.x;
    if (i < E) {
        int d = ei[E + i];
        int p = atomicAdd(&cursor[d], 1);
        csr[p] = ei[i];
    } else if (i < E + N) {
        int n = i - E;
        int p = atomicAdd(&cursor[n], 1);
        csr[p] = n;
    }
}

// ---------------- GEMM: [N,K] f32 @ [K,256] f32 -> [N,256] f32 ---------------
// wave = 1 row (A-row loads are wave-uniform broadcast; W loads fully coalesced)
template <int K>
__global__ __launch_bounds__(256) void gemm_rowcol(const float* __restrict__ A,
                                                   const float* __restrict__ W,
                                                   float* __restrict__ O, int Nrows) {
    int gid = blockIdx.x * 256 + threadIdx.x;
    int row = gid >> 6;
    int cg = gid & 63;  // this lane owns cols 4cg..4cg+3
    if (row >= Nrows) return;
    const float* arow = A + (size_t)row * K;
    float4 acc = make_float4(0.f, 0.f, 0.f, 0.f);
#pragma unroll 4
    for (int k = 0; k < K; k += 4) {
        float4 xv = *(const float4*)(arow + k);
        const float* wp = W + (size_t)k * 256 + cg * 4;
        float4 w0 = *(const float4*)(wp);
        float4 w1 = *(const float4*)(wp + 256);
        float4 w2 = *(const float4*)(wp + 512);
        float4 w3 = *(const float4*)(wp + 768);
        acc.x += xv.x * w0.x + xv.y * w1.x + xv.z * w2.x + xv.w * w3.x;
        acc.y += xv.x * w0.y + xv.y * w1.y + xv.z * w2.y + xv.w * w3.y;
        acc.z += xv.x * w0.z + xv.y * w1.z + xv.z * w2.z + xv.w * w3.z;
        acc.w += xv.x * w0.w + xv.y * w1.w + xv.z * w2.w + xv.w * w3.w;
    }
    *(float4*)(O + (size_t)row * 256 + cg * 4) = acc;
}

// ---------------- attention logits al_s/al_d = (h * a).sum(-1) per head -------
template <int H>
__global__ __launch_bounds__(256) void al_kernel(const float* __restrict__ h,
                                                 const float* __restrict__ as_, const float* __restrict__ ad_,
                                                 float* __restrict__ als, float* __restrict__ ald, int N) {
    const int G = 64 / H;  // lanes per head
    int w = (blockIdx.x * 256 + threadIdx.x) >> 6;
    int lane = threadIdx.x & 63;
    if (w >= N) return;
    float4 hv = ((const float4*)(h + (size_t)w * 256))[lane];
    float4 sv = ((const float4*)as_)[lane];
    float4 dv = ((const float4*)ad_)[lane];
    float ps = hv.x * sv.x + hv.y * sv.y + hv.z * sv.z + hv.w * sv.w;
    float pd = hv.x * dv.x + hv.y * dv.y + hv.z * dv.z + hv.w * dv.w;
#pragma unroll
    for (int o = G / 2; o; o >>= 1) {
        ps += __shfl_xor(ps, o);
        pd += __shfl_xor(pd, o);
    }
    if ((lane & (G - 1)) == 0) {
        als[w * H + lane / G] = ps;
        ald[w * H + lane / G] = pd;
    }
}

// ---------------- GAT aggregation: one wave per dst node, no atomics ----------
template <int H>
__global__ __launch_bounds__(256) void gat_agg_kernel(const int* __restrict__ offs,
                                                      const int* __restrict__ csr,
                                                      const float* __restrict__ h,
                                                      const float* __restrict__ als,
                                                      const float* __restrict__ ald,
                                                      float* __restrict__ out, int N) {
    int w = (blockIdx.x * 256 + threadIdx.x) >> 6;
    int lane = threadIdx.x & 63;
    if (w >= N) return;
    int s0 = offs[w], s1 = offs[w + 1];
    float adl[H], m[H], den[H];
#pragma unroll
    for (int hh = 0; hh < H; hh++) { adl[hh] = ald[w * H + hh]; m[hh] = -1e30f; den[hh] = 0.f; }
    // pass 1: segment max (lane-parallel over edges)
    for (int i = s0 + lane; i < s1; i += 64) {
        int s = csr[i];
#pragma unroll
        for (int hh = 0; hh < H; hh++) {
            float e = als[s * H + hh] + adl[hh];
            e = e > 0.f ? e : 0.2f * e;
            m[hh] = fmaxf(m[hh], e);
        }
    }
#pragma unroll
    for (int hh = 0; hh < H; hh++)
        for (int o = 32; o; o >>= 1) m[hh] = fmaxf(m[hh], __shfl_xor(m[hh], o));
    // pass 2: softmax denominator
    for (int i = s0 + lane; i < s1; i += 64) {
        int s = csr[i];
#pragma unroll
        for (int hh = 0; hh < H; hh++) {
            float e = als[s * H + hh] + adl[hh];
            e = e > 0.f ? e : 0.2f * e;
            den[hh] += __expf(e - m[hh]);
        }
    }
#pragma unroll
    for (int hh = 0; hh < H; hh++)
        for (int o = 32; o; o >>= 1) den[hh] += __shfl_xor(den[hh], o);
    // pass 3: weighted accumulate, lanes cover the 256 cols (4 each)
    int myh = (H == 4) ? (lane >> 4) : 0;
    float mm = m[myh], rden = 1.f / (den[myh] + 1e-16f), aa = adl[myh];
    float4 acc = make_float4(0.f, 0.f, 0.f, 0.f);
    for (int i = s0; i < s1; i++) {
        int s = csr[i];  // wave-uniform
        float e = als[s * H + myh] + aa;
        e = e > 0.f ? e : 0.2f * e;
        float al = __expf(e - mm) * rden;
        float4 hv = ((const float4*)(h + (size_t)s * 256))[lane];
        acc.x = fmaf(al, hv.x, acc.x);
        acc.y = fmaf(al, hv.y, acc.y);
        acc.z = fmaf(al, hv.z, acc.z);
        acc.w = fmaf(al, hv.w, acc.w);
    }
    ((float4*)(out + (size_t)w * 256))[lane] = acc;
}

// ---------------- BatchNorm (training-mode batch stats) -----------------------
__global__ __launch_bounds__(256) void bn_stats(const float* __restrict__ agg, int N,
                                                float* __restrict__ sum, float* __restrict__ sq) {
    int t = threadIdx.x;
    int rows = (N + gridDim.x - 1) / gridDim.x;
    int r0 = blockIdx.x * rows, r1 = min(r0 + rows, N);
    float s = 0.f, q = 0.f;
    for (int r = r0; r < r1; r++) {
        float v = agg[(size_t)r * 256 + t];
        s += v;
        q = fmaf(v, v, q);
    }
    atomicAdd(&sum[t], s);
    atomicAdd(&sq[t], q);
}

__global__ __launch_bounds__(256) void bn_final(const float* __restrict__ sum, const float* __restrict__ sq,
                                                const float* __restrict__ g, const float* __restrict__ be,
                                                int N, float* __restrict__ scale, float* __restrict__ shift) {
    int t = threadIdx.x;
    float inv = 1.f / (float)N;
    float m = sum[t] * inv;
    float v = fmaxf(sq[t] * inv - m * m, 0.f);
    float sc = rsqrtf(v + 1e-5f) * g[t];
    scale[t] = sc;
    shift[t] = be[t] - m * sc;
}

__global__ __launch_bounds__(256) void bn_apply_relu(const float* __restrict__ agg,
                                                     const float* __restrict__ scale,
                                                     const float* __restrict__ shift,
                                                     float* __restrict__ out, int N) {
    int i = blockIdx.x * 256 + threadIdx.x;  // one float4 (4 cols) per thread
    if (i >= N * 64) return;
    float4 v = ((const float4*)agg)[i];
    int c4 = i & 63;
    float4 sc = ((const float4*)scale)[c4];
    float4 sh = ((const float4*)shift)[c4];
    float4 o;
    o.x = fmaxf(fmaf(v.x, sc.x, sh.x), 0.f);
    o.y = fmaxf(fmaf(v.y, sc.y, sh.y), 0.f);
    o.z = fmaxf(fmaf(v.z, sc.z, sh.z), 0.f);
    o.w = fmaxf(fmaf(v.w, sc.w, sh.w), 0.f);
    ((float4*)out)[i] = o;
}

// ---------------- global mean pool ---------------------------------------------
__global__ __launch_bounds__(256) void pool_kernel(const float* __restrict__ xn, const int* __restrict__ batch,
                                                   int N, float* __restrict__ pools, int* __restrict__ cnt) {
    __shared__ float ps[2048];
    __shared__ int pc[8];
    int t = threadIdx.x;
    for (int i = t; i < 2048; i += 256) ps[i] = 0.f;
    if (t < 8) pc[t] = 0;
    __syncthreads();
    int rows = (N + gridDim.x - 1) / gridDim.x;
    int r0 = blockIdx.x * rows, r1 = min(r0 + rows, N);
    for (int r = r0; r < r1; r++) {
        int b = batch[r];  // uniform across block
        ps[b * 256 + t] += xn[(size_t)r * 256 + t];
        if (t == 0) pc[b]++;
    }
    __syncthreads();
    for (int i = t; i < 2048; i += 256) atomicAdd(&pools[i], ps[i]);
    if (t < 8) atomicAdd(&cnt[t], pc[t]);
}

// shared = relu(global_feat @ W_sh + b_sh); one block per graph
__global__ __launch_bounds__(256) void shared_kernel(const float* __restrict__ pools, const int* __restrict__ cnt,
                                                     const float* __restrict__ Wsh, const float* __restrict__ bsh,
                                                     float* __restrict__ shg) {
    __shared__ float gf[256];
    int b = blockIdx.x, t = threadIdx.x;
    gf[t] = pools[b * 256 + t] / fmaxf((float)cnt[b], 1.f);
    __syncthreads();
    float acc = bsh[t];
    for (int k = 0; k < 256; k++) acc = fmaf(gf[k], Wsh[k * 256 + t], acc);
    shg[b * 256 + t] = fmaxf(acc, 0.f);
}

// tiny heads: gdot (shared . W_node[256:512]), value, type_logits
__global__ __launch_bounds__(64) void head2_kernel(const float* __restrict__ shg,
                                                   const float* __restrict__ Wnode,
                                                   const float* __restrict__ Wtype, const float* __restrict__ btype,
                                                   const float* __restrict__ Wcrit, const float* __restrict__ bcrit,
                                                   const float* __restrict__ xn, const int* __restrict__ tgt,
                                                   float* __restrict__ gdot, float* __restrict__ out_tail) {
    int t = threadIdx.x;
    if (t >= 32 && t < 40) {
        int b = t - 32;
        float g = 0.f, v = 0.f;
        for (int k = 0; k < 256; k++) {
            float s = shg[b * 256 + k];
            g = fmaf(s, Wnode[256 + k], g);
            v = fmaf(s, Wcrit[k], v);
        }
        gdot[b] = g;
        out_tail[32 + b] = v + bcrit[0];
    } else if (t < 32) {
        int b = t >> 2, a = t & 3;
        float acc = btype[a];
        int tn = tgt[b];
        for (int k = 0; k < 256; k++) acc = fmaf(shg[b * 256 + k], Wtype[k * 4 + a], acc);
        for (int k = 0; k < 256; k++) acc = fmaf(xn[(size_t)tn * 256 + k], Wtype[(256 + k) * 4 + a], acc);
        out_tail[t] = acc;
    }
}

// node_scores: one wave per node
__global__ __launch_bounds__(256) void node_scores_kernel(const float* __restrict__ xn,
                                                          const float* __restrict__ Wnode, const float* __restrict__ bnode,
                                                          const int* __restrict__ batch, const float* __restrict__ gdot,
                                                          float* __restrict__ out, int N) {
    int w = (blockIdx.x * 256 + threadIdx.x) >> 6;
    int lane = threadIdx.x & 63;
    if (w >= N) return;
    float4 xv = ((const float4*)(xn + (size_t)w * 256))[lane];
    float4 wv = ((const float4*)Wnode)[lane];
    float p = xv.x * wv.x + xv.y * wv.y + xv.z * wv.z + xv.w * wv.w;
    for (int o = 32; o; o >>= 1) p += __shfl_xor(p, o);
    if (lane == 0) out[w] = p + gdot[batch[w]] + bnode[0];
}

extern "C" void kernel_launch(void* const* d_in, const int* in_sizes, int n_in,
                              void* d_out, int out_size, void* d_ws, size_t ws_size,
                              hipStream_t stream) {
    const float* x = (const float*)d_in[0];
    const int* ei = (const int*)d_in[1];
    const int* batch = (const int*)d_in[2];
    const int* tgt = (const int*)d_in[3];
    const float* W1 = (const float*)d_in[4];
    const float* a1s = (const float*)d_in[5];
    const float* a1d = (const float*)d_in[6];
    // b1 (d_in[7]) / b2 (d_in[11]): constant column shifts cancel exactly in BatchNorm
    const float* W2 = (const float*)d_in[8];
    const float* a2s = (const float*)d_in[9];
    const float* a2d = (const float*)d_in[10];
    const float* g1 = (const float*)d_in[12];
    const float* be1 = (const float*)d_in[13];
    const float* g2 = (const float*)d_in[14];
    const float* be2 = (const float*)d_in[15];
    const float* Wsh = (const float*)d_in[16];
    const float* bsh = (const float*)d_in[17];
    const float* Wnode = (const float*)d_in[18];
    const float* bnode = (const float*)d_in[19];
    const float* Wtype = (const float*)d_in[20];
    const float* btype = (const float*)d_in[21];
    const float* Wcrit = (const float*)d_in[22];
    const float* bcrit = (const float*)d_in[23];

    const int N = in_sizes[2];
    const int E = in_sizes[1] / 2;
    const int Et = E + N;

    // ---- workspace carve ----
    char* w = (char*)d_ws;
    size_t off = 0;
    auto carve = [&](size_t bytes) -> char* {
        char* p = w + off;
        off = (off + bytes + 255) & ~(size_t)255;
        return p;
    };
    float* agg = (float*)carve((size_t)N * 256 * 4);   // f32 GAT output (per layer, reused)
    float* bufA = (float*)carve((size_t)N * 256 * 4);  // h1 -> hin2
    float* bufB = (float*)carve((size_t)N * 256 * 4);  // h2 -> x_nodes
    float* al1s = (float*)carve((size_t)N * 4 * 4);
    float* al1d = (float*)carve((size_t)N * 4 * 4);
    float* al2s = (float*)carve((size_t)N * 4);
    float* al2d = (float*)carve((size_t)N * 4);
    int* offs = (int*)carve((size_t)(N + 1) * 4);
    int* cursor = (int*)carve((size_t)N * 4);
    int* csr = (int*)carve((size_t)Et * 4);
    float* scale = (float*)carve(1024);
    float* shift = (float*)carve(1024);
    float* gdot = (float*)carve(64);
    float* shg = (float*)carve(8 * 256 * 4);
    char* zero0 = w + off;
    int* counts = (int*)carve((size_t)N * 4);
    float* bn1s = (float*)carve(1024);
    float* bn1q = (float*)carve(1024);
    float* bn2s = (float*)carve(1024);
    float* bn2q = (float*)carve(1024);
    float* pools = (float*)carve(8 * 256 * 4);
    int* cnt = (int*)carve(64);
    size_t zbytes = (size_t)((w + off) - zero0);
    hipMemsetAsync(zero0, 0, zbytes, stream);

    int wavesPerGrid = (N + 3) / 4;  // 4 waves (nodes) per 256-thread block

    // ---- CSR build (shared by both layers) ----
    hist_kernel<<<(Et + 255) / 256, 256, 0, stream>>>(ei, E, N, counts);
    scan_kernel<<<1, 1024, 0, stream>>>(counts, N, offs, cursor);
    scatter_kernel<<<(Et + 255) / 256, 256, 0, stream>>>(ei, E, N, cursor, csr);

    // ---- layer 1: GAT(4 heads) + BN + ReLU ----
    gemm_rowcol<64><<<(N * 64 + 255) / 256, 256, 0, stream>>>(x, W1, bufA, N);
    al_kernel<4><<<wavesPerGrid, 256, 0, stream>>>(bufA, a1s, a1d, al1s, al1d, N);
    gat_agg_kernel<4><<<wavesPerGrid, 256, 0, stream>>>(offs, csr, bufA, al1s, al1d, agg, N);
    bn_stats<<<256, 256, 0, stream>>>(agg, N, bn1s, bn1q);
    bn_final<<<1, 256, 0, stream>>>(bn1s, bn1q, g1, be1, N, scale, shift);
    bn_apply_relu<<<(N * 64 + 255) / 256, 256, 0, stream>>>(agg, scale, shift, bufA, N);

    // ---- layer 2: GAT(1 head) + BN + ReLU ----
    gemm_rowcol<256><<<(N * 64 + 255) / 256, 256, 0, stream>>>(bufA, W2, bufB, N);
    al_kernel<1><<<wavesPerGrid, 256, 0, stream>>>(bufB, a2s, a2d, al2s, al2d, N);
    gat_agg_kernel<1><<<wavesPerGrid, 256, 0, stream>>>(offs, csr, bufB, al2s, al2d, agg, N);
    bn_stats<<<256, 256, 0, stream>>>(agg, N, bn2s, bn2q);
    bn_final<<<1, 256, 0, stream>>>(bn2s, bn2q, g2, be2, N, scale, shift);
    bn_apply_relu<<<(N * 64 + 255) / 256, 256, 0, stream>>>(agg, scale, shift, bufB, N);

    // ---- pooling + heads ----
    pool_kernel<<<128, 256, 0, stream>>>(bufB, batch, N, pools, cnt);
    shared_kernel<<<8, 256, 0, stream>>>(pools, cnt, Wsh, bsh, shg);
    head2_kernel<<<1, 64, 0, stream>>>(shg, Wnode, Wtype, btype, Wcrit, bcrit, bufB, tgt,
                                       gdot, (float*)d_out + N);
    node_scores_kernel<<<wavesPerGrid, 256, 0, stream>>>(bufB, Wnode, bnode, batch, gdot,
                                                         (float*)d_out, N);
}

// Round 4
// 922.287 us; speedup vs baseline: 1.4132x; 1.4132x over previous
//
#include <hip/hip_runtime.h>

// ---------------- CSR build (dst-indexed), reused by both GAT layers ----------
__global__ __launch_bounds__(256) void hist_kernel(const int* __restrict__ ei, int E, int N,
                                                   int* __restrict__ counts) {
    int i = blockIdx.x * 256 + threadIdx.x;
    if (i < E) atomicAdd(&counts[ei[E + i]], 1);          // dst row of edge_index
    else if (i < E + N) atomicAdd(&counts[i - E], 1);     // self-loop
}

__global__ __launch_bounds__(1024) void scan_kernel(const int* __restrict__ counts, int N,
                                                    int* __restrict__ offs, int* __restrict__ cursor) {
    __shared__ int tot[1024];
    int t = threadIdx.x;
    int chunk = (N + 1023) / 1024;
    int b = t * chunk, e = min(b + chunk, N);
    int s = 0;
    for (int i = b; i < e; i++) s += counts[i];
    tot[t] = s;
    __syncthreads();
    for (int off = 1; off < 1024; off <<= 1) {
        int v = (t >= off) ? tot[t - off] : 0;
        __syncthreads();
        tot[t] += v;
        __syncthreads();
    }
    int run = (t > 0) ? tot[t - 1] : 0;
    for (int i = b; i < e; i++) {
        offs[i] = run; cursor[i] = run; run += counts[i];
    }
    if (t == 1023) offs[N] = tot[1023];
}

__global__ __launch_bounds__(256) void scatter_kernel(const int* __restrict__ ei, int E, int N,
                                                      int* __restrict__ cursor, int* __restrict__ csr) {
    int i = blockIdx.x * 256 + threadIdx.x;
    if (i < E) {
        int d = ei[E + i];
        int p = atomicAdd(&cursor[d], 1);
        csr[p] = ei[i];
    } else if (i < E + N) {
        int n = i - E;
        int p = atomicAdd(&cursor[n], 1);
        csr[p] = n;
    }
}

// ---------------- tiled GEMM: [N,K] f32 @ [K,256] f32 -> [N,256] f32 ----------
// block = 64 rows x 256 cols. A-tile staged in LDS; W read once per block
// (cooperative, coalesced). Thread register tile: 16 rows x 4 cols.
template <int K>
__global__ __launch_bounds__(256) void gemm_tile(const float* __restrict__ A,
                                                 const float* __restrict__ W,
                                                 float* __restrict__ O, int Nrows) {
    __shared__ float As[64 * K];
    int row0 = blockIdx.x * 64;
    int t = threadIdx.x;
    int rows = min(64, Nrows - row0);
    for (int idx = t; idx < rows * K; idx += 256)
        As[idx] = A[(size_t)row0 * K + idx];
    __syncthreads();

    int rg = t >> 6;        // row group: rows rg*16 .. rg*16+15
    int c = (t & 63) * 4;   // cols c..c+3
    float4 acc[16];
#pragma unroll
    for (int r = 0; r < 16; r++) acc[r] = make_float4(0.f, 0.f, 0.f, 0.f);

    const float* wp = W + c;
    float4 w0 = *(const float4*)(wp + 0 * 256);
    float4 w1 = *(const float4*)(wp + 1 * 256);
    float4 w2 = *(const float4*)(wp + 2 * 256);
    float4 w3 = *(const float4*)(wp + 3 * 256);
    for (int k = 0; k < K; k += 4) {
        float4 nw0, nw1, nw2, nw3;
        if (k + 4 < K) {  // prefetch next W quad
            const float* np = W + (size_t)(k + 4) * 256 + c;
            nw0 = *(const float4*)(np + 0 * 256);
            nw1 = *(const float4*)(np + 1 * 256);
            nw2 = *(const float4*)(np + 2 * 256);
            nw3 = *(const float4*)(np + 3 * 256);
        }
#pragma unroll
        for (int r = 0; r < 16; r++) {
            float4 a4 = *(const float4*)(&As[(rg * 16 + r) * K + k]);
            acc[r].x += a4.x * w0.x + a4.y * w1.x + a4.z * w2.x + a4.w * w3.x;
            acc[r].y += a4.x * w0.y + a4.y * w1.y + a4.z * w2.y + a4.w * w3.y;
            acc[r].z += a4.x * w0.z + a4.y * w1.z + a4.z * w2.z + a4.w * w3.z;
            acc[r].w += a4.x * w0.w + a4.y * w1.w + a4.z * w2.w + a4.w * w3.w;
        }
        w0 = nw0; w1 = nw1; w2 = nw2; w3 = nw3;
    }
#pragma unroll
    for (int r = 0; r < 16; r++) {
        int row = rg * 16 + r;
        if (row0 + row < Nrows)
            *(float4*)(O + (size_t)(row0 + row) * 256 + c) = acc[r];
    }
}

// ---------------- attention logits al_s/al_d = (h * a).sum(-1) per head -------
template <int H>
__global__ __launch_bounds__(256) void al_kernel(const float* __restrict__ h,
                                                 const float* __restrict__ as_, const float* __restrict__ ad_,
                                                 float* __restrict__ als, float* __restrict__ ald, int N) {
    const int G = 64 / H;  // lanes per head
    int w = (blockIdx.x * 256 + threadIdx.x) >> 6;
    int lane = threadIdx.x & 63;
    if (w >= N) return;
    float4 hv = ((const float4*)(h + (size_t)w * 256))[lane];
    float4 sv = ((const float4*)as_)[lane];
    float4 dv = ((const float4*)ad_)[lane];
    float ps = hv.x * sv.x + hv.y * sv.y + hv.z * sv.z + hv.w * sv.w;
    float pd = hv.x * dv.x + hv.y * dv.y + hv.z * dv.z + hv.w * dv.w;
#pragma unroll
    for (int o = G / 2; o; o >>= 1) {
        ps += __shfl_xor(ps, o);
        pd += __shfl_xor(pd, o);
    }
    if ((lane & (G - 1)) == 0) {
        als[w * H + lane / G] = ps;
        ald[w * H + lane / G] = pd;
    }
}

// ---------------- GAT softmax: per-dst max/denom, writes per-edge alpha -------
template <int H>
__global__ __launch_bounds__(256) void gat_softmax_kernel(const int* __restrict__ offs,
                                                          const int* __restrict__ csr,
                                                          const float* __restrict__ als,
                                                          const float* __restrict__ ald,
                                                          float* __restrict__ alpha, int N) {
    int w = (blockIdx.x * 256 + threadIdx.x) >> 6;
    int lane = threadIdx.x & 63;
    if (w >= N) return;
    int s0 = offs[w], s1 = offs[w + 1];
    float adl[H], e0[H], m[H], den[H];
#pragma unroll
    for (int hh = 0; hh < H; hh++) { adl[hh] = ald[w * H + hh]; m[hh] = -1e30f; }
    int i0 = s0 + lane;
    bool have = (i0 < s1);
    if (have) {
        int s = csr[i0];
        if (H == 4) {
            float4 av = ((const float4*)als)[s];
            float tmp[4] = {av.x, av.y, av.z, av.w};
#pragma unroll
            for (int hh = 0; hh < 4; hh++) {
                float e = tmp[hh] + adl[hh];
                e = e > 0.f ? e : 0.2f * e;
                e0[hh] = e; m[hh] = e;
            }
        } else {
            float e = als[s] + adl[0];
            e = e > 0.f ? e : 0.2f * e;
            e0[0] = e; m[0] = e;
        }
    }
    for (int i = i0 + 64; i < s1; i += 64) {  // rare: deg > 64
        int s = csr[i];
#pragma unroll
        for (int hh = 0; hh < H; hh++) {
            float e = als[s * H + hh] + adl[hh];
            e = e > 0.f ? e : 0.2f * e;
            m[hh] = fmaxf(m[hh], e);
        }
    }
#pragma unroll
    for (int hh = 0; hh < H; hh++)
        for (int o = 32; o; o >>= 1) m[hh] = fmaxf(m[hh], __shfl_xor(m[hh], o));
#pragma unroll
    for (int hh = 0; hh < H; hh++) den[hh] = have ? __expf(e0[hh] - m[hh]) : 0.f;
    for (int i = i0 + 64; i < s1; i += 64) {
        int s = csr[i];
#pragma unroll
        for (int hh = 0; hh < H; hh++) {
            float e = als[s * H + hh] + adl[hh];
            e = e > 0.f ? e : 0.2f * e;
            den[hh] += __expf(e - m[hh]);
        }
    }
#pragma unroll
    for (int hh = 0; hh < H; hh++)
        for (int o = 32; o; o >>= 1) den[hh] += __shfl_xor(den[hh], o);
    float rden[H];
#pragma unroll
    for (int hh = 0; hh < H; hh++) rden[hh] = 1.f / (den[hh] + 1e-16f);
    if (have) {
        if (H == 4) {
            float4 a;
            a.x = __expf(e0[0] - m[0]) * rden[0];
            a.y = __expf(e0[1] - m[1]) * rden[1];
            a.z = __expf(e0[2] - m[2]) * rden[2];
            a.w = __expf(e0[3] - m[3]) * rden[3];
            ((float4*)alpha)[i0] = a;
        } else {
            alpha[i0] = __expf(e0[0] - m[0]) * rden[0];
        }
    }
    for (int i = i0 + 64; i < s1; i += 64) {
        int s = csr[i];
#pragma unroll
        for (int hh = 0; hh < H; hh++) {
            float e = als[s * H + hh] + adl[hh];
            e = e > 0.f ? e : 0.2f * e;
            alpha[i * H + hh] = __expf(e - m[hh]) * rden[hh];
        }
    }
}

// ---------------- GAT accumulate: wave per dst, 4-wide unrolled gathers -------
template <int H>
__global__ __launch_bounds__(256) void gat_accum_kernel(const int* __restrict__ offs,
                                                        const int* __restrict__ csr,
                                                        const float* __restrict__ alpha,
                                                        const float* __restrict__ h,
                                                        float* __restrict__ out, int N) {
    int w = (blockIdx.x * 256 + threadIdx.x) >> 6;
    int lane = threadIdx.x & 63;
    if (w >= N) return;
    int s0 = offs[w], s1 = offs[w + 1];
    int myh = (H == 4) ? (lane >> 4) : 0;
    const float4* h4 = (const float4*)h;
    float4 acc = make_float4(0.f, 0.f, 0.f, 0.f);
    int i = s0;
    for (; i + 4 <= s1; i += 4) {
        int sa = csr[i], sb = csr[i + 1], sc = csr[i + 2], sd = csr[i + 3];
        float aa = alpha[i * H + myh];
        float ab = alpha[(i + 1) * H + myh];
        float ac = alpha[(i + 2) * H + myh];
        float ad = alpha[(i + 3) * H + myh];
        float4 ha = h4[(size_t)sa * 64 + lane];
        float4 hb = h4[(size_t)sb * 64 + lane];
        float4 hc = h4[(size_t)sc * 64 + lane];
        float4 hd = h4[(size_t)sd * 64 + lane];
        acc.x = fmaf(aa, ha.x, acc.x); acc.y = fmaf(aa, ha.y, acc.y);
        acc.z = fmaf(aa, ha.z, acc.z); acc.w = fmaf(aa, ha.w, acc.w);
        acc.x = fmaf(ab, hb.x, acc.x); acc.y = fmaf(ab, hb.y, acc.y);
        acc.z = fmaf(ab, hb.z, acc.z); acc.w = fmaf(ab, hb.w, acc.w);
        acc.x = fmaf(ac, hc.x, acc.x); acc.y = fmaf(ac, hc.y, acc.y);
        acc.z = fmaf(ac, hc.z, acc.z); acc.w = fmaf(ac, hc.w, acc.w);
        acc.x = fmaf(ad, hd.x, acc.x); acc.y = fmaf(ad, hd.y, acc.y);
        acc.z = fmaf(ad, hd.z, acc.z); acc.w = fmaf(ad, hd.w, acc.w);
    }
    for (; i < s1; i++) {
        int s = csr[i];
        float a = alpha[i * H + myh];
        float4 hv = h4[(size_t)s * 64 + lane];
        acc.x = fmaf(a, hv.x, acc.x); acc.y = fmaf(a, hv.y, acc.y);
        acc.z = fmaf(a, hv.z, acc.z); acc.w = fmaf(a, hv.w, acc.w);
    }
    ((float4*)out)[(size_t)w * 64 + lane] = acc;
}

// ---------------- BatchNorm (training-mode batch stats) -----------------------
__global__ __launch_bounds__(256) void bn_stats(const float* __restrict__ agg, int N,
                                                float* __restrict__ sum, float* __restrict__ sq) {
    int t = threadIdx.x;
    int rows = (N + gridDim.x - 1) / gridDim.x;
    int r0 = blockIdx.x * rows, r1 = min(r0 + rows, N);
    float s = 0.f, q = 0.f;
    for (int r = r0; r < r1; r++) {
        float v = agg[(size_t)r * 256 + t];
        s += v;
        q = fmaf(v, v, q);
    }
    atomicAdd(&sum[t], s);
    atomicAdd(&sq[t], q);
}

__global__ __launch_bounds__(256) void bn_final(const float* __restrict__ sum, const float* __restrict__ sq,
                                                const float* __restrict__ g, const float* __restrict__ be,
                                                int N, float* __restrict__ scale, float* __restrict__ shift) {
    int t = threadIdx.x;
    float inv = 1.f / (float)N;
    float m = sum[t] * inv;
    float v = fmaxf(sq[t] * inv - m * m, 0.f);
    float sc = rsqrtf(v + 1e-5f) * g[t];
    scale[t] = sc;
    shift[t] = be[t] - m * sc;
}

__global__ __launch_bounds__(256) void bn_apply_relu(const float* __restrict__ agg,
                                                     const float* __restrict__ scale,
                                                     const float* __restrict__ shift,
                                                     float* __restrict__ out, int N) {
    int i = blockIdx.x * 256 + threadIdx.x;  // one float4 (4 cols) per thread
    if (i >= N * 64) return;
    float4 v = ((const float4*)agg)[i];
    int c4 = i & 63;
    float4 sc = ((const float4*)scale)[c4];
    float4 sh = ((const float4*)shift)[c4];
    float4 o;
    o.x = fmaxf(fmaf(v.x, sc.x, sh.x), 0.f);
    o.y = fmaxf(fmaf(v.y, sc.y, sh.y), 0.f);
    o.z = fmaxf(fmaf(v.z, sc.z, sh.z), 0.f);
    o.w = fmaxf(fmaf(v.w, sc.w, sh.w), 0.f);
    ((float4*)out)[i] = o;
}

// ---------------- global mean pool ---------------------------------------------
__global__ __launch_bounds__(256) void pool_kernel(const float* __restrict__ xn, const int* __restrict__ batch,
                                                   int N, float* __restrict__ pools, int* __restrict__ cnt) {
    __shared__ float ps[2048];
    __shared__ int pc[8];
    int t = threadIdx.x;
    for (int i = t; i < 2048; i += 256) ps[i] = 0.f;
    if (t < 8) pc[t] = 0;
    __syncthreads();
    int rows = (N + gridDim.x - 1) / gridDim.x;
    int r0 = blockIdx.x * rows, r1 = min(r0 + rows, N);
    for (int r = r0; r < r1; r++) {
        int b = batch[r];
        ps[b * 256 + t] += xn[(size_t)r * 256 + t];
        if (t == 0) pc[b]++;
    }
    __syncthreads();
    for (int i = t; i < 2048; i += 256) atomicAdd(&pools[i], ps[i]);
    if (t < 8) atomicAdd(&cnt[t], pc[t]);
}

// shared = relu(global_feat @ W_sh + b_sh); one block per graph
__global__ __launch_bounds__(256) void shared_kernel(const float* __restrict__ pools, const int* __restrict__ cnt,
                                                     const float* __restrict__ Wsh, const float* __restrict__ bsh,
                                                     float* __restrict__ shg) {
    __shared__ float gf[256];
    int b = blockIdx.x, t = threadIdx.x;
    gf[t] = pools[b * 256 + t] / fmaxf((float)cnt[b], 1.f);
    __syncthreads();
    float acc = bsh[t];
    for (int k = 0; k < 256; k++) acc = fmaf(gf[k], Wsh[k * 256 + t], acc);
    shg[b * 256 + t] = fmaxf(acc, 0.f);
}

// tiny heads: gdot (shared . W_node[256:512]), value, type_logits
__global__ __launch_bounds__(64) void head2_kernel(const float* __restrict__ shg,
                                                   const float* __restrict__ Wnode,
                                                   const float* __restrict__ Wtype, const float* __restrict__ btype,
                                                   const float* __restrict__ Wcrit, const float* __restrict__ bcrit,
                                                   const float* __restrict__ xn, const int* __restrict__ tgt,
                                                   float* __restrict__ gdot, float* __restrict__ out_tail) {
    int t = threadIdx.x;
    if (t >= 32 && t < 40) {
        int b = t - 32;
        float g = 0.f, v = 0.f;
        for (int k = 0; k < 256; k++) {
            float s = shg[b * 256 + k];
            g = fmaf(s, Wnode[256 + k], g);
            v = fmaf(s, Wcrit[k], v);
        }
        gdot[b] = g;
        out_tail[32 + b] = v + bcrit[0];
    } else if (t < 32) {
        int b = t >> 2, a = t & 3;
        float acc = btype[a];
        int tn = tgt[b];
        for (int k = 0; k < 256; k++) acc = fmaf(shg[b * 256 + k], Wtype[k * 4 + a], acc);
        for (int k = 0; k < 256; k++) acc = fmaf(xn[(size_t)tn * 256 + k], Wtype[(256 + k) * 4 + a], acc);
        out_tail[t] = acc;
    }
}

// node_scores: one wave per node
__global__ __launch_bounds__(256) void node_scores_kernel(const float* __restrict__ xn,
                                                          const float* __restrict__ Wnode, const float* __restrict__ bnode,
                                                          const int* __restrict__ batch, const float* __restrict__ gdot,
                                                          float* __restrict__ out, int N) {
    int w = (blockIdx.x * 256 + threadIdx.x) >> 6;
    int lane = threadIdx.x & 63;
    if (w >= N) return;
    float4 xv = ((const float4*)(xn + (size_t)w * 256))[lane];
    float4 wv = ((const float4*)Wnode)[lane];
    float p = xv.x * wv.x + xv.y * wv.y + xv.z * wv.z + xv.w * wv.w;
    for (int o = 32; o; o >>= 1) p += __shfl_xor(p, o);
    if (lane == 0) out[w] = p + gdot[batch[w]] + bnode[0];
}

extern "C" void kernel_launch(void* const* d_in, const int* in_sizes, int n_in,
                              void* d_out, int out_size, void* d_ws, size_t ws_size,
                              hipStream_t stream) {
    const float* x = (const float*)d_in[0];
    const int* ei = (const int*)d_in[1];
    const int* batch = (const int*)d_in[2];
    const int* tgt = (const int*)d_in[3];
    const float* W1 = (const float*)d_in[4];
    const float* a1s = (const float*)d_in[5];
    const float* a1d = (const float*)d_in[6];
    // b1 (d_in[7]) / b2 (d_in[11]): constant column shifts cancel exactly in BatchNorm
    const float* W2 = (const float*)d_in[8];
    const float* a2s = (const float*)d_in[9];
    const float* a2d = (const float*)d_in[10];
    const float* g1 = (const float*)d_in[12];
    const float* be1 = (const float*)d_in[13];
    const float* g2 = (const float*)d_in[14];
    const float* be2 = (const float*)d_in[15];
    const float* Wsh = (const float*)d_in[16];
    const float* bsh = (const float*)d_in[17];
    const float* Wnode = (const float*)d_in[18];
    const float* bnode = (const float*)d_in[19];
    const float* Wtype = (const float*)d_in[20];
    const float* btype = (const float*)d_in[21];
    const float* Wcrit = (const float*)d_in[22];
    const float* bcrit = (const float*)d_in[23];

    const int N = in_sizes[2];
    const int E = in_sizes[1] / 2;
    const int Et = E + N;

    // ---- workspace carve (total ~114 MB; ping-pong between two N*256 bufs) ----
    char* w = (char*)d_ws;
    size_t off = 0;
    auto carve = [&](size_t bytes) -> char* {
        char* p = w + off;
        off = (off + bytes + 255) & ~(size_t)255;
        return p;
    };
    float* bufA = (float*)carve((size_t)N * 256 * 4);  // ping
    float* bufB = (float*)carve((size_t)N * 256 * 4);  // pong
    float* alpha = (float*)carve((size_t)Et * 4 * 4);  // per-edge softmax weights (H<=4)
    float* al1s = (float*)carve((size_t)N * 4 * 4);
    float* al1d = (float*)carve((size_t)N * 4 * 4);
    float* al2s = (float*)carve((size_t)N * 4);
    float* al2d = (float*)carve((size_t)N * 4);
    int* offs = (int*)carve((size_t)(N + 1) * 4);
    int* cursor = (int*)carve((size_t)N * 4);
    int* csr = (int*)carve((size_t)Et * 4);
    float* scale = (float*)carve(1024);
    float* shift = (float*)carve(1024);
    float* gdot = (float*)carve(64);
    float* shg = (float*)carve(8 * 256 * 4);
    char* zero0 = w + off;
    int* counts = (int*)carve((size_t)N * 4);
    float* bn1s = (float*)carve(1024);
    float* bn1q = (float*)carve(1024);
    float* bn2s = (float*)carve(1024);
    float* bn2q = (float*)carve(1024);
    float* pools = (float*)carve(8 * 256 * 4);
    int* cnt = (int*)carve(64);
    size_t zbytes = (size_t)((w + off) - zero0);
    hipMemsetAsync(zero0, 0, zbytes, stream);

    int wavesPerGrid = (N + 3) / 4;    // 4 waves (nodes) per 256-thread block
    int tileGrid = (N + 63) / 64;      // 64 rows per GEMM block

    // ---- CSR build (shared by both layers) ----
    hist_kernel<<<(Et + 255) / 256, 256, 0, stream>>>(ei, E, N, counts);
    scan_kernel<<<1, 1024, 0, stream>>>(counts, N, offs, cursor);
    scatter_kernel<<<(Et + 255) / 256, 256, 0, stream>>>(ei, E, N, cursor, csr);

    // ---- layer 1: GAT(4 heads) + BN + ReLU ----
    // gemm: x -> A(h1); accum: A -> B(agg1); bn: B -> A(layer-2 input)
    gemm_tile<64><<<tileGrid, 256, 0, stream>>>(x, W1, bufA, N);
    al_kernel<4><<<wavesPerGrid, 256, 0, stream>>>(bufA, a1s, a1d, al1s, al1d, N);
    gat_softmax_kernel<4><<<wavesPerGrid, 256, 0, stream>>>(offs, csr, al1s, al1d, alpha, N);
    gat_accum_kernel<4><<<wavesPerGrid, 256, 0, stream>>>(offs, csr, alpha, bufA, bufB, N);
    bn_stats<<<256, 256, 0, stream>>>(bufB, N, bn1s, bn1q);
    bn_final<<<1, 256, 0, stream>>>(bn1s, bn1q, g1, be1, N, scale, shift);
    bn_apply_relu<<<(N * 64 + 255) / 256, 256, 0, stream>>>(bufB, scale, shift, bufA, N);

    // ---- layer 2: GAT(1 head) + BN + ReLU ----
    // gemm: A -> B(h2); accum: B -> A(agg2); bn: A -> B(x_nodes)
    gemm_tile<256><<<tileGrid, 256, 0, stream>>>(bufA, W2, bufB, N);
    al_kernel<1><<<wavesPerGrid, 256, 0, stream>>>(bufB, a2s, a2d, al2s, al2d, N);
    gat_softmax_kernel<1><<<wavesPerGrid, 256, 0, stream>>>(offs, csr, al2s, al2d, alpha, N);
    gat_accum_kernel<1><<<wavesPerGrid, 256, 0, stream>>>(offs, csr, alpha, bufB, bufA, N);
    bn_stats<<<256, 256, 0, stream>>>(bufA, N, bn2s, bn2q);
    bn_final<<<1, 256, 0, stream>>>(bn2s, bn2q, g2, be2, N, scale, shift);
    bn_apply_relu<<<(N * 64 + 255) / 256, 256, 0, stream>>>(bufA, scale, shift, bufB, N);

    // ---- pooling + heads ----
    pool_kernel<<<128, 256, 0, stream>>>(bufB, batch, N, pools, cnt);
    shared_kernel<<<8, 256, 0, stream>>>(pools, cnt, Wsh, bsh, shg);
    head2_kernel<<<1, 64, 0, stream>>>(shg, Wnode, Wtype, btype, Wcrit, bcrit, bufB, tgt,
                                       gdot, (float*)d_out + N);
    node_scores_kernel<<<wavesPerGrid, 256, 0, stream>>>(bufB, Wnode, bnode, batch, gdot,
                                                         (float*)d_out, N);
}

// Round 5
// 747.089 us; speedup vs baseline: 1.7447x; 1.2345x over previous
//
#include <hip/hip_runtime.h>

typedef unsigned short u16;
typedef __attribute__((ext_vector_type(8))) short bf16x8;   // 8 bf16 = 4 VGPRs
typedef __attribute__((ext_vector_type(4))) float f32x4;

__device__ __forceinline__ float bf2f(u16 u) {
    return __uint_as_float(((unsigned int)u) << 16);
}
__device__ __forceinline__ u16 f2bf(float f) {
    unsigned int u = __float_as_uint(f);
    u += 0x7fffu + ((u >> 16) & 1u);
    return (u16)(u >> 16);
}

// ---------------- CSR build (dst-indexed), reused by both GAT layers ----------
__global__ __launch_bounds__(256) void hist_kernel(const int* __restrict__ ei, int E, int N,
                                                   int* __restrict__ counts) {
    int i = blockIdx.x * 256 + threadIdx.x;
    if (i < E) atomicAdd(&counts[ei[E + i]], 1);
    else if (i < E + N) atomicAdd(&counts[i - E], 1);
}

__global__ __launch_bounds__(1024) void scan_kernel(const int* __restrict__ counts, int N,
                                                    int* __restrict__ offs, int* __restrict__ cursor) {
    __shared__ int tot[1024];
    int t = threadIdx.x;
    int chunk = (N + 1023) / 1024;
    int b = t * chunk, e = min(b + chunk, N);
    int s = 0;
    for (int i = b; i < e; i++) s += counts[i];
    tot[t] = s;
    __syncthreads();
    for (int off = 1; off < 1024; off <<= 1) {
        int v = (t >= off) ? tot[t - off] : 0;
        __syncthreads();
        tot[t] += v;
        __syncthreads();
    }
    int run = (t > 0) ? tot[t - 1] : 0;
    for (int i = b; i < e; i++) {
        offs[i] = run; cursor[i] = run; run += counts[i];
    }
    if (t == 1023) offs[N] = tot[1023];
}

__global__ __launch_bounds__(256) void scatter_kernel(const int* __restrict__ ei, int E, int N,
                                                      int* __restrict__ cursor, int* __restrict__ csr) {
    int i = blockIdx.x * 256 + threadIdx.x;
    if (i < E) {
        int d = ei[E + i];
        int p = atomicAdd(&cursor[d], 1);
        csr[p] = ei[i];
    } else if (i < E + N) {
        int n = i - E;
        int p = atomicAdd(&cursor[n], 1);
        csr[p] = n;
    }
}

// ---------------- f32 -> bf16 convert (vectorized) ----------------------------
__global__ __launch_bounds__(256) void cvt_bf16_kernel(const float* __restrict__ in,
                                                       u16* __restrict__ out, int n4) {
    int i = blockIdx.x * 256 + threadIdx.x;
    if (i >= n4) return;
    float4 v = ((const float4*)in)[i];
    ushort4 o;
    o.x = f2bf(v.x); o.y = f2bf(v.y); o.z = f2bf(v.z); o.w = f2bf(v.w);
    ((ushort4*)out)[i] = o;
}

// ---------------- pack W [K,256] f32 into MFMA B-fragment order (bf16) --------
// B-frag for 16x16x32: lane holds B[k=ks*32+(lane>>4)*8+j][n=ct*16+(lane&15)]
// packed index: ((ct*KS+ks)*64+lane)*8+j  -> frag load = one 16B load per lane
__global__ __launch_bounds__(256) void packW_kernel(const float* __restrict__ W, int KS,
                                                    u16* __restrict__ out) {
    int idx = blockIdx.x * 256 + threadIdx.x;
    int total = 16 * KS * 512;
    if (idx >= total) return;
    int j = idx & 7;
    int lane = (idx >> 3) & 63;
    int rest = idx >> 9;        // ct*KS + ks
    int ks = rest % KS;
    int ct = rest / KS;
    int k = ks * 32 + (lane >> 4) * 8 + j;
    int n = ct * 16 + (lane & 15);
    out[idx] = f2bf(W[k * 256 + n]);
}

// ---------------- MFMA GEMM: [N,K] bf16 @ packed W -> [N,256] bf16 ------------
// wave = one 16-row tile; 16 col-tiles x (K/32) mfma_f32_16x16x32_bf16 steps.
// Epilogue transposes C through per-wave LDS for coalesced bf16 stores.
template <int K>
__global__ __launch_bounds__(256) void gemm_mfma(const u16* __restrict__ A,
                                                 const u16* __restrict__ Bp,
                                                 u16* __restrict__ O, int Nrows) {
    constexpr int KS = K / 32;
    __shared__ u16 lds[4][16 * 256];
    int wave = threadIdx.x >> 6, lane = threadIdx.x & 63;
    int tile = blockIdx.x * 4 + wave;
    if (tile * 16 >= Nrows) return;
    int row0 = tile * 16;
    int m = lane & 15, q = lane >> 4;

    bf16x8 afrag[KS];
    const u16* arow = A + (size_t)(row0 + m) * K + q * 8;
#pragma unroll
    for (int ks = 0; ks < KS; ks++)
        afrag[ks] = *(const bf16x8*)(arow + ks * 32);

    u16* myl = lds[wave];
#pragma unroll
    for (int ct = 0; ct < 16; ct++) {
        f32x4 acc = {0.f, 0.f, 0.f, 0.f};
        const u16* bp = Bp + ((size_t)(ct * KS) * 64 + lane) * 8;
#pragma unroll
        for (int ks = 0; ks < KS; ks++) {
            bf16x8 bfrag = *(const bf16x8*)(bp + (size_t)ks * 512);
            acc = __builtin_amdgcn_mfma_f32_16x16x32_bf16(afrag[ks], bfrag, acc, 0, 0, 0);
        }
        // C/D layout: col = lane&15, row = (lane>>4)*4 + r   [verified m89]
#pragma unroll
        for (int r = 0; r < 4; r++)
            myl[(q * 4 + r) * 256 + ct * 16 + m] = f2bf(acc[r]);
    }
    // same-wave LDS write->read (in-order DS per wave, no barrier needed)
#pragma unroll
    for (int p = 0; p < 8; p++) {
        int row = p * 2 + (lane >> 5);
        int c8 = (lane & 31) * 8;
        int4 v = *(const int4*)&myl[row * 256 + c8];
        *(int4*)&O[(size_t)(row0 + row) * 256 + c8] = v;
    }
}

// ---------------- attention logits al_s/al_d = (h * a).sum(-1) per head -------
template <int H>
__global__ __launch_bounds__(256) void al_kernel(const u16* __restrict__ h,
                                                 const float* __restrict__ as_, const float* __restrict__ ad_,
                                                 float* __restrict__ als, float* __restrict__ ald, int N) {
    const int G = 64 / H;
    int w = (blockIdx.x * 256 + threadIdx.x) >> 6;
    int lane = threadIdx.x & 63;
    if (w >= N) return;
    ushort4 hv = ((const ushort4*)(h + (size_t)w * 256))[lane];
    float4 sv = ((const float4*)as_)[lane];
    float4 dv = ((const float4*)ad_)[lane];
    float h0 = bf2f(hv.x), h1 = bf2f(hv.y), h2 = bf2f(hv.z), h3 = bf2f(hv.w);
    float ps = h0 * sv.x + h1 * sv.y + h2 * sv.z + h3 * sv.w;
    float pd = h0 * dv.x + h1 * dv.y + h2 * dv.z + h3 * dv.w;
#pragma unroll
    for (int o = G / 2; o; o >>= 1) {
        ps += __shfl_xor(ps, o);
        pd += __shfl_xor(pd, o);
    }
    if ((lane & (G - 1)) == 0) {
        als[w * H + lane / G] = ps;
        ald[w * H + lane / G] = pd;
    }
}

// ---------------- GAT softmax: per-dst max/denom, writes per-edge alpha -------
template <int H>
__global__ __launch_bounds__(256) void gat_softmax_kernel(const int* __restrict__ offs,
                                                          const int* __restrict__ csr,
                                                          const float* __restrict__ als,
                                                          const float* __restrict__ ald,
                                                          float* __restrict__ alpha, int N) {
    int w = (blockIdx.x * 256 + threadIdx.x) >> 6;
    int lane = threadIdx.x & 63;
    if (w >= N) return;
    int s0 = offs[w], s1 = offs[w + 1];
    float adl[H], e0[H], m[H], den[H];
#pragma unroll
    for (int hh = 0; hh < H; hh++) { adl[hh] = ald[w * H + hh]; m[hh] = -1e30f; }
    int i0 = s0 + lane;
    bool have = (i0 < s1);
    if (have) {
        int s = csr[i0];
        if (H == 4) {
            float4 av = ((const float4*)als)[s];
            float tmp[4] = {av.x, av.y, av.z, av.w};
#pragma unroll
            for (int hh = 0; hh < 4; hh++) {
                float e = tmp[hh] + adl[hh];
                e = e > 0.f ? e : 0.2f * e;
                e0[hh] = e; m[hh] = e;
            }
        } else {
            float e = als[s] + adl[0];
            e = e > 0.f ? e : 0.2f * e;
            e0[0] = e; m[0] = e;
        }
    }
    for (int i = i0 + 64; i < s1; i += 64) {  // rare: deg > 64
        int s = csr[i];
#pragma unroll
        for (int hh = 0; hh < H; hh++) {
            float e = als[s * H + hh] + adl[hh];
            e = e > 0.f ? e : 0.2f * e;
            m[hh] = fmaxf(m[hh], e);
        }
    }
#pragma unroll
    for (int hh = 0; hh < H; hh++)
        for (int o = 32; o; o >>= 1) m[hh] = fmaxf(m[hh], __shfl_xor(m[hh], o));
#pragma unroll
    for (int hh = 0; hh < H; hh++) den[hh] = have ? __expf(e0[hh] - m[hh]) : 0.f;
    for (int i = i0 + 64; i < s1; i += 64) {
        int s = csr[i];
#pragma unroll
        for (int hh = 0; hh < H; hh++) {
            float e = als[s * H + hh] + adl[hh];
            e = e > 0.f ? e : 0.2f * e;
            den[hh] += __expf(e - m[hh]);
        }
    }
#pragma unroll
    for (int hh = 0; hh < H; hh++)
        for (int o = 32; o; o >>= 1) den[hh] += __shfl_xor(den[hh], o);
    float rden[H];
#pragma unroll
    for (int hh = 0; hh < H; hh++) rden[hh] = 1.f / (den[hh] + 1e-16f);
    if (have) {
        if (H == 4) {
            float4 a;
            a.x = __expf(e0[0] - m[0]) * rden[0];
            a.y = __expf(e0[1] - m[1]) * rden[1];
            a.z = __expf(e0[2] - m[2]) * rden[2];
            a.w = __expf(e0[3] - m[3]) * rden[3];
            ((float4*)alpha)[i0] = a;
        } else {
            alpha[i0] = __expf(e0[0] - m[0]) * rden[0];
        }
    }
    for (int i = i0 + 64; i < s1; i += 64) {
        int s = csr[i];
#pragma unroll
        for (int hh = 0; hh < H; hh++) {
            float e = als[s * H + hh] + adl[hh];
            e = e > 0.f ? e : 0.2f * e;
            alpha[i * H + hh] = __expf(e - m[hh]) * rden[hh];
        }
    }
}

// ---------------- GAT accumulate: wave per dst, bf16 gathers, 4-wide unroll ---
template <int H>
__global__ __launch_bounds__(256) void gat_accum_kernel(const int* __restrict__ offs,
                                                        const int* __restrict__ csr,
                                                        const float* __restrict__ alpha,
                                                        const u16* __restrict__ h,
                                                        float* __restrict__ out, int N) {
    int w = (blockIdx.x * 256 + threadIdx.x) >> 6;
    int lane = threadIdx.x & 63;
    if (w >= N) return;
    int s0 = offs[w], s1 = offs[w + 1];
    int myh = (H == 4) ? (lane >> 4) : 0;
    const ushort4* h4 = (const ushort4*)h;
    float4 acc = make_float4(0.f, 0.f, 0.f, 0.f);
    int i = s0;
    for (; i + 4 <= s1; i += 4) {
        int sa = csr[i], sb = csr[i + 1], sc = csr[i + 2], sd = csr[i + 3];
        float aa = alpha[i * H + myh];
        float ab = alpha[(i + 1) * H + myh];
        float ac = alpha[(i + 2) * H + myh];
        float ad = alpha[(i + 3) * H + myh];
        ushort4 ha = h4[(size_t)sa * 64 + lane];
        ushort4 hb = h4[(size_t)sb * 64 + lane];
        ushort4 hc = h4[(size_t)sc * 64 + lane];
        ushort4 hd = h4[(size_t)sd * 64 + lane];
        acc.x = fmaf(aa, bf2f(ha.x), acc.x); acc.y = fmaf(aa, bf2f(ha.y), acc.y);
        acc.z = fmaf(aa, bf2f(ha.z), acc.z); acc.w = fmaf(aa, bf2f(ha.w), acc.w);
        acc.x = fmaf(ab, bf2f(hb.x), acc.x); acc.y = fmaf(ab, bf2f(hb.y), acc.y);
        acc.z = fmaf(ab, bf2f(hb.z), acc.z); acc.w = fmaf(ab, bf2f(hb.w), acc.w);
        acc.x = fmaf(ac, bf2f(hc.x), acc.x); acc.y = fmaf(ac, bf2f(hc.y), acc.y);
        acc.z = fmaf(ac, bf2f(hc.z), acc.z); acc.w = fmaf(ac, bf2f(hc.w), acc.w);
        acc.x = fmaf(ad, bf2f(hd.x), acc.x); acc.y = fmaf(ad, bf2f(hd.y), acc.y);
        acc.z = fmaf(ad, bf2f(hd.z), acc.z); acc.w = fmaf(ad, bf2f(hd.w), acc.w);
    }
    for (; i < s1; i++) {
        int s = csr[i];
        float a = alpha[i * H + myh];
        ushort4 hv = h4[(size_t)s * 64 + lane];
        acc.x = fmaf(a, bf2f(hv.x), acc.x); acc.y = fmaf(a, bf2f(hv.y), acc.y);
        acc.z = fmaf(a, bf2f(hv.z), acc.z); acc.w = fmaf(a, bf2f(hv.w), acc.w);
    }
    ((float4*)out)[(size_t)w * 64 + lane] = acc;
}

// ---------------- BatchNorm (training-mode batch stats) -----------------------
__global__ __launch_bounds__(256) void bn_stats(const float* __restrict__ agg, int N,
                                                float* __restrict__ sum, float* __restrict__ sq) {
    int t = threadIdx.x;
    int rows = (N + gridDim.x - 1) / gridDim.x;
    int r0 = blockIdx.x * rows, r1 = min(r0 + rows, N);
    float s = 0.f, q = 0.f;
    for (int r = r0; r < r1; r++) {
        float v = agg[(size_t)r * 256 + t];
        s += v;
        q = fmaf(v, v, q);
    }
    atomicAdd(&sum[t], s);
    atomicAdd(&sq[t], q);
}

__global__ __launch_bounds__(256) void bn_final(const float* __restrict__ sum, const float* __restrict__ sq,
                                                const float* __restrict__ g, const float* __restrict__ be,
                                                int N, float* __restrict__ scale, float* __restrict__ shift) {
    int t = threadIdx.x;
    float inv = 1.f / (float)N;
    float m = sum[t] * inv;
    float v = fmaxf(sq[t] * inv - m * m, 0.f);
    float sc = rsqrtf(v + 1e-5f) * g[t];
    scale[t] = sc;
    shift[t] = be[t] - m * sc;
}

// bn-apply + relu, f32 in -> bf16 out
__global__ __launch_bounds__(256) void bn_apply_relu(const float* __restrict__ agg,
                                                     const float* __restrict__ scale,
                                                     const float* __restrict__ shift,
                                                     u16* __restrict__ out, int N) {
    int i = blockIdx.x * 256 + threadIdx.x;
    if (i >= N * 64) return;
    float4 v = ((const float4*)agg)[i];
    int c4 = i & 63;
    float4 sc = ((const float4*)scale)[c4];
    float4 sh = ((const float4*)shift)[c4];
    ushort4 o;
    o.x = f2bf(fmaxf(fmaf(v.x, sc.x, sh.x), 0.f));
    o.y = f2bf(fmaxf(fmaf(v.y, sc.y, sh.y), 0.f));
    o.z = f2bf(fmaxf(fmaf(v.z, sc.z, sh.z), 0.f));
    o.w = f2bf(fmaxf(fmaf(v.w, sc.w, sh.w), 0.f));
    ((ushort4*)out)[i] = o;
}

// ---------------- global mean pool (bf16 input) --------------------------------
__global__ __launch_bounds__(256) void pool_kernel(const u16* __restrict__ xn, const int* __restrict__ batch,
                                                   int N, float* __restrict__ pools, int* __restrict__ cnt) {
    __shared__ float ps[2048];
    __shared__ int pc[8];
    int t = threadIdx.x;
    for (int i = t; i < 2048; i += 256) ps[i] = 0.f;
    if (t < 8) pc[t] = 0;
    __syncthreads();
    int rows = (N + gridDim.x - 1) / gridDim.x;
    int r0 = blockIdx.x * rows, r1 = min(r0 + rows, N);
    for (int r = r0; r < r1; r++) {
        int b = batch[r];
        ps[b * 256 + t] += bf2f(xn[(size_t)r * 256 + t]);
        if (t == 0) pc[b]++;
    }
    __syncthreads();
    for (int i = t; i < 2048; i += 256) atomicAdd(&pools[i], ps[i]);
    if (t < 8) atomicAdd(&cnt[t], pc[t]);
}

// shared = relu(global_feat @ W_sh + b_sh); one block per graph
__global__ __launch_bounds__(256) void shared_kernel(const float* __restrict__ pools, const int* __restrict__ cnt,
                                                     const float* __restrict__ Wsh, const float* __restrict__ bsh,
                                                     float* __restrict__ shg) {
    __shared__ float gf[256];
    int b = blockIdx.x, t = threadIdx.x;
    gf[t] = pools[b * 256 + t] / fmaxf((float)cnt[b], 1.f);
    __syncthreads();
    float acc = bsh[t];
    for (int k = 0; k < 256; k++) acc = fmaf(gf[k], Wsh[k * 256 + t], acc);
    shg[b * 256 + t] = fmaxf(acc, 0.f);
}

// tiny heads: gdot (shared . W_node[256:512]), value, type_logits
__global__ __launch_bounds__(64) void head2_kernel(const float* __restrict__ shg,
                                                   const float* __restrict__ Wnode,
                                                   const float* __restrict__ Wtype, const float* __restrict__ btype,
                                                   const float* __restrict__ Wcrit, const float* __restrict__ bcrit,
                                                   const u16* __restrict__ xn, const int* __restrict__ tgt,
                                                   float* __restrict__ gdot, float* __restrict__ out_tail) {
    int t = threadIdx.x;
    if (t >= 32 && t < 40) {
        int b = t - 32;
        float g = 0.f, v = 0.f;
        for (int k = 0; k < 256; k++) {
            float s = shg[b * 256 + k];
            g = fmaf(s, Wnode[256 + k], g);
            v = fmaf(s, Wcrit[k], v);
        }
        gdot[b] = g;
        out_tail[32 + b] = v + bcrit[0];
    } else if (t < 32) {
        int b = t >> 2, a = t & 3;
        float acc = btype[a];
        int tn = tgt[b];
        for (int k = 0; k < 256; k++) acc = fmaf(shg[b * 256 + k], Wtype[k * 4 + a], acc);
        for (int k = 0; k < 256; k++) acc = fmaf(bf2f(xn[(size_t)tn * 256 + k]), Wtype[(256 + k) * 4 + a], acc);
        out_tail[t] = acc;
    }
}

// node_scores: one wave per node (bf16 x_nodes)
__global__ __launch_bounds__(256) void node_scores_kernel(const u16* __restrict__ xn,
                                                          const float* __restrict__ Wnode, const float* __restrict__ bnode,
                                                          const int* __restrict__ batch, const float* __restrict__ gdot,
                                                          float* __restrict__ out, int N) {
    int w = (blockIdx.x * 256 + threadIdx.x) >> 6;
    int lane = threadIdx.x & 63;
    if (w >= N) return;
    ushort4 xv = ((const ushort4*)(xn + (size_t)w * 256))[lane];
    float4 wv = ((const float4*)Wnode)[lane];
    float p = bf2f(xv.x) * wv.x + bf2f(xv.y) * wv.y + bf2f(xv.z) * wv.z + bf2f(xv.w) * wv.w;
    for (int o = 32; o; o >>= 1) p += __shfl_xor(p, o);
    if (lane == 0) out[w] = p + gdot[batch[w]] + bnode[0];
}

extern "C" void kernel_launch(void* const* d_in, const int* in_sizes, int n_in,
                              void* d_out, int out_size, void* d_ws, size_t ws_size,
                              hipStream_t stream) {
    const float* x = (const float*)d_in[0];
    const int* ei = (const int*)d_in[1];
    const int* batch = (const int*)d_in[2];
    const int* tgt = (const int*)d_in[3];
    const float* W1 = (const float*)d_in[4];
    const float* a1s = (const float*)d_in[5];
    const float* a1d = (const float*)d_in[6];
    // b1 (d_in[7]) / b2 (d_in[11]): constant column shifts cancel exactly in BatchNorm
    const float* W2 = (const float*)d_in[8];
    const float* a2s = (const float*)d_in[9];
    const float* a2d = (const float*)d_in[10];
    const float* g1 = (const float*)d_in[12];
    const float* be1 = (const float*)d_in[13];
    const float* g2 = (const float*)d_in[14];
    const float* be2 = (const float*)d_in[15];
    const float* Wsh = (const float*)d_in[16];
    const float* bsh = (const float*)d_in[17];
    const float* Wnode = (const float*)d_in[18];
    const float* bnode = (const float*)d_in[19];
    const float* Wtype = (const float*)d_in[20];
    const float* btype = (const float*)d_in[21];
    const float* Wcrit = (const float*)d_in[22];
    const float* bcrit = (const float*)d_in[23];

    const int N = in_sizes[2];
    const int E = in_sizes[1] / 2;
    const int Et = E + N;

    // ---- workspace carve (~118 MB) ----
    char* w = (char*)d_ws;
    size_t off = 0;
    auto carve = [&](size_t bytes) -> char* {
        char* p = w + off;
        off = (off + bytes + 255) & ~(size_t)255;
        return p;
    };
    float* aggF = (float*)carve((size_t)N * 256 * 4);  // f32 aggregation (both layers)
    u16* h_bf = (u16*)carve((size_t)N * 256 * 2);      // h1 -> h2 (gemm outputs)
    u16* y_bf = (u16*)carve((size_t)N * 256 * 2);      // y1 (bn1 out) -> x_nodes
    u16* x_bf = (u16*)carve((size_t)N * 64 * 2);       // x in bf16
    u16* W1p = (u16*)carve(16 * 2 * 512 * 2);          // packed W1 frags
    u16* W2p = (u16*)carve(16 * 8 * 512 * 2);          // packed W2 frags
    float* alpha = (float*)carve((size_t)Et * 4 * 4);
    float* al1s = (float*)carve((size_t)N * 4 * 4);
    float* al1d = (float*)carve((size_t)N * 4 * 4);
    float* al2s = (float*)carve((size_t)N * 4);
    float* al2d = (float*)carve((size_t)N * 4);
    int* offs = (int*)carve((size_t)(N + 1) * 4);
    int* cursor = (int*)carve((size_t)N * 4);
    int* csr = (int*)carve((size_t)Et * 4);
    float* scale = (float*)carve(1024);
    float* shift = (float*)carve(1024);
    float* gdot = (float*)carve(64);
    float* shg = (float*)carve(8 * 256 * 4);
    char* zero0 = w + off;
    int* counts = (int*)carve((size_t)N * 4);
    float* bn1s = (float*)carve(1024);
    float* bn1q = (float*)carve(1024);
    float* bn2s = (float*)carve(1024);
    float* bn2q = (float*)carve(1024);
    float* pools = (float*)carve(8 * 256 * 4);
    int* cnt = (int*)carve(64);
    size_t zbytes = (size_t)((w + off) - zero0);
    hipMemsetAsync(zero0, 0, zbytes, stream);

    int wavesPerGrid = (N + 3) / 4;                 // 4 node-waves per 256-thread block
    int mfmaGrid = (((N + 15) / 16) + 3) / 4;       // 4 row-tiles (waves) per block

    // ---- CSR build + dtype prep ----
    hist_kernel<<<(Et + 255) / 256, 256, 0, stream>>>(ei, E, N, counts);
    scan_kernel<<<1, 1024, 0, stream>>>(counts, N, offs, cursor);
    scatter_kernel<<<(Et + 255) / 256, 256, 0, stream>>>(ei, E, N, cursor, csr);
    cvt_bf16_kernel<<<(N * 16 + 255) / 256, 256, 0, stream>>>(x, x_bf, N * 16);
    packW_kernel<<<(16 * 2 * 512 + 255) / 256, 256, 0, stream>>>(W1, 2, W1p);
    packW_kernel<<<(16 * 8 * 512 + 255) / 256, 256, 0, stream>>>(W2, 8, W2p);

    // ---- layer 1: GAT(4 heads) + BN + ReLU ----
    gemm_mfma<64><<<mfmaGrid, 256, 0, stream>>>(x_bf, W1p, h_bf, N);
    al_kernel<4><<<wavesPerGrid, 256, 0, stream>>>(h_bf, a1s, a1d, al1s, al1d, N);
    gat_softmax_kernel<4><<<wavesPerGrid, 256, 0, stream>>>(offs, csr, al1s, al1d, alpha, N);
    gat_accum_kernel<4><<<wavesPerGrid, 256, 0, stream>>>(offs, csr, alpha, h_bf, aggF, N);
    bn_stats<<<256, 256, 0, stream>>>(aggF, N, bn1s, bn1q);
    bn_final<<<1, 256, 0, stream>>>(bn1s, bn1q, g1, be1, N, scale, shift);
    bn_apply_relu<<<(N * 64 + 255) / 256, 256, 0, stream>>>(aggF, scale, shift, y_bf, N);

    // ---- layer 2: GAT(1 head) + BN + ReLU ----
    gemm_mfma<256><<<mfmaGrid, 256, 0, stream>>>(y_bf, W2p, h_bf, N);
    al_kernel<1><<<wavesPerGrid, 256, 0, stream>>>(h_bf, a2s, a2d, al2s, al2d, N);
    gat_softmax_kernel<1><<<wavesPerGrid, 256, 0, stream>>>(offs, csr, al2s, al2d, alpha, N);
    gat_accum_kernel<1><<<wavesPerGrid, 256, 0, stream>>>(offs, csr, alpha, h_bf, aggF, N);
    bn_stats<<<256, 256, 0, stream>>>(aggF, N, bn2s, bn2q);
    bn_final<<<1, 256, 0, stream>>>(bn2s, bn2q, g2, be2, N, scale, shift);
    bn_apply_relu<<<(N * 64 + 255) / 256, 256, 0, stream>>>(aggF, scale, shift, y_bf, N);

    // ---- pooling + heads ----
    pool_kernel<<<128, 256, 0, stream>>>(y_bf, batch, N, pools, cnt);
    shared_kernel<<<8, 256, 0, stream>>>(pools, cnt, Wsh, bsh, shg);
    head2_kernel<<<1, 64, 0, stream>>>(shg, Wnode, Wtype, btype, Wcrit, bcrit, y_bf, tgt,
                                       gdot, (float*)d_out + N);
    node_scores_kernel<<<wavesPerGrid, 256, 0, stream>>>(y_bf, Wnode, bnode, batch, gdot,
                                                         (float*)d_out, N);
}

// Round 6
// 621.003 us; speedup vs baseline: 2.0989x; 1.2030x over previous
//
#include <hip/hip_runtime.h>

typedef unsigned short u16;
typedef __attribute__((ext_vector_type(8))) short bf16x8;   // 8 bf16 = 4 VGPRs
typedef __attribute__((ext_vector_type(4))) float f32x4;

__device__ __forceinline__ float bf2f(u16 u) {
    return __uint_as_float(((unsigned int)u) << 16);
}
__device__ __forceinline__ u16 f2bf(float f) {
    unsigned int u = __float_as_uint(f);
    u += 0x7fffu + ((u >> 16) & 1u);
    return (u16)(u >> 16);
}

// ---------------- CSR build (dst-indexed), reused by both GAT layers ----------
__global__ __launch_bounds__(256) void hist_kernel(const int* __restrict__ ei, int E, int N,
                                                   int* __restrict__ counts) {
    int i = blockIdx.x * 256 + threadIdx.x;
    if (i < E) atomicAdd(&counts[ei[E + i]], 1);
    else if (i < E + N) atomicAdd(&counts[i - E], 1);
}

__global__ __launch_bounds__(1024) void scan_kernel(const int* __restrict__ counts, int N,
                                                    int* __restrict__ offs, int* __restrict__ cursor) {
    __shared__ int tot[1024];
    int t = threadIdx.x;
    int chunk = (N + 1023) / 1024;
    int b = t * chunk, e = min(b + chunk, N);
    int s = 0;
    for (int i = b; i < e; i++) s += counts[i];
    tot[t] = s;
    __syncthreads();
    for (int off = 1; off < 1024; off <<= 1) {
        int v = (t >= off) ? tot[t - off] : 0;
        __syncthreads();
        tot[t] += v;
        __syncthreads();
    }
    int run = (t > 0) ? tot[t - 1] : 0;
    for (int i = b; i < e; i++) {
        offs[i] = run; cursor[i] = run; run += counts[i];
    }
    if (t == 1023) offs[N] = tot[1023];
}

__global__ __launch_bounds__(256) void scatter_kernel(const int* __restrict__ ei, int E, int N,
                                                      int* __restrict__ cursor, int* __restrict__ csr) {
    int i = blockIdx.x * 256 + threadIdx.x;
    if (i < E) {
        int d = ei[E + i];
        int p = atomicAdd(&cursor[d], 1);
        csr[p] = ei[i];
    } else if (i < E + N) {
        int n = i - E;
        int p = atomicAdd(&cursor[n], 1);
        csr[p] = n;
    }
}

// ---------------- f32 -> bf16 convert (vectorized) ----------------------------
__global__ __launch_bounds__(256) void cvt_bf16_kernel(const float* __restrict__ in,
                                                       u16* __restrict__ out, int n4) {
    int i = blockIdx.x * 256 + threadIdx.x;
    if (i >= n4) return;
    float4 v = ((const float4*)in)[i];
    ushort4 o;
    o.x = f2bf(v.x); o.y = f2bf(v.y); o.z = f2bf(v.z); o.w = f2bf(v.w);
    ((ushort4*)out)[i] = o;
}

// ---------------- pack W [K,256] f32 into MFMA B-fragment order (bf16) --------
__global__ __launch_bounds__(256) void packW_kernel(const float* __restrict__ W, int KS,
                                                    u16* __restrict__ out) {
    int idx = blockIdx.x * 256 + threadIdx.x;
    int total = 16 * KS * 512;
    if (idx >= total) return;
    int j = idx & 7;
    int lane = (idx >> 3) & 63;
    int rest = idx >> 9;        // ct*KS + ks
    int ks = rest % KS;
    int ct = rest / KS;
    int k = ks * 32 + (lane >> 4) * 8 + j;
    int n = ct * 16 + (lane & 15);
    out[idx] = f2bf(W[k * 256 + n]);
}

// ---------------- MFMA GEMM: [N,K] bf16 @ packed W -> [N,256] bf16 ------------
template <int K>
__global__ __launch_bounds__(256) void gemm_mfma(const u16* __restrict__ A,
                                                 const u16* __restrict__ Bp,
                                                 u16* __restrict__ O, int Nrows) {
    constexpr int KS = K / 32;
    __shared__ u16 lds[4][16 * 256];
    int wave = threadIdx.x >> 6, lane = threadIdx.x & 63;
    int tile = blockIdx.x * 4 + wave;
    if (tile * 16 >= Nrows) return;
    int row0 = tile * 16;
    int m = lane & 15, q = lane >> 4;

    bf16x8 afrag[KS];
    const u16* arow = A + (size_t)(row0 + m) * K + q * 8;
#pragma unroll
    for (int ks = 0; ks < KS; ks++)
        afrag[ks] = *(const bf16x8*)(arow + ks * 32);

    u16* myl = lds[wave];
#pragma unroll
    for (int ct = 0; ct < 16; ct++) {
        f32x4 acc = {0.f, 0.f, 0.f, 0.f};
        const u16* bp = Bp + ((size_t)(ct * KS) * 64 + lane) * 8;
#pragma unroll
        for (int ks = 0; ks < KS; ks++) {
            bf16x8 bfrag = *(const bf16x8*)(bp + (size_t)ks * 512);
            acc = __builtin_amdgcn_mfma_f32_16x16x32_bf16(afrag[ks], bfrag, acc, 0, 0, 0);
        }
        // C/D layout: col = lane&15, row = (lane>>4)*4 + r   [verified m89]
#pragma unroll
        for (int r = 0; r < 4; r++)
            myl[(q * 4 + r) * 256 + ct * 16 + m] = f2bf(acc[r]);
    }
    // same-wave LDS write->read (in-order DS per wave, no barrier needed)
#pragma unroll
    for (int p = 0; p < 8; p++) {
        int row = p * 2 + (lane >> 5);
        int c8 = (lane & 31) * 8;
        int4 v = *(const int4*)&myl[row * 256 + c8];
        *(int4*)&O[(size_t)(row0 + row) * 256 + c8] = v;
    }
}

// ---------------- attention logits al_s/al_d = (h * a).sum(-1) per head -------
template <int H>
__global__ __launch_bounds__(256) void al_kernel(const u16* __restrict__ h,
                                                 const float* __restrict__ as_, const float* __restrict__ ad_,
                                                 float* __restrict__ als, float* __restrict__ ald, int N) {
    const int G = 64 / H;
    int w = (blockIdx.x * 256 + threadIdx.x) >> 6;
    int lane = threadIdx.x & 63;
    if (w >= N) return;
    ushort4 hv = ((const ushort4*)(h + (size_t)w * 256))[lane];
    float4 sv = ((const float4*)as_)[lane];
    float4 dv = ((const float4*)ad_)[lane];
    float h0 = bf2f(hv.x), h1 = bf2f(hv.y), h2 = bf2f(hv.z), h3 = bf2f(hv.w);
    float ps = h0 * sv.x + h1 * sv.y + h2 * sv.z + h3 * sv.w;
    float pd = h0 * dv.x + h1 * dv.y + h2 * dv.z + h3 * dv.w;
#pragma unroll
    for (int o = G / 2; o; o >>= 1) {
        ps += __shfl_xor(ps, o);
        pd += __shfl_xor(pd, o);
    }
    if ((lane & (G - 1)) == 0) {
        als[w * H + lane / G] = ps;
        ald[w * H + lane / G] = pd;
    }
}

// ---------------- GAT softmax: per-dst max/denom, writes per-edge alpha -------
template <int H>
__global__ __launch_bounds__(256) void gat_softmax_kernel(const int* __restrict__ offs,
                                                          const int* __restrict__ csr,
                                                          const float* __restrict__ als,
                                                          const float* __restrict__ ald,
                                                          float* __restrict__ alpha, int N) {
    int w = (blockIdx.x * 256 + threadIdx.x) >> 6;
    int lane = threadIdx.x & 63;
    if (w >= N) return;
    int s0 = offs[w], s1 = offs[w + 1];
    float adl[H], e0[H], m[H], den[H];
#pragma unroll
    for (int hh = 0; hh < H; hh++) { adl[hh] = ald[w * H + hh]; m[hh] = -1e30f; }
    int i0 = s0 + lane;
    bool have = (i0 < s1);
    if (have) {
        int s = csr[i0];
        if (H == 4) {
            float4 av = ((const float4*)als)[s];
            float tmp[4] = {av.x, av.y, av.z, av.w};
#pragma unroll
            for (int hh = 0; hh < 4; hh++) {
                float e = tmp[hh] + adl[hh];
                e = e > 0.f ? e : 0.2f * e;
                e0[hh] = e; m[hh] = e;
            }
        } else {
            float e = als[s] + adl[0];
            e = e > 0.f ? e : 0.2f * e;
            e0[0] = e; m[0] = e;
        }
    }
    for (int i = i0 + 64; i < s1; i += 64) {  // rare: deg > 64
        int s = csr[i];
#pragma unroll
        for (int hh = 0; hh < H; hh++) {
            float e = als[s * H + hh] + adl[hh];
            e = e > 0.f ? e : 0.2f * e;
            m[hh] = fmaxf(m[hh], e);
        }
    }
#pragma unroll
    for (int hh = 0; hh < H; hh++)
        for (int o = 32; o; o >>= 1) m[hh] = fmaxf(m[hh], __shfl_xor(m[hh], o));
#pragma unroll
    for (int hh = 0; hh < H; hh++) den[hh] = have ? __expf(e0[hh] - m[hh]) : 0.f;
    for (int i = i0 + 64; i < s1; i += 64) {
        int s = csr[i];
#pragma unroll
        for (int hh = 0; hh < H; hh++) {
            float e = als[s * H + hh] + adl[hh];
            e = e > 0.f ? e : 0.2f * e;
            den[hh] += __expf(e - m[hh]);
        }
    }
#pragma unroll
    for (int hh = 0; hh < H; hh++)
        for (int o = 32; o; o >>= 1) den[hh] += __shfl_xor(den[hh], o);
    float rden[H];
#pragma unroll
    for (int hh = 0; hh < H; hh++) rden[hh] = 1.f / (den[hh] + 1e-16f);
    if (have) {
        if (H == 4) {
            float4 a;
            a.x = __expf(e0[0] - m[0]) * rden[0];
            a.y = __expf(e0[1] - m[1]) * rden[1];
            a.z = __expf(e0[2] - m[2]) * rden[2];
            a.w = __expf(e0[3] - m[3]) * rden[3];
            ((float4*)alpha)[i0] = a;
        } else {
            alpha[i0] = __expf(e0[0] - m[0]) * rden[0];
        }
    }
    for (int i = i0 + 64; i < s1; i += 64) {
        int s = csr[i];
#pragma unroll
        for (int hh = 0; hh < H; hh++) {
            float e = als[s * H + hh] + adl[hh];
            e = e > 0.f ? e : 0.2f * e;
            alpha[i * H + hh] = __expf(e - m[hh]) * rden[hh];
        }
    }
}

// ---------------- GAT accumulate: wave per dst, bf16 gathers, 4-wide unroll ---
template <int H>
__global__ __launch_bounds__(256) void gat_accum_kernel(const int* __restrict__ offs,
                                                        const int* __restrict__ csr,
                                                        const float* __restrict__ alpha,
                                                        const u16* __restrict__ h,
                                                        float* __restrict__ out, int N) {
    int w = (blockIdx.x * 256 + threadIdx.x) >> 6;
    int lane = threadIdx.x & 63;
    if (w >= N) return;
    int s0 = offs[w], s1 = offs[w + 1];
    int myh = (H == 4) ? (lane >> 4) : 0;
    const ushort4* h4 = (const ushort4*)h;
    float4 acc = make_float4(0.f, 0.f, 0.f, 0.f);
    int i = s0;
    for (; i + 4 <= s1; i += 4) {
        int sa = csr[i], sb = csr[i + 1], sc = csr[i + 2], sd = csr[i + 3];
        float aa = alpha[i * H + myh];
        float ab = alpha[(i + 1) * H + myh];
        float ac = alpha[(i + 2) * H + myh];
        float ad = alpha[(i + 3) * H + myh];
        ushort4 ha = h4[(size_t)sa * 64 + lane];
        ushort4 hb = h4[(size_t)sb * 64 + lane];
        ushort4 hc = h4[(size_t)sc * 64 + lane];
        ushort4 hd = h4[(size_t)sd * 64 + lane];
        acc.x = fmaf(aa, bf2f(ha.x), acc.x); acc.y = fmaf(aa, bf2f(ha.y), acc.y);
        acc.z = fmaf(aa, bf2f(ha.z), acc.z); acc.w = fmaf(aa, bf2f(ha.w), acc.w);
        acc.x = fmaf(ab, bf2f(hb.x), acc.x); acc.y = fmaf(ab, bf2f(hb.y), acc.y);
        acc.z = fmaf(ab, bf2f(hb.z), acc.z); acc.w = fmaf(ab, bf2f(hb.w), acc.w);
        acc.x = fmaf(ac, bf2f(hc.x), acc.x); acc.y = fmaf(ac, bf2f(hc.y), acc.y);
        acc.z = fmaf(ac, bf2f(hc.z), acc.z); acc.w = fmaf(ac, bf2f(hc.w), acc.w);
        acc.x = fmaf(ad, bf2f(hd.x), acc.x); acc.y = fmaf(ad, bf2f(hd.y), acc.y);
        acc.z = fmaf(ad, bf2f(hd.z), acc.z); acc.w = fmaf(ad, bf2f(hd.w), acc.w);
    }
    for (; i < s1; i++) {
        int s = csr[i];
        float a = alpha[i * H + myh];
        ushort4 hv = h4[(size_t)s * 64 + lane];
        acc.x = fmaf(a, bf2f(hv.x), acc.x); acc.y = fmaf(a, bf2f(hv.y), acc.y);
        acc.z = fmaf(a, bf2f(hv.z), acc.z); acc.w = fmaf(a, bf2f(hv.w), acc.w);
    }
    ((float4*)out)[(size_t)w * 64 + lane] = acc;
}

// ---------------- BatchNorm stats (register acc; launch with many blocks) -----
__global__ __launch_bounds__(256) void bn_stats(const float* __restrict__ agg, int N,
                                                float* __restrict__ sum, float* __restrict__ sq) {
    int t = threadIdx.x;
    int rows = (N + gridDim.x - 1) / gridDim.x;
    int r0 = blockIdx.x * rows, r1 = min(r0 + rows, N);
    if (r0 >= r1) return;
    float s = 0.f, q = 0.f;
    for (int r = r0; r < r1; r++) {
        float v = agg[(size_t)r * 256 + t];
        s += v;
        q = fmaf(v, v, q);
    }
    atomicAdd(&sum[t], s);
    atomicAdd(&sq[t], q);
}

// bn scale/shift computed per-block in LDS (bn_final folded in), f32->bf16+relu
__global__ __launch_bounds__(256) void bn_apply_relu(const float* __restrict__ agg,
                                                     const float* __restrict__ sum,
                                                     const float* __restrict__ sq,
                                                     const float* __restrict__ g,
                                                     const float* __restrict__ be,
                                                     u16* __restrict__ out, int N) {
    __shared__ float sc_s[256], sh_s[256];
    int t = threadIdx.x;
    float inv = 1.f / (float)N;
    float mm = sum[t] * inv;
    float vv = fmaxf(sq[t] * inv - mm * mm, 0.f);
    float sc = rsqrtf(vv + 1e-5f) * g[t];
    sc_s[t] = sc;
    sh_s[t] = be[t] - mm * sc;
    __syncthreads();
    int total = N * 64;
    for (int i = blockIdx.x * 256 + t; i < total; i += gridDim.x * 256) {
        float4 v = ((const float4*)agg)[i];
        int c4 = i & 63;
        float4 scv = ((const float4*)sc_s)[c4];
        float4 shv = ((const float4*)sh_s)[c4];
        ushort4 o;
        o.x = f2bf(fmaxf(fmaf(v.x, scv.x, shv.x), 0.f));
        o.y = f2bf(fmaxf(fmaf(v.y, scv.y, shv.y), 0.f));
        o.z = f2bf(fmaxf(fmaf(v.z, scv.z, shv.z), 0.f));
        o.w = f2bf(fmaxf(fmaf(v.w, scv.w, shv.w), 0.f));
        ((ushort4*)out)[i] = o;
    }
}

// ---------------- global mean pool: register acc over sorted-batch segments ---
__global__ __launch_bounds__(256) void pool_kernel(const u16* __restrict__ xn, const int* __restrict__ batch,
                                                   int N, float* __restrict__ pools, int* __restrict__ cnt) {
    int t = threadIdx.x;
    int rows = (N + gridDim.x - 1) / gridDim.x;
    int r0 = blockIdx.x * rows, r1 = min(r0 + rows, N);
    if (r0 >= r1) return;
    float acc = 0.f;
    int cur = batch[r0];
    int c0 = 0;
    for (int r = r0; r < r1; r++) {
        int b = batch[r];
        if (b != cur) {  // rare: batch sorted, few segments per block
            atomicAdd(&pools[cur * 256 + t], acc);
            if (t == 0) atomicAdd(&cnt[cur], c0);
            acc = 0.f; c0 = 0; cur = b;
        }
        acc += bf2f(xn[(size_t)r * 256 + t]);
        c0++;
    }
    atomicAdd(&pools[cur * 256 + t], acc);
    if (t == 0) atomicAdd(&cnt[cur], c0);
}

// shared = relu(global_feat @ W_sh + b_sh); one block per graph
__global__ __launch_bounds__(256) void shared_kernel(const float* __restrict__ pools, const int* __restrict__ cnt,
                                                     const float* __restrict__ Wsh, const float* __restrict__ bsh,
                                                     float* __restrict__ shg) {
    __shared__ float gf[256];
    int b = blockIdx.x, t = threadIdx.x;
    gf[t] = pools[b * 256 + t] / fmaxf((float)cnt[b], 1.f);
    __syncthreads();
    float acc = bsh[t];
    for (int k = 0; k < 256; k++) acc = fmaf(gf[k], Wsh[k * 256 + t], acc);
    shg[b * 256 + t] = fmaxf(acc, 0.f);
}

// tiny heads: gdot (shared . W_node[256:512]), value, type_logits
__global__ __launch_bounds__(64) void head2_kernel(const float* __restrict__ shg,
                                                   const float* __restrict__ Wnode,
                                                   const float* __restrict__ Wtype, const float* __restrict__ btype,
                                                   const float* __restrict__ Wcrit, const float* __restrict__ bcrit,
                                                   const u16* __restrict__ xn, const int* __restrict__ tgt,
                                                   float* __restrict__ gdot, float* __restrict__ out_tail) {
    int t = threadIdx.x;
    if (t >= 32 && t < 40) {
        int b = t - 32;
        float g = 0.f, v = 0.f;
        for (int k = 0; k < 256; k++) {
            float s = shg[b * 256 + k];
            g = fmaf(s, Wnode[256 + k], g);
            v = fmaf(s, Wcrit[k], v);
        }
        gdot[b] = g;
        out_tail[32 + b] = v + bcrit[0];
    } else if (t < 32) {
        int b = t >> 2, a = t & 3;
        float acc = btype[a];
        int tn = tgt[b];
        for (int k = 0; k < 256; k++) acc = fmaf(shg[b * 256 + k], Wtype[k * 4 + a], acc);
        for (int k = 0; k < 256; k++) acc = fmaf(bf2f(xn[(size_t)tn * 256 + k]), Wtype[(256 + k) * 4 + a], acc);
        out_tail[t] = acc;
    }
}

// node_scores: one wave per node (bf16 x_nodes)
__global__ __launch_bounds__(256) void node_scores_kernel(const u16* __restrict__ xn,
                                                          const float* __restrict__ Wnode, const float* __restrict__ bnode,
                                                          const int* __restrict__ batch, const float* __restrict__ gdot,
                                                          float* __restrict__ out, int N) {
    int w = (blockIdx.x * 256 + threadIdx.x) >> 6;
    int lane = threadIdx.x & 63;
    if (w >= N) return;
    ushort4 xv = ((const ushort4*)(xn + (size_t)w * 256))[lane];
    float4 wv = ((const float4*)Wnode)[lane];
    float p = bf2f(xv.x) * wv.x + bf2f(xv.y) * wv.y + bf2f(xv.z) * wv.z + bf2f(xv.w) * wv.w;
    for (int o = 32; o; o >>= 1) p += __shfl_xor(p, o);
    if (lane == 0) out[w] = p + gdot[batch[w]] + bnode[0];
}

extern "C" void kernel_launch(void* const* d_in, const int* in_sizes, int n_in,
                              void* d_out, int out_size, void* d_ws, size_t ws_size,
                              hipStream_t stream) {
    const float* x = (const float*)d_in[0];
    const int* ei = (const int*)d_in[1];
    const int* batch = (const int*)d_in[2];
    const int* tgt = (const int*)d_in[3];
    const float* W1 = (const float*)d_in[4];
    const float* a1s = (const float*)d_in[5];
    const float* a1d = (const float*)d_in[6];
    // b1 (d_in[7]) / b2 (d_in[11]): constant column shifts cancel exactly in BatchNorm
    const float* W2 = (const float*)d_in[8];
    const float* a2s = (const float*)d_in[9];
    const float* a2d = (const float*)d_in[10];
    const float* g1 = (const float*)d_in[12];
    const float* be1 = (const float*)d_in[13];
    const float* g2 = (const float*)d_in[14];
    const float* be2 = (const float*)d_in[15];
    const float* Wsh = (const float*)d_in[16];
    const float* bsh = (const float*)d_in[17];
    const float* Wnode = (const float*)d_in[18];
    const float* bnode = (const float*)d_in[19];
    const float* Wtype = (const float*)d_in[20];
    const float* btype = (const float*)d_in[21];
    const float* Wcrit = (const float*)d_in[22];
    const float* bcrit = (const float*)d_in[23];

    const int N = in_sizes[2];
    const int E = in_sizes[1] / 2;
    const int Et = E + N;

    // ---- workspace carve (~118 MB) ----
    char* w = (char*)d_ws;
    size_t off = 0;
    auto carve = [&](size_t bytes) -> char* {
        char* p = w + off;
        off = (off + bytes + 255) & ~(size_t)255;
        return p;
    };
    float* aggF = (float*)carve((size_t)N * 256 * 4);  // f32 aggregation (both layers)
    u16* h_bf = (u16*)carve((size_t)N * 256 * 2);      // h1 -> h2 (gemm outputs)
    u16* y_bf = (u16*)carve((size_t)N * 256 * 2);      // y1 (bn1 out) -> x_nodes
    u16* x_bf = (u16*)carve((size_t)N * 64 * 2);       // x in bf16
    u16* W1p = (u16*)carve(16 * 2 * 512 * 2);          // packed W1 frags
    u16* W2p = (u16*)carve(16 * 8 * 512 * 2);          // packed W2 frags
    float* alpha = (float*)carve((size_t)Et * 4 * 4);
    float* al1s = (float*)carve((size_t)N * 4 * 4);
    float* al1d = (float*)carve((size_t)N * 4 * 4);
    float* al2s = (float*)carve((size_t)N * 4);
    float* al2d = (float*)carve((size_t)N * 4);
    int* offs = (int*)carve((size_t)(N + 1) * 4);
    int* cursor = (int*)carve((size_t)N * 4);
    int* csr = (int*)carve((size_t)Et * 4);
    float* gdot = (float*)carve(64);
    float* shg = (float*)carve(8 * 256 * 4);
    char* zero0 = w + off;
    int* counts = (int*)carve((size_t)N * 4);
    float* bn1s = (float*)carve(1024);
    float* bn1q = (float*)carve(1024);
    float* bn2s = (float*)carve(1024);
    float* bn2q = (float*)carve(1024);
    float* pools = (float*)carve(8 * 256 * 4);
    int* cnt = (int*)carve(64);
    size_t zbytes = (size_t)((w + off) - zero0);
    hipMemsetAsync(zero0, 0, zbytes, stream);

    int wavesPerGrid = (N + 3) / 4;                 // 4 node-waves per 256-thread block
    int mfmaGrid = (((N + 15) / 16) + 3) / 4;       // 4 row-tiles (waves) per block

    // ---- CSR build + dtype prep ----
    hist_kernel<<<(Et + 255) / 256, 256, 0, stream>>>(ei, E, N, counts);
    scan_kernel<<<1, 1024, 0, stream>>>(counts, N, offs, cursor);
    scatter_kernel<<<(Et + 255) / 256, 256, 0, stream>>>(ei, E, N, cursor, csr);
    cvt_bf16_kernel<<<(N * 16 + 255) / 256, 256, 0, stream>>>(x, x_bf, N * 16);
    packW_kernel<<<(16 * 2 * 512 + 255) / 256, 256, 0, stream>>>(W1, 2, W1p);
    packW_kernel<<<(16 * 8 * 512 + 255) / 256, 256, 0, stream>>>(W2, 8, W2p);

    // ---- layer 1: GAT(4 heads) + BN + ReLU ----
    gemm_mfma<64><<<mfmaGrid, 256, 0, stream>>>(x_bf, W1p, h_bf, N);
    al_kernel<4><<<wavesPerGrid, 256, 0, stream>>>(h_bf, a1s, a1d, al1s, al1d, N);
    gat_softmax_kernel<4><<<wavesPerGrid, 256, 0, stream>>>(offs, csr, al1s, al1d, alpha, N);
    gat_accum_kernel<4><<<wavesPerGrid, 256, 0, stream>>>(offs, csr, alpha, h_bf, aggF, N);
    bn_stats<<<1024, 256, 0, stream>>>(aggF, N, bn1s, bn1q);
    bn_apply_relu<<<2048, 256, 0, stream>>>(aggF, bn1s, bn1q, g1, be1, y_bf, N);

    // ---- layer 2: GAT(1 head) + BN + ReLU ----
    gemm_mfma<256><<<mfmaGrid, 256, 0, stream>>>(y_bf, W2p, h_bf, N);
    al_kernel<1><<<wavesPerGrid, 256, 0, stream>>>(h_bf, a2s, a2d, al2s, al2d, N);
    gat_softmax_kernel<1><<<wavesPerGrid, 256, 0, stream>>>(offs, csr, al2s, al2d, alpha, N);
    gat_accum_kernel<1><<<wavesPerGrid, 256, 0, stream>>>(offs, csr, alpha, h_bf, aggF, N);
    bn_stats<<<1024, 256, 0, stream>>>(aggF, N, bn2s, bn2q);
    bn_apply_relu<<<2048, 256, 0, stream>>>(aggF, bn2s, bn2q, g2, be2, y_bf, N);

    // ---- pooling + heads ----
    pool_kernel<<<1024, 256, 0, stream>>>(y_bf, batch, N, pools, cnt);
    shared_kernel<<<8, 256, 0, stream>>>(pools, cnt, Wsh, bsh, shg);
    head2_kernel<<<1, 64, 0, stream>>>(shg, Wnode, Wtype, btype, Wcrit, bcrit, y_bf, tgt,
                                       gdot, (float*)d_out + N);
    node_scores_kernel<<<wavesPerGrid, 256, 0, stream>>>(y_bf, Wnode, bnode, batch, gdot,
                                                         (float*)d_out, N);
}

// Round 7
// 514.921 us; speedup vs baseline: 2.5313x; 1.2060x over previous
//
#include <hip/hip_runtime.h>

typedef unsigned short u16;
typedef __attribute__((ext_vector_type(8))) short bf16x8;   // 8 bf16 = 4 VGPRs
typedef __attribute__((ext_vector_type(4))) float f32x4;

__device__ __forceinline__ float bf2f(u16 u) {
    return __uint_as_float(((unsigned int)u) << 16);
}
__device__ __forceinline__ u16 f2bf(float f) {
    unsigned int u = __float_as_uint(f);
    u += 0x7fffu + ((u >> 16) & 1u);
    return (u16)(u >> 16);
}

// ---------------- CSR build (dst-indexed), reused by both GAT layers ----------
__global__ __launch_bounds__(256) void hist_kernel(const int* __restrict__ ei, int E, int N,
                                                   int* __restrict__ counts) {
    int i = blockIdx.x * 256 + threadIdx.x;
    if (i < E) atomicAdd(&counts[ei[E + i]], 1);
    else if (i < E + N) atomicAdd(&counts[i - E], 1);
}

// ---- 3-phase parallel exclusive scan over counts[N] -> offs[N+1], cursor[N] --
__global__ __launch_bounds__(256) void scan_p1(const int* __restrict__ counts, int N,
                                               int* __restrict__ excl, int* __restrict__ bsum) {
    __shared__ int tmp[256];
    int t = threadIdx.x, b = blockIdx.x, i = b * 256 + t;
    int v = (i < N) ? counts[i] : 0;
    tmp[t] = v;
    __syncthreads();
    for (int o = 1; o < 256; o <<= 1) {
        int u = (t >= o) ? tmp[t - o] : 0;
        __syncthreads();
        tmp[t] += u;
        __syncthreads();
    }
    if (i < N) excl[i] = tmp[t] - v;
    if (t == 255) bsum[b] = tmp[255];
}

__global__ __launch_bounds__(256) void scan_p2(const int* __restrict__ bsum, int nb,
                                               int* __restrict__ bbase, int* __restrict__ total) {
    __shared__ int tmp[256];
    int t = threadIdx.x;
    int run = 0;
    for (int base = 0; base < nb; base += 256) {
        int idx = base + t;
        int v = (idx < nb) ? bsum[idx] : 0;
        tmp[t] = v;
        __syncthreads();
        for (int o = 1; o < 256; o <<= 1) {
            int u = (t >= o) ? tmp[t - o] : 0;
            __syncthreads();
            tmp[t] += u;
            __syncthreads();
        }
        if (idx < nb) bbase[idx] = run + tmp[t] - v;
        run += tmp[255];
        __syncthreads();
    }
    if (t == 0) *total = run;
}

__global__ __launch_bounds__(256) void scan_p3(const int* __restrict__ excl, const int* __restrict__ bbase,
                                               const int* __restrict__ total, int N,
                                               int* __restrict__ offs, int* __restrict__ cursor) {
    int t = threadIdx.x, b = blockIdx.x, i = b * 256 + t;
    if (i < N) {
        int o = excl[i] + bbase[b];
        offs[i] = o;
        cursor[i] = o;
    }
    if (i == 0) offs[N] = *total;
}

__global__ __launch_bounds__(256) void scatter_kernel(const int* __restrict__ ei, int E, int N,
                                                      int* __restrict__ cursor, int* __restrict__ csr) {
    int i = blockIdx.x * 256 + threadIdx.x;
    if (i < E) {
        int d = ei[E + i];
        int p = atomicAdd(&cursor[d], 1);
        csr[p] = ei[i];
    } else if (i < E + N) {
        int n = i - E;
        int p = atomicAdd(&cursor[n], 1);
        csr[p] = n;
    }
}

// ---------------- f32 -> bf16 convert (vectorized) ----------------------------
__global__ __launch_bounds__(256) void cvt_bf16_kernel(const float* __restrict__ in,
                                                       u16* __restrict__ out, int n4) {
    int i = blockIdx.x * 256 + threadIdx.x;
    if (i >= n4) return;
    float4 v = ((const float4*)in)[i];
    ushort4 o;
    o.x = f2bf(v.x); o.y = f2bf(v.y); o.z = f2bf(v.z); o.w = f2bf(v.w);
    ((ushort4*)out)[i] = o;
}

// ---------------- pack W [K,256] f32 into MFMA B-fragment order (bf16) --------
__global__ __launch_bounds__(256) void packW_kernel(const float* __restrict__ W, int KS,
                                                    u16* __restrict__ out) {
    int idx = blockIdx.x * 256 + threadIdx.x;
    int total = 16 * KS * 512;
    if (idx >= total) return;
    int j = idx & 7;
    int lane = (idx >> 3) & 63;
    int rest = idx >> 9;        // ct*KS + ks
    int ks = rest % KS;
    int ct = rest / KS;
    int k = ks * 32 + (lane >> 4) * 8 + j;
    int n = ct * 16 + (lane & 15);
    out[idx] = f2bf(W[k * 256 + n]);
}

// ---------------- MFMA GEMM: [N,K] bf16 @ packed W -> [N,256] bf16 ------------
template <int K>
__global__ __launch_bounds__(256) void gemm_mfma(const u16* __restrict__ A,
                                                 const u16* __restrict__ Bp,
                                                 u16* __restrict__ O, int Nrows) {
    constexpr int KS = K / 32;
    __shared__ u16 lds[4][16 * 256];
    int wave = threadIdx.x >> 6, lane = threadIdx.x & 63;
    int tile = blockIdx.x * 4 + wave;
    if (tile * 16 >= Nrows) return;
    int row0 = tile * 16;
    int m = lane & 15, q = lane >> 4;

    bf16x8 afrag[KS];
    const u16* arow = A + (size_t)(row0 + m) * K + q * 8;
#pragma unroll
    for (int ks = 0; ks < KS; ks++)
        afrag[ks] = *(const bf16x8*)(arow + ks * 32);

    u16* myl = lds[wave];
#pragma unroll
    for (int ct = 0; ct < 16; ct++) {
        f32x4 acc = {0.f, 0.f, 0.f, 0.f};
        const u16* bp = Bp + ((size_t)(ct * KS) * 64 + lane) * 8;
#pragma unroll
        for (int ks = 0; ks < KS; ks++) {
            bf16x8 bfrag = *(const bf16x8*)(bp + (size_t)ks * 512);
            acc = __builtin_amdgcn_mfma_f32_16x16x32_bf16(afrag[ks], bfrag, acc, 0, 0, 0);
        }
        // C/D layout: col = lane&15, row = (lane>>4)*4 + r   [verified m89]
#pragma unroll
        for (int r = 0; r < 4; r++)
            myl[(q * 4 + r) * 256 + ct * 16 + m] = f2bf(acc[r]);
    }
    // same-wave LDS write->read (in-order DS per wave, no barrier needed)
#pragma unroll
    for (int p = 0; p < 8; p++) {
        int row = p * 2 + (lane >> 5);
        int c8 = (lane & 31) * 8;
        int4 v = *(const int4*)&myl[row * 256 + c8];
        *(int4*)&O[(size_t)(row0 + row) * 256 + c8] = v;
    }
}

// ---------------- attention logits al_s/al_d = (h * a).sum(-1) per head -------
template <int H>
__global__ __launch_bounds__(256) void al_kernel(const u16* __restrict__ h,
                                                 const float* __restrict__ as_, const float* __restrict__ ad_,
                                                 float* __restrict__ als, float* __restrict__ ald, int N) {
    const int G = 64 / H;
    int w = (blockIdx.x * 256 + threadIdx.x) >> 6;
    int lane = threadIdx.x & 63;
    if (w >= N) return;
    ushort4 hv = ((const ushort4*)(h + (size_t)w * 256))[lane];
    float4 sv = ((const float4*)as_)[lane];
    float4 dv = ((const float4*)ad_)[lane];
    float h0 = bf2f(hv.x), h1 = bf2f(hv.y), h2 = bf2f(hv.z), h3 = bf2f(hv.w);
    float ps = h0 * sv.x + h1 * sv.y + h2 * sv.z + h3 * sv.w;
    float pd = h0 * dv.x + h1 * dv.y + h2 * dv.z + h3 * dv.w;
#pragma unroll
    for (int o = G / 2; o; o >>= 1) {
        ps += __shfl_xor(ps, o);
        pd += __shfl_xor(pd, o);
    }
    if ((lane & (G - 1)) == 0) {
        als[w * H + lane / G] = ps;
        ald[w * H + lane / G] = pd;
    }
}

// ---------------- GAT softmax: per-dst max/denom, writes per-edge alpha -------
template <int H>
__global__ __launch_bounds__(256) void gat_softmax_kernel(const int* __restrict__ offs,
                                                          const int* __restrict__ csr,
                                                          const float* __restrict__ als,
                                                          const float* __restrict__ ald,
                                                          float* __restrict__ alpha, int N) {
    int w = (blockIdx.x * 256 + threadIdx.x) >> 6;
    int lane = threadIdx.x & 63;
    if (w >= N) return;
    int s0 = offs[w], s1 = offs[w + 1];
    float adl[H], e0[H], m[H], den[H];
#pragma unroll
    for (int hh = 0; hh < H; hh++) { adl[hh] = ald[w * H + hh]; m[hh] = -1e30f; }
    int i0 = s0 + lane;
    bool have = (i0 < s1);
    if (have) {
        int s = csr[i0];
        if (H == 4) {
            float4 av = ((const float4*)als)[s];
            float tmp[4] = {av.x, av.y, av.z, av.w};
#pragma unroll
            for (int hh = 0; hh < 4; hh++) {
                float e = tmp[hh] + adl[hh];
                e = e > 0.f ? e : 0.2f * e;
                e0[hh] = e; m[hh] = e;
            }
        } else {
            float e = als[s] + adl[0];
            e = e > 0.f ? e : 0.2f * e;
            e0[0] = e; m[0] = e;
        }
    }
    for (int i = i0 + 64; i < s1; i += 64) {  // rare: deg > 64
        int s = csr[i];
#pragma unroll
        for (int hh = 0; hh < H; hh++) {
            float e = als[s * H + hh] + adl[hh];
            e = e > 0.f ? e : 0.2f * e;
            m[hh] = fmaxf(m[hh], e);
        }
    }
#pragma unroll
    for (int hh = 0; hh < H; hh++)
        for (int o = 32; o; o >>= 1) m[hh] = fmaxf(m[hh], __shfl_xor(m[hh], o));
#pragma unroll
    for (int hh = 0; hh < H; hh++) den[hh] = have ? __expf(e0[hh] - m[hh]) : 0.f;
    for (int i = i0 + 64; i < s1; i += 64) {
        int s = csr[i];
#pragma unroll
        for (int hh = 0; hh < H; hh++) {
            float e = als[s * H + hh] + adl[hh];
            e = e > 0.f ? e : 0.2f * e;
            den[hh] += __expf(e - m[hh]);
        }
    }
#pragma unroll
    for (int hh = 0; hh < H; hh++)
        for (int o = 32; o; o >>= 1) den[hh] += __shfl_xor(den[hh], o);
    float rden[H];
#pragma unroll
    for (int hh = 0; hh < H; hh++) rden[hh] = 1.f / (den[hh] + 1e-16f);
    if (have) {
        if (H == 4) {
            float4 a;
            a.x = __expf(e0[0] - m[0]) * rden[0];
            a.y = __expf(e0[1] - m[1]) * rden[1];
            a.z = __expf(e0[2] - m[2]) * rden[2];
            a.w = __expf(e0[3] - m[3]) * rden[3];
            ((float4*)alpha)[i0] = a;
        } else {
            alpha[i0] = __expf(e0[0] - m[0]) * rden[0];
        }
    }
    for (int i = i0 + 64; i < s1; i += 64) {
        int s = csr[i];
#pragma unroll
        for (int hh = 0; hh < H; hh++) {
            float e = als[s * H + hh] + adl[hh];
            e = e > 0.f ? e : 0.2f * e;
            alpha[i * H + hh] = __expf(e - m[hh]) * rden[hh];
        }
    }
}

// ---------------- GAT accumulate: wave per dst, bf16 gathers, 4-wide unroll ---
template <int H>
__global__ __launch_bounds__(256) void gat_accum_kernel(const int* __restrict__ offs,
                                                        const int* __restrict__ csr,
                                                        const float* __restrict__ alpha,
                                                        const u16* __restrict__ h,
                                                        float* __restrict__ out, int N) {
    int w = (blockIdx.x * 256 + threadIdx.x) >> 6;
    int lane = threadIdx.x & 63;
    if (w >= N) return;
    int s0 = offs[w], s1 = offs[w + 1];
    int myh = (H == 4) ? (lane >> 4) : 0;
    const ushort4* h4 = (const ushort4*)h;
    float4 acc = make_float4(0.f, 0.f, 0.f, 0.f);
    int i = s0;
    for (; i + 4 <= s1; i += 4) {
        int sa = csr[i], sb = csr[i + 1], sc = csr[i + 2], sd = csr[i + 3];
        float aa = alpha[i * H + myh];
        float ab = alpha[(i + 1) * H + myh];
        float ac = alpha[(i + 2) * H + myh];
        float ad = alpha[(i + 3) * H + myh];
        ushort4 ha = h4[(size_t)sa * 64 + lane];
        ushort4 hb = h4[(size_t)sb * 64 + lane];
        ushort4 hc = h4[(size_t)sc * 64 + lane];
        ushort4 hd = h4[(size_t)sd * 64 + lane];
        acc.x = fmaf(aa, bf2f(ha.x), acc.x); acc.y = fmaf(aa, bf2f(ha.y), acc.y);
        acc.z = fmaf(aa, bf2f(ha.z), acc.z); acc.w = fmaf(aa, bf2f(ha.w), acc.w);
        acc.x = fmaf(ab, bf2f(hb.x), acc.x); acc.y = fmaf(ab, bf2f(hb.y), acc.y);
        acc.z = fmaf(ab, bf2f(hb.z), acc.z); acc.w = fmaf(ab, bf2f(hb.w), acc.w);
        acc.x = fmaf(ac, bf2f(hc.x), acc.x); acc.y = fmaf(ac, bf2f(hc.y), acc.y);
        acc.z = fmaf(ac, bf2f(hc.z), acc.z); acc.w = fmaf(ac, bf2f(hc.w), acc.w);
        acc.x = fmaf(ad, bf2f(hd.x), acc.x); acc.y = fmaf(ad, bf2f(hd.y), acc.y);
        acc.z = fmaf(ad, bf2f(hd.z), acc.z); acc.w = fmaf(ad, bf2f(hd.w), acc.w);
    }
    for (; i < s1; i++) {
        int s = csr[i];
        float a = alpha[i * H + myh];
        ushort4 hv = h4[(size_t)s * 64 + lane];
        acc.x = fmaf(a, bf2f(hv.x), acc.x); acc.y = fmaf(a, bf2f(hv.y), acc.y);
        acc.z = fmaf(a, bf2f(hv.z), acc.z); acc.w = fmaf(a, bf2f(hv.w), acc.w);
    }
    ((float4*)out)[(size_t)w * 64 + lane] = acc;
}

// ---------------- BatchNorm stats (register acc; launch with many blocks) -----
__global__ __launch_bounds__(256) void bn_stats(const float* __restrict__ agg, int N,
                                                float* __restrict__ sum, float* __restrict__ sq) {
    int t = threadIdx.x;
    int rows = (N + gridDim.x - 1) / gridDim.x;
    int r0 = blockIdx.x * rows, r1 = min(r0 + rows, N);
    if (r0 >= r1) return;
    float s = 0.f, q = 0.f;
    for (int r = r0; r < r1; r++) {
        float v = agg[(size_t)r * 256 + t];
        s += v;
        q = fmaf(v, v, q);
    }
    atomicAdd(&sum[t], s);
    atomicAdd(&sq[t], q);
}

// bn scale/shift computed per-block in LDS (bn_final folded in), f32->bf16+relu
__global__ __launch_bounds__(256) void bn_apply_relu(const float* __restrict__ agg,
                                                     const float* __restrict__ sum,
                                                     const float* __restrict__ sq,
                                                     const float* __restrict__ g,
                                                     const float* __restrict__ be,
                                                     u16* __restrict__ out, int N) {
    __shared__ float sc_s[256], sh_s[256];
    int t = threadIdx.x;
    float inv = 1.f / (float)N;
    float mm = sum[t] * inv;
    float vv = fmaxf(sq[t] * inv - mm * mm, 0.f);
    float sc = rsqrtf(vv + 1e-5f) * g[t];
    sc_s[t] = sc;
    sh_s[t] = be[t] - mm * sc;
    __syncthreads();
    int total = N * 64;
    for (int i = blockIdx.x * 256 + t; i < total; i += gridDim.x * 256) {
        float4 v = ((const float4*)agg)[i];
        int c4 = i & 63;
        float4 scv = ((const float4*)sc_s)[c4];
        float4 shv = ((const float4*)sh_s)[c4];
        ushort4 o;
        o.x = f2bf(fmaxf(fmaf(v.x, scv.x, shv.x), 0.f));
        o.y = f2bf(fmaxf(fmaf(v.y, scv.y, shv.y), 0.f));
        o.z = f2bf(fmaxf(fmaf(v.z, scv.z, shv.z), 0.f));
        o.w = f2bf(fmaxf(fmaf(v.w, scv.w, shv.w), 0.f));
        ((ushort4*)out)[i] = o;
    }
}

// ---------------- global mean pool: register acc over sorted-batch segments ---
__global__ __launch_bounds__(256) void pool_kernel(const u16* __restrict__ xn, const int* __restrict__ batch,
                                                   int N, float* __restrict__ pools, int* __restrict__ cnt) {
    int t = threadIdx.x;
    int rows = (N + gridDim.x - 1) / gridDim.x;
    int r0 = blockIdx.x * rows, r1 = min(r0 + rows, N);
    if (r0 >= r1) return;
    float acc = 0.f;
    int cur = batch[r0];
    int c0 = 0;
    for (int r = r0; r < r1; r++) {
        int b = batch[r];
        if (b != cur) {  // rare: batch sorted, few segments per block
            atomicAdd(&pools[cur * 256 + t], acc);
            if (t == 0) atomicAdd(&cnt[cur], c0);
            acc = 0.f; c0 = 0; cur = b;
        }
        acc += bf2f(xn[(size_t)r * 256 + t]);
        c0++;
    }
    atomicAdd(&pools[cur * 256 + t], acc);
    if (t == 0) atomicAdd(&cnt[cur], c0);
}

// shared = relu(global_feat @ W_sh + b_sh); one block per graph
__global__ __launch_bounds__(256) void shared_kernel(const float* __restrict__ pools, const int* __restrict__ cnt,
                                                     const float* __restrict__ Wsh, const float* __restrict__ bsh,
                                                     float* __restrict__ shg) {
    __shared__ float gf[256];
    int b = blockIdx.x, t = threadIdx.x;
    gf[t] = pools[b * 256 + t] / fmaxf((float)cnt[b], 1.f);
    __syncthreads();
    float acc = bsh[t];
    for (int k = 0; k < 256; k++) acc = fmaf(gf[k], Wsh[k * 256 + t], acc);
    shg[b * 256 + t] = fmaxf(acc, 0.f);
}

// tiny heads: gdot (shared . W_node[256:512]), value, type_logits
__global__ __launch_bounds__(64) void head2_kernel(const float* __restrict__ shg,
                                                   const float* __restrict__ Wnode,
                                                   const float* __restrict__ Wtype, const float* __restrict__ btype,
                                                   const float* __restrict__ Wcrit, const float* __restrict__ bcrit,
                                                   const u16* __restrict__ xn, const int* __restrict__ tgt,
                                                   float* __restrict__ gdot, float* __restrict__ out_tail) {
    int t = threadIdx.x;
    if (t >= 32 && t < 40) {
        int b = t - 32;
        float g = 0.f, v = 0.f;
        for (int k = 0; k < 256; k++) {
            float s = shg[b * 256 + k];
            g = fmaf(s, Wnode[256 + k], g);
            v = fmaf(s, Wcrit[k], v);
        }
        gdot[b] = g;
        out_tail[32 + b] = v + bcrit[0];
    } else if (t < 32) {
        int b = t >> 2, a = t & 3;
        float acc = btype[a];
        int tn = tgt[b];
        for (int k = 0; k < 256; k++) acc = fmaf(shg[b * 256 + k], Wtype[k * 4 + a], acc);
        for (int k = 0; k < 256; k++) acc = fmaf(bf2f(xn[(size_t)tn * 256 + k]), Wtype[(256 + k) * 4 + a], acc);
        out_tail[t] = acc;
    }
}

// node_scores: one wave per node (bf16 x_nodes)
__global__ __launch_bounds__(256) void node_scores_kernel(const u16* __restrict__ xn,
                                                          const float* __restrict__ Wnode, const float* __restrict__ bnode,
                                                          const int* __restrict__ batch, const float* __restrict__ gdot,
                                                          float* __restrict__ out, int N) {
    int w = (blockIdx.x * 256 + threadIdx.x) >> 6;
    int lane = threadIdx.x & 63;
    if (w >= N) return;
    ushort4 xv = ((const ushort4*)(xn + (size_t)w * 256))[lane];
    float4 wv = ((const float4*)Wnode)[lane];
    float p = bf2f(xv.x) * wv.x + bf2f(xv.y) * wv.y + bf2f(xv.z) * wv.z + bf2f(xv.w) * wv.w;
    for (int o = 32; o; o >>= 1) p += __shfl_xor(p, o);
    if (lane == 0) out[w] = p + gdot[batch[w]] + bnode[0];
}

extern "C" void kernel_launch(void* const* d_in, const int* in_sizes, int n_in,
                              void* d_out, int out_size, void* d_ws, size_t ws_size,
                              hipStream_t stream) {
    const float* x = (const float*)d_in[0];
    const int* ei = (const int*)d_in[1];
    const int* batch = (const int*)d_in[2];
    const int* tgt = (const int*)d_in[3];
    const float* W1 = (const float*)d_in[4];
    const float* a1s = (const float*)d_in[5];
    const float* a1d = (const float*)d_in[6];
    // b1 (d_in[7]) / b2 (d_in[11]): constant column shifts cancel exactly in BatchNorm
    const float* W2 = (const float*)d_in[8];
    const float* a2s = (const float*)d_in[9];
    const float* a2d = (const float*)d_in[10];
    const float* g1 = (const float*)d_in[12];
    const float* be1 = (const float*)d_in[13];
    const float* g2 = (const float*)d_in[14];
    const float* be2 = (const float*)d_in[15];
    const float* Wsh = (const float*)d_in[16];
    const float* bsh = (const float*)d_in[17];
    const float* Wnode = (const float*)d_in[18];
    const float* bnode = (const float*)d_in[19];
    const float* Wtype = (const float*)d_in[20];
    const float* btype = (const float*)d_in[21];
    const float* Wcrit = (const float*)d_in[22];
    const float* bcrit = (const float*)d_in[23];

    const int N = in_sizes[2];
    const int E = in_sizes[1] / 2;
    const int Et = E + N;
    const int nb = (N + 255) / 256;   // scan blocks

    // ---- workspace carve (~119 MB) ----
    char* w = (char*)d_ws;
    size_t off = 0;
    auto carve = [&](size_t bytes) -> char* {
        char* p = w + off;
        off = (off + bytes + 255) & ~(size_t)255;
        return p;
    };
    float* aggF = (float*)carve((size_t)N * 256 * 4);  // f32 aggregation (both layers)
    u16* h_bf = (u16*)carve((size_t)N * 256 * 2);      // h1 -> h2 (gemm outputs)
    u16* y_bf = (u16*)carve((size_t)N * 256 * 2);      // y1 (bn1 out) -> x_nodes
    u16* x_bf = (u16*)carve((size_t)N * 64 * 2);       // x in bf16
    u16* W1p = (u16*)carve(16 * 2 * 512 * 2);          // packed W1 frags
    u16* W2p = (u16*)carve(16 * 8 * 512 * 2);          // packed W2 frags
    float* alpha = (float*)carve((size_t)Et * 4 * 4);
    float* al1s = (float*)carve((size_t)N * 4 * 4);
    float* al1d = (float*)carve((size_t)N * 4 * 4);
    float* al2s = (float*)carve((size_t)N * 4);
    float* al2d = (float*)carve((size_t)N * 4);
    int* offs = (int*)carve((size_t)(N + 1) * 4);
    int* cursor = (int*)carve((size_t)N * 4);
    int* csr = (int*)carve((size_t)Et * 4);
    int* excl = (int*)carve((size_t)N * 4);
    int* bsum = (int*)carve((size_t)nb * 4);
    int* bbase = (int*)carve((size_t)nb * 4);
    int* stotal = (int*)carve(64);
    float* gdot = (float*)carve(64);
    float* shg = (float*)carve(8 * 256 * 4);
    char* zero0 = w + off;
    int* counts = (int*)carve((size_t)N * 4);
    float* bn1s = (float*)carve(1024);
    float* bn1q = (float*)carve(1024);
    float* bn2s = (float*)carve(1024);
    float* bn2q = (float*)carve(1024);
    float* pools = (float*)carve(8 * 256 * 4);
    int* cnt = (int*)carve(64);
    size_t zbytes = (size_t)((w + off) - zero0);
    hipMemsetAsync(zero0, 0, zbytes, stream);

    int wavesPerGrid = (N + 3) / 4;                 // 4 node-waves per 256-thread block
    int mfmaGrid = (((N + 15) / 16) + 3) / 4;       // 4 row-tiles (waves) per block

    // ---- CSR build (3-phase parallel scan) + dtype prep ----
    hist_kernel<<<(Et + 255) / 256, 256, 0, stream>>>(ei, E, N, counts);
    scan_p1<<<nb, 256, 0, stream>>>(counts, N, excl, bsum);
    scan_p2<<<1, 256, 0, stream>>>(bsum, nb, bbase, stotal);
    scan_p3<<<nb, 256, 0, stream>>>(excl, bbase, stotal, N, offs, cursor);
    scatter_kernel<<<(Et + 255) / 256, 256, 0, stream>>>(ei, E, N, cursor, csr);
    cvt_bf16_kernel<<<(N * 16 + 255) / 256, 256, 0, stream>>>(x, x_bf, N * 16);
    packW_kernel<<<(16 * 2 * 512 + 255) / 256, 256, 0, stream>>>(W1, 2, W1p);
    packW_kernel<<<(16 * 8 * 512 + 255) / 256, 256, 0, stream>>>(W2, 8, W2p);

    // ---- layer 1: GAT(4 heads) + BN + ReLU ----
    gemm_mfma<64><<<mfmaGrid, 256, 0, stream>>>(x_bf, W1p, h_bf, N);
    al_kernel<4><<<wavesPerGrid, 256, 0, stream>>>(h_bf, a1s, a1d, al1s, al1d, N);
    gat_softmax_kernel<4><<<wavesPerGrid, 256, 0, stream>>>(offs, csr, al1s, al1d, alpha, N);
    gat_accum_kernel<4><<<wavesPerGrid, 256, 0, stream>>>(offs, csr, alpha, h_bf, aggF, N);
    bn_stats<<<1024, 256, 0, stream>>>(aggF, N, bn1s, bn1q);
    bn_apply_relu<<<2048, 256, 0, stream>>>(aggF, bn1s, bn1q, g1, be1, y_bf, N);

    // ---- layer 2: GAT(1 head) + BN + ReLU ----
    gemm_mfma<256><<<mfmaGrid, 256, 0, stream>>>(y_bf, W2p, h_bf, N);
    al_kernel<1><<<wavesPerGrid, 256, 0, stream>>>(h_bf, a2s, a2d, al2s, al2d, N);
    gat_softmax_kernel<1><<<wavesPerGrid, 256, 0, stream>>>(offs, csr, al2s, al2d, alpha, N);
    gat_accum_kernel<1><<<wavesPerGrid, 256, 0, stream>>>(offs, csr, alpha, h_bf, aggF, N);
    bn_stats<<<1024, 256, 0, stream>>>(aggF, N, bn2s, bn2q);
    bn_apply_relu<<<2048, 256, 0, stream>>>(aggF, bn2s, bn2q, g2, be2, y_bf, N);

    // ---- pooling + heads ----
    pool_kernel<<<1024, 256, 0, stream>>>(y_bf, batch, N, pools, cnt);
    shared_kernel<<<8, 256, 0, stream>>>(pools, cnt, Wsh, bsh, shg);
    head2_kernel<<<1, 64, 0, stream>>>(shg, Wnode, Wtype, btype, Wcrit, bcrit, y_bf, tgt,
                                       gdot, (float*)d_out + N);
    node_scores_kernel<<<wavesPerGrid, 256, 0, stream>>>(y_bf, Wnode, bnode, batch, gdot,
                                                         (float*)d_out, N);
}

// Round 8
// 455.594 us; speedup vs baseline: 2.8609x; 1.1302x over previous
//
#include <hip/hip_runtime.h>

typedef unsigned short u16;
typedef __attribute__((ext_vector_type(8))) short bf16x8;   // 8 bf16 = 4 VGPRs
typedef __attribute__((ext_vector_type(4))) float f32x4;

__device__ __forceinline__ float bf2f(u16 u) {
    return __uint_as_float(((unsigned int)u) << 16);
}
__device__ __forceinline__ u16 f2bf(float f) {
    unsigned int u = __float_as_uint(f);
    u += 0x7fffu + ((u >> 16) & 1u);
    return (u16)(u >> 16);
}

// ---------------- CSR build (dst-indexed), reused by both GAT layers ----------
__global__ __launch_bounds__(256) void hist_kernel(const int* __restrict__ ei, int E, int N,
                                                   int* __restrict__ counts) {
    int i = blockIdx.x * 256 + threadIdx.x;
    if (i < E) atomicAdd(&counts[ei[E + i]], 1);
    else if (i < E + N) atomicAdd(&counts[i - E], 1);
}

// ---- 3-phase parallel exclusive scan over counts[N] -> offs[N+1], cursor[N] --
__global__ __launch_bounds__(256) void scan_p1(const int* __restrict__ counts, int N,
                                               int* __restrict__ excl, int* __restrict__ bsum) {
    __shared__ int tmp[256];
    int t = threadIdx.x, b = blockIdx.x, i = b * 256 + t;
    int v = (i < N) ? counts[i] : 0;
    tmp[t] = v;
    __syncthreads();
    for (int o = 1; o < 256; o <<= 1) {
        int u = (t >= o) ? tmp[t - o] : 0;
        __syncthreads();
        tmp[t] += u;
        __syncthreads();
    }
    if (i < N) excl[i] = tmp[t] - v;
    if (t == 255) bsum[b] = tmp[255];
}

__global__ __launch_bounds__(256) void scan_p2(const int* __restrict__ bsum, int nb,
                                               int* __restrict__ bbase, int* __restrict__ total) {
    __shared__ int tmp[256];
    int t = threadIdx.x;
    int run = 0;
    for (int base = 0; base < nb; base += 256) {
        int idx = base + t;
        int v = (idx < nb) ? bsum[idx] : 0;
        tmp[t] = v;
        __syncthreads();
        for (int o = 1; o < 256; o <<= 1) {
            int u = (t >= o) ? tmp[t - o] : 0;
            __syncthreads();
            tmp[t] += u;
            __syncthreads();
        }
        if (idx < nb) bbase[idx] = run + tmp[t] - v;
        run += tmp[255];
        __syncthreads();
    }
    if (t == 0) *total = run;
}

__global__ __launch_bounds__(256) void scan_p3(const int* __restrict__ excl, const int* __restrict__ bbase,
                                               const int* __restrict__ total, int N,
                                               int* __restrict__ offs, int* __restrict__ cursor) {
    int t = threadIdx.x, b = blockIdx.x, i = b * 256 + t;
    if (i < N) {
        int o = excl[i] + bbase[b];
        offs[i] = o;
        cursor[i] = o;
    }
    if (i == 0) offs[N] = *total;
}

__global__ __launch_bounds__(256) void scatter_kernel(const int* __restrict__ ei, int E, int N,
                                                      int* __restrict__ cursor, int* __restrict__ csr) {
    int i = blockIdx.x * 256 + threadIdx.x;
    if (i < E) {
        int d = ei[E + i];
        int p = atomicAdd(&cursor[d], 1);
        csr[p] = ei[i];
    } else if (i < E + N) {
        int n = i - E;
        int p = atomicAdd(&cursor[n], 1);
        csr[p] = n;
    }
}

// ---------------- f32 -> bf16 convert (vectorized) ----------------------------
__global__ __launch_bounds__(256) void cvt_bf16_kernel(const float* __restrict__ in,
                                                       u16* __restrict__ out, int n4) {
    int i = blockIdx.x * 256 + threadIdx.x;
    if (i >= n4) return;
    float4 v = ((const float4*)in)[i];
    ushort4 o;
    o.x = f2bf(v.x); o.y = f2bf(v.y); o.z = f2bf(v.z); o.w = f2bf(v.w);
    ((ushort4*)out)[i] = o;
}

// ---------------- pack W [K,256] f32 into MFMA B-fragment order (bf16) --------
__global__ __launch_bounds__(256) void packW_kernel(const float* __restrict__ W, int KS,
                                                    u16* __restrict__ out) {
    int idx = blockIdx.x * 256 + threadIdx.x;
    int total = 16 * KS * 512;
    if (idx >= total) return;
    int j = idx & 7;
    int lane = (idx >> 3) & 63;
    int rest = idx >> 9;        // ct*KS + ks
    int ks = rest % KS;
    int ct = rest / KS;
    int k = ks * 32 + (lane >> 4) * 8 + j;
    int n = ct * 16 + (lane & 15);
    out[idx] = f2bf(W[k * 256 + n]);
}

// ---------------- MFMA GEMM + fused attention-logit epilogue ------------------
// wave = 16-row tile; ct loop unrolled x2 (two independent MFMA chains for
// latency hiding). Epilogue: LDS transpose -> coalesced bf16 store AND the
// per-row al_s/al_d dot products (h row already in registers).
template <int K, int H>
__global__ __launch_bounds__(256) void gemm_mfma(const u16* __restrict__ A,
                                                 const u16* __restrict__ Bp,
                                                 u16* __restrict__ O,
                                                 const float* __restrict__ as_,
                                                 const float* __restrict__ ad_,
                                                 float* __restrict__ als,
                                                 float* __restrict__ ald, int Nrows) {
    constexpr int KS = K / 32;
    __shared__ u16 lds[4][16 * 256];
    int wave = threadIdx.x >> 6, lane = threadIdx.x & 63;
    int tile = blockIdx.x * 4 + wave;
    if (tile * 16 >= Nrows) return;
    int row0 = tile * 16;
    int m = lane & 15, q = lane >> 4;

    bf16x8 afrag[KS];
    const u16* arow = A + (size_t)(row0 + m) * K + q * 8;
#pragma unroll
    for (int ks = 0; ks < KS; ks++)
        afrag[ks] = *(const bf16x8*)(arow + ks * 32);

    u16* myl = lds[wave];
#pragma unroll
    for (int ct2 = 0; ct2 < 8; ct2++) {
        int ct0 = ct2 * 2;
        f32x4 acc0 = {0.f, 0.f, 0.f, 0.f};
        f32x4 acc1 = {0.f, 0.f, 0.f, 0.f};
        const u16* bp0 = Bp + ((size_t)(ct0 * KS) * 64 + lane) * 8;
        const u16* bp1 = bp0 + (size_t)KS * 512;
        bf16x8 b0[KS], b1[KS];
#pragma unroll
        for (int ks = 0; ks < KS; ks++) {
            b0[ks] = *(const bf16x8*)(bp0 + (size_t)ks * 512);
            b1[ks] = *(const bf16x8*)(bp1 + (size_t)ks * 512);
        }
#pragma unroll
        for (int ks = 0; ks < KS; ks++) {  // two independent chains
            acc0 = __builtin_amdgcn_mfma_f32_16x16x32_bf16(afrag[ks], b0[ks], acc0, 0, 0, 0);
            acc1 = __builtin_amdgcn_mfma_f32_16x16x32_bf16(afrag[ks], b1[ks], acc1, 0, 0, 0);
        }
        // C/D layout: col = lane&15, row = (lane>>4)*4 + r   [verified m89]
#pragma unroll
        for (int r = 0; r < 4; r++) {
            myl[(q * 4 + r) * 256 + ct0 * 16 + m] = f2bf(acc0[r]);
            myl[(q * 4 + r) * 256 + ct0 * 16 + 16 + m] = f2bf(acc1[r]);
        }
    }
    // epilogue: coalesced store + al dot (same-wave LDS, no barrier needed)
    int c8 = (lane & 31) * 8;
    float4 s0 = *(const float4*)(as_ + c8);
    float4 s1 = *(const float4*)(as_ + c8 + 4);
    float4 d0 = *(const float4*)(ad_ + c8);
    float4 d1 = *(const float4*)(ad_ + c8 + 4);
#pragma unroll
    for (int p = 0; p < 8; p++) {
        int row = p * 2 + (lane >> 5);
        int4 v = *(const int4*)&myl[row * 256 + c8];
        *(int4*)&O[(size_t)(row0 + row) * 256 + c8] = v;
        float f0 = bf2f((u16)(v.x & 0xffff)), f1 = bf2f((u16)((unsigned)v.x >> 16));
        float f2 = bf2f((u16)(v.y & 0xffff)), f3 = bf2f((u16)((unsigned)v.y >> 16));
        float f4 = bf2f((u16)(v.z & 0xffff)), f5 = bf2f((u16)((unsigned)v.z >> 16));
        float f6 = bf2f((u16)(v.w & 0xffff)), f7 = bf2f((u16)((unsigned)v.w >> 16));
        float ps = f0 * s0.x + f1 * s0.y + f2 * s0.z + f3 * s0.w +
                   f4 * s1.x + f5 * s1.y + f6 * s1.z + f7 * s1.w;
        float pd = f0 * d0.x + f1 * d0.y + f2 * d0.z + f3 * d0.w +
                   f4 * d1.x + f5 * d1.y + f6 * d1.z + f7 * d1.w;
        const int W = (H == 4) ? 8 : 32;   // lanes per head-segment in a 32-lane row-group
#pragma unroll
        for (int o = 1; o < W; o <<= 1) {
            ps += __shfl_xor(ps, o);
            pd += __shfl_xor(pd, o);
        }
        if (H == 4) {
            if ((lane & 7) == 0) {
                int head = (lane & 31) >> 3;
                als[(row0 + row) * 4 + head] = ps;
                ald[(row0 + row) * 4 + head] = pd;
            }
        } else {
            if ((lane & 31) == 0) {
                als[row0 + row] = ps;
                ald[row0 + row] = pd;
            }
        }
    }
}

// ---------------- GAT softmax: per-dst max/denom, writes per-edge alpha -------
template <int H>
__global__ __launch_bounds__(256) void gat_softmax_kernel(const int* __restrict__ offs,
                                                          const int* __restrict__ csr,
                                                          const float* __restrict__ als,
                                                          const float* __restrict__ ald,
                                                          float* __restrict__ alpha, int N) {
    int w = (blockIdx.x * 256 + threadIdx.x) >> 6;
    int lane = threadIdx.x & 63;
    if (w >= N) return;
    int s0 = offs[w], s1 = offs[w + 1];
    float adl[H], e0[H], m[H], den[H];
#pragma unroll
    for (int hh = 0; hh < H; hh++) { adl[hh] = ald[w * H + hh]; m[hh] = -1e30f; }
    int i0 = s0 + lane;
    bool have = (i0 < s1);
    if (have) {
        int s = csr[i0];
        if (H == 4) {
            float4 av = ((const float4*)als)[s];
            float tmp[4] = {av.x, av.y, av.z, av.w};
#pragma unroll
            for (int hh = 0; hh < 4; hh++) {
                float e = tmp[hh] + adl[hh];
                e = e > 0.f ? e : 0.2f * e;
                e0[hh] = e; m[hh] = e;
            }
        } else {
            float e = als[s] + adl[0];
            e = e > 0.f ? e : 0.2f * e;
            e0[0] = e; m[0] = e;
        }
    }
    for (int i = i0 + 64; i < s1; i += 64) {  // rare: deg > 64
        int s = csr[i];
#pragma unroll
        for (int hh = 0; hh < H; hh++) {
            float e = als[s * H + hh] + adl[hh];
            e = e > 0.f ? e : 0.2f * e;
            m[hh] = fmaxf(m[hh], e);
        }
    }
#pragma unroll
    for (int hh = 0; hh < H; hh++)
        for (int o = 32; o; o >>= 1) m[hh] = fmaxf(m[hh], __shfl_xor(m[hh], o));
#pragma unroll
    for (int hh = 0; hh < H; hh++) den[hh] = have ? __expf(e0[hh] - m[hh]) : 0.f;
    for (int i = i0 + 64; i < s1; i += 64) {
        int s = csr[i];
#pragma unroll
        for (int hh = 0; hh < H; hh++) {
            float e = als[s * H + hh] + adl[hh];
            e = e > 0.f ? e : 0.2f * e;
            den[hh] += __expf(e - m[hh]);
        }
    }
#pragma unroll
    for (int hh = 0; hh < H; hh++)
        for (int o = 32; o; o >>= 1) den[hh] += __shfl_xor(den[hh], o);
    float rden[H];
#pragma unroll
    for (int hh = 0; hh < H; hh++) rden[hh] = 1.f / (den[hh] + 1e-16f);
    if (have) {
        if (H == 4) {
            float4 a;
            a.x = __expf(e0[0] - m[0]) * rden[0];
            a.y = __expf(e0[1] - m[1]) * rden[1];
            a.z = __expf(e0[2] - m[2]) * rden[2];
            a.w = __expf(e0[3] - m[3]) * rden[3];
            ((float4*)alpha)[i0] = a;
        } else {
            alpha[i0] = __expf(e0[0] - m[0]) * rden[0];
        }
    }
    for (int i = i0 + 64; i < s1; i += 64) {
        int s = csr[i];
#pragma unroll
        for (int hh = 0; hh < H; hh++) {
            float e = als[s * H + hh] + adl[hh];
            e = e > 0.f ? e : 0.2f * e;
            alpha[i * H + hh] = __expf(e - m[hh]) * rden[hh];
        }
    }
}

// ---------------- GAT accumulate: wave per dst, bf16 gathers, 4-wide unroll ---
template <int H>
__global__ __launch_bounds__(256) void gat_accum_kernel(const int* __restrict__ offs,
                                                        const int* __restrict__ csr,
                                                        const float* __restrict__ alpha,
                                                        const u16* __restrict__ h,
                                                        float* __restrict__ out, int N) {
    int w = (blockIdx.x * 256 + threadIdx.x) >> 6;
    int lane = threadIdx.x & 63;
    if (w >= N) return;
    int s0 = offs[w], s1 = offs[w + 1];
    int myh = (H == 4) ? (lane >> 4) : 0;
    const ushort4* h4 = (const ushort4*)h;
    float4 acc = make_float4(0.f, 0.f, 0.f, 0.f);
    int i = s0;
    for (; i + 4 <= s1; i += 4) {
        int sa = csr[i], sb = csr[i + 1], sc = csr[i + 2], sd = csr[i + 3];
        float aa = alpha[i * H + myh];
        float ab = alpha[(i + 1) * H + myh];
        float ac = alpha[(i + 2) * H + myh];
        float ad = alpha[(i + 3) * H + myh];
        ushort4 ha = h4[(size_t)sa * 64 + lane];
        ushort4 hb = h4[(size_t)sb * 64 + lane];
        ushort4 hc = h4[(size_t)sc * 64 + lane];
        ushort4 hd = h4[(size_t)sd * 64 + lane];
        acc.x = fmaf(aa, bf2f(ha.x), acc.x); acc.y = fmaf(aa, bf2f(ha.y), acc.y);
        acc.z = fmaf(aa, bf2f(ha.z), acc.z); acc.w = fmaf(aa, bf2f(ha.w), acc.w);
        acc.x = fmaf(ab, bf2f(hb.x), acc.x); acc.y = fmaf(ab, bf2f(hb.y), acc.y);
        acc.z = fmaf(ab, bf2f(hb.z), acc.z); acc.w = fmaf(ab, bf2f(hb.w), acc.w);
        acc.x = fmaf(ac, bf2f(hc.x), acc.x); acc.y = fmaf(ac, bf2f(hc.y), acc.y);
        acc.z = fmaf(ac, bf2f(hc.z), acc.z); acc.w = fmaf(ac, bf2f(hc.w), acc.w);
        acc.x = fmaf(ad, bf2f(hd.x), acc.x); acc.y = fmaf(ad, bf2f(hd.y), acc.y);
        acc.z = fmaf(ad, bf2f(hd.z), acc.z); acc.w = fmaf(ad, bf2f(hd.w), acc.w);
    }
    for (; i < s1; i++) {
        int s = csr[i];
        float a = alpha[i * H + myh];
        ushort4 hv = h4[(size_t)s * 64 + lane];
        acc.x = fmaf(a, bf2f(hv.x), acc.x); acc.y = fmaf(a, bf2f(hv.y), acc.y);
        acc.z = fmaf(a, bf2f(hv.z), acc.z); acc.w = fmaf(a, bf2f(hv.w), acc.w);
    }
    ((float4*)out)[(size_t)w * 64 + lane] = acc;
}

// ---------------- BatchNorm stats (register acc; many blocks) -----------------
__global__ __launch_bounds__(256) void bn_stats(const float* __restrict__ agg, int N,
                                                float* __restrict__ sum, float* __restrict__ sq) {
    int t = threadIdx.x;
    int rows = (N + gridDim.x - 1) / gridDim.x;
    int r0 = blockIdx.x * rows, r1 = min(r0 + rows, N);
    if (r0 >= r1) return;
    float s = 0.f, q = 0.f;
    for (int r = r0; r < r1; r++) {
        float v = agg[(size_t)r * 256 + t];
        s += v;
        q = fmaf(v, v, q);
    }
    atomicAdd(&sum[t], s);
    atomicAdd(&sq[t], q);
}

// bn scale/shift folded; f32 -> bf16 + relu (layer 1)
__global__ __launch_bounds__(256) void bn_apply_relu(const float* __restrict__ agg,
                                                     const float* __restrict__ sum,
                                                     const float* __restrict__ sq,
                                                     const float* __restrict__ g,
                                                     const float* __restrict__ be,
                                                     u16* __restrict__ out, int N) {
    __shared__ float sc_s[256], sh_s[256];
    int t = threadIdx.x;
    float inv = 1.f / (float)N;
    float mm = sum[t] * inv;
    float vv = fmaxf(sq[t] * inv - mm * mm, 0.f);
    float sc = rsqrtf(vv + 1e-5f) * g[t];
    sc_s[t] = sc;
    sh_s[t] = be[t] - mm * sc;
    __syncthreads();
    int total = N * 64;
    for (int i = blockIdx.x * 256 + t; i < total; i += gridDim.x * 256) {
        float4 v = ((const float4*)agg)[i];
        int c4 = i & 63;
        float4 scv = ((const float4*)sc_s)[c4];
        float4 shv = ((const float4*)sh_s)[c4];
        ushort4 o;
        o.x = f2bf(fmaxf(fmaf(v.x, scv.x, shv.x), 0.f));
        o.y = f2bf(fmaxf(fmaf(v.y, scv.y, shv.y), 0.f));
        o.z = f2bf(fmaxf(fmaf(v.z, scv.z, shv.z), 0.f));
        o.w = f2bf(fmaxf(fmaf(v.w, scv.w, shv.w), 0.f));
        ((ushort4*)out)[i] = o;
    }
}

// layer 2: bn-apply + relu + fused global-mean-pool (batch sorted -> register
// run-accumulate per thread-column, atomic flush per segment)
__global__ __launch_bounds__(256) void bn_apply_pool(const float* __restrict__ agg,
                                                     const float* __restrict__ sum,
                                                     const float* __restrict__ sq,
                                                     const float* __restrict__ g,
                                                     const float* __restrict__ be,
                                                     const int* __restrict__ batch,
                                                     u16* __restrict__ out,
                                                     float* __restrict__ pools,
                                                     int* __restrict__ cnt, int N) {
    int t = threadIdx.x;
    float inv = 1.f / (float)N;
    float mm = sum[t] * inv;
    float vv = fmaxf(sq[t] * inv - mm * mm, 0.f);
    float sc = rsqrtf(vv + 1e-5f) * g[t];
    float sh = be[t] - mm * sc;
    int rows = (N + gridDim.x - 1) / gridDim.x;
    int r0 = blockIdx.x * rows, r1 = min(r0 + rows, N);
    if (r0 >= r1) return;
    float acc = 0.f;
    int cur = batch[r0], c0 = 0;
    for (int r = r0; r < r1; r++) {
        int b = batch[r];  // wave-uniform scalar load
        if (b != cur) {
            atomicAdd(&pools[cur * 256 + t], acc);
            if (t == 0) atomicAdd(&cnt[cur], c0);
            acc = 0.f; c0 = 0; cur = b;
        }
        float v = agg[(size_t)r * 256 + t];
        float y = fmaxf(fmaf(v, sc, sh), 0.f);
        out[(size_t)r * 256 + t] = f2bf(y);
        acc += y; c0++;
    }
    atomicAdd(&pools[cur * 256 + t], acc);
    if (t == 0) atomicAdd(&cnt[cur], c0);
}

// shared = relu(gf @ W_sh + b_sh) fused with heads (gdot, value, type logits);
// one block per graph
__global__ __launch_bounds__(256) void shared_head_kernel(const float* __restrict__ pools,
                                                          const int* __restrict__ cnt,
                                                          const float* __restrict__ Wsh,
                                                          const float* __restrict__ bsh,
                                                          const float* __restrict__ Wnode,
                                                          const float* __restrict__ Wcrit,
                                                          const float* __restrict__ bcrit,
                                                          const float* __restrict__ Wtype,
                                                          const float* __restrict__ btype,
                                                          const u16* __restrict__ xn,
                                                          const int* __restrict__ tgt,
                                                          float* __restrict__ gdot,
                                                          float* __restrict__ out_tail) {
    __shared__ float gf[256], red[256];
    int b = blockIdx.x, t = threadIdx.x;
    gf[t] = pools[b * 256 + t] / fmaxf((float)cnt[b], 1.f);
    __syncthreads();
    float acc = bsh[t];
    for (int k = 0; k < 256; k++) acc = fmaf(gf[k], Wsh[k * 256 + t], acc);
    float s = fmaxf(acc, 0.f);
    int tn = tgt[b];
    float xnt = bf2f(xn[(size_t)tn * 256 + t]);
    float pg = s * Wnode[256 + t];
    float pv = s * Wcrit[t];
    float pt0 = s * Wtype[t * 4 + 0] + xnt * Wtype[(256 + t) * 4 + 0];
    float pt1 = s * Wtype[t * 4 + 1] + xnt * Wtype[(256 + t) * 4 + 1];
    float pt2 = s * Wtype[t * 4 + 2] + xnt * Wtype[(256 + t) * 4 + 2];
    float pt3 = s * Wtype[t * 4 + 3] + xnt * Wtype[(256 + t) * 4 + 3];
    auto bred = [&](float v) -> float {
        __syncthreads();
        red[t] = v;
        __syncthreads();
        for (int o = 128; o; o >>= 1) {
            if (t < o) red[t] += red[t + o];
            __syncthreads();
        }
        return red[0];
    };
    float rg = bred(pg);
    float rv = bred(pv);
    float r0 = bred(pt0);
    float r1 = bred(pt1);
    float r2 = bred(pt2);
    float r3 = bred(pt3);
    if (t == 0) {
        gdot[b] = rg;
        out_tail[32 + b] = rv + bcrit[0];
        out_tail[b * 4 + 0] = r0 + btype[0];
        out_tail[b * 4 + 1] = r1 + btype[1];
        out_tail[b * 4 + 2] = r2 + btype[2];
        out_tail[b * 4 + 3] = r3 + btype[3];
    }
}

// node_scores: one wave per node (bf16 x_nodes)
__global__ __launch_bounds__(256) void node_scores_kernel(const u16* __restrict__ xn,
                                                          const float* __restrict__ Wnode, const float* __restrict__ bnode,
                                                          const int* __restrict__ batch, const float* __restrict__ gdot,
                                                          float* __restrict__ out, int N) {
    int w = (blockIdx.x * 256 + threadIdx.x) >> 6;
    int lane = threadIdx.x & 63;
    if (w >= N) return;
    ushort4 xv = ((const ushort4*)(xn + (size_t)w * 256))[lane];
    float4 wv = ((const float4*)Wnode)[lane];
    float p = bf2f(xv.x) * wv.x + bf2f(xv.y) * wv.y + bf2f(xv.z) * wv.z + bf2f(xv.w) * wv.w;
    for (int o = 32; o; o >>= 1) p += __shfl_xor(p, o);
    if (lane == 0) out[w] = p + gdot[batch[w]] + bnode[0];
}

extern "C" void kernel_launch(void* const* d_in, const int* in_sizes, int n_in,
                              void* d_out, int out_size, void* d_ws, size_t ws_size,
                              hipStream_t stream) {
    const float* x = (const float*)d_in[0];
    const int* ei = (const int*)d_in[1];
    const int* batch = (const int*)d_in[2];
    const int* tgt = (const int*)d_in[3];
    const float* W1 = (const float*)d_in[4];
    const float* a1s = (const float*)d_in[5];
    const float* a1d = (const float*)d_in[6];
    // b1 (d_in[7]) / b2 (d_in[11]): constant column shifts cancel exactly in BatchNorm
    const float* W2 = (const float*)d_in[8];
    const float* a2s = (const float*)d_in[9];
    const float* a2d = (const float*)d_in[10];
    const float* g1 = (const float*)d_in[12];
    const float* be1 = (const float*)d_in[13];
    const float* g2 = (const float*)d_in[14];
    const float* be2 = (const float*)d_in[15];
    const float* Wsh = (const float*)d_in[16];
    const float* bsh = (const float*)d_in[17];
    const float* Wnode = (const float*)d_in[18];
    const float* bnode = (const float*)d_in[19];
    const float* Wtype = (const float*)d_in[20];
    const float* btype = (const float*)d_in[21];
    const float* Wcrit = (const float*)d_in[22];
    const float* bcrit = (const float*)d_in[23];

    const int N = in_sizes[2];
    const int E = in_sizes[1] / 2;
    const int Et = E + N;
    const int nb = (N + 255) / 256;   // scan blocks

    // ---- workspace carve (~119 MB) ----
    char* w = (char*)d_ws;
    size_t off = 0;
    auto carve = [&](size_t bytes) -> char* {
        char* p = w + off;
        off = (off + bytes + 255) & ~(size_t)255;
        return p;
    };
    float* aggF = (float*)carve((size_t)N * 256 * 4);  // f32 aggregation (both layers)
    u16* h_bf = (u16*)carve((size_t)N * 256 * 2);      // h1 -> h2 (gemm outputs)
    u16* y_bf = (u16*)carve((size_t)N * 256 * 2);      // y1 (bn1 out) -> x_nodes
    u16* x_bf = (u16*)carve((size_t)N * 64 * 2);       // x in bf16
    u16* W1p = (u16*)carve(16 * 2 * 512 * 2);          // packed W1 frags
    u16* W2p = (u16*)carve(16 * 8 * 512 * 2);          // packed W2 frags
    float* alpha = (float*)carve((size_t)Et * 4 * 4);
    float* al1s = (float*)carve((size_t)N * 4 * 4);
    float* al1d = (float*)carve((size_t)N * 4 * 4);
    float* al2s = (float*)carve((size_t)N * 4);
    float* al2d = (float*)carve((size_t)N * 4);
    int* offs = (int*)carve((size_t)(N + 1) * 4);
    int* cursor = (int*)carve((size_t)N * 4);
    int* csr = (int*)carve((size_t)Et * 4);
    int* excl = (int*)carve((size_t)N * 4);
    int* bsum = (int*)carve((size_t)nb * 4);
    int* bbase = (int*)carve((size_t)nb * 4);
    int* stotal = (int*)carve(64);
    float* gdot = (float*)carve(64);
    char* zero0 = w + off;
    int* counts = (int*)carve((size_t)N * 4);
    float* bn1s = (float*)carve(1024);
    float* bn1q = (float*)carve(1024);
    float* bn2s = (float*)carve(1024);
    float* bn2q = (float*)carve(1024);
    float* pools = (float*)carve(8 * 256 * 4);
    int* cnt = (int*)carve(64);
    size_t zbytes = (size_t)((w + off) - zero0);
    hipMemsetAsync(zero0, 0, zbytes, stream);

    int wavesPerGrid = (N + 3) / 4;                 // 4 node-waves per 256-thread block
    int mfmaGrid = (((N + 15) / 16) + 3) / 4;       // 4 row-tiles (waves) per block

    // ---- CSR build (3-phase parallel scan) + dtype prep ----
    hist_kernel<<<(Et + 255) / 256, 256, 0, stream>>>(ei, E, N, counts);
    scan_p1<<<nb, 256, 0, stream>>>(counts, N, excl, bsum);
    scan_p2<<<1, 256, 0, stream>>>(bsum, nb, bbase, stotal);
    scan_p3<<<nb, 256, 0, stream>>>(excl, bbase, stotal, N, offs, cursor);
    scatter_kernel<<<(Et + 255) / 256, 256, 0, stream>>>(ei, E, N, cursor, csr);
    cvt_bf16_kernel<<<(N * 16 + 255) / 256, 256, 0, stream>>>(x, x_bf, N * 16);
    packW_kernel<<<(16 * 2 * 512 + 255) / 256, 256, 0, stream>>>(W1, 2, W1p);
    packW_kernel<<<(16 * 8 * 512 + 255) / 256, 256, 0, stream>>>(W2, 8, W2p);

    // ---- layer 1: GAT(4 heads) + BN + ReLU ----
    gemm_mfma<64, 4><<<mfmaGrid, 256, 0, stream>>>(x_bf, W1p, h_bf, a1s, a1d, al1s, al1d, N);
    gat_softmax_kernel<4><<<wavesPerGrid, 256, 0, stream>>>(offs, csr, al1s, al1d, alpha, N);
    gat_accum_kernel<4><<<wavesPerGrid, 256, 0, stream>>>(offs, csr, alpha, h_bf, aggF, N);
    bn_stats<<<1024, 256, 0, stream>>>(aggF, N, bn1s, bn1q);
    bn_apply_relu<<<2048, 256, 0, stream>>>(aggF, bn1s, bn1q, g1, be1, y_bf, N);

    // ---- layer 2: GAT(1 head) + BN + ReLU + pool ----
    gemm_mfma<256, 1><<<mfmaGrid, 256, 0, stream>>>(y_bf, W2p, h_bf, a2s, a2d, al2s, al2d, N);
    gat_softmax_kernel<1><<<wavesPerGrid, 256, 0, stream>>>(offs, csr, al2s, al2d, alpha, N);
    gat_accum_kernel<1><<<wavesPerGrid, 256, 0, stream>>>(offs, csr, alpha, h_bf, aggF, N);
    bn_stats<<<1024, 256, 0, stream>>>(aggF, N, bn2s, bn2q);
    bn_apply_pool<<<1024, 256, 0, stream>>>(aggF, bn2s, bn2q, g2, be2, batch, y_bf, pools, cnt, N);

    // ---- heads ----
    shared_head_kernel<<<8, 256, 0, stream>>>(pools, cnt, Wsh, bsh, Wnode, Wcrit, bcrit,
                                              Wtype, btype, y_bf, tgt, gdot, (float*)d_out + N);
    node_scores_kernel<<<wavesPerGrid, 256, 0, stream>>>(y_bf, Wnode, bnode, batch, gdot,
                                                         (float*)d_out, N);
}

// Round 9
// 414.905 us; speedup vs baseline: 3.1415x; 1.0981x over previous
//
#include <hip/hip_runtime.h>

typedef unsigned short u16;
typedef __attribute__((ext_vector_type(8))) short bf16x8;   // 8 bf16 = 4 VGPRs
typedef __attribute__((ext_vector_type(4))) float f32x4;

__device__ __forceinline__ float bf2f(u16 u) {
    return __uint_as_float(((unsigned int)u) << 16);
}
__device__ __forceinline__ u16 f2bf(float f) {
    unsigned int u = __float_as_uint(f);
    u += 0x7fffu + ((u >> 16) & 1u);
    return (u16)(u >> 16);
}

// ---------------- CSR build (dst-indexed), reused by both GAT layers ----------
__global__ __launch_bounds__(256) void hist_kernel(const int* __restrict__ ei, int E, int N,
                                                   int* __restrict__ counts) {
    int i = blockIdx.x * 256 + threadIdx.x;
    if (i < E) atomicAdd(&counts[ei[E + i]], 1);
    else if (i < E + N) atomicAdd(&counts[i - E], 1);
}

// ---- 3-phase parallel exclusive scan over counts[N] -> offs[N+1], cursor[N] --
__global__ __launch_bounds__(256) void scan_p1(const int* __restrict__ counts, int N,
                                               int* __restrict__ excl, int* __restrict__ bsum) {
    __shared__ int tmp[256];
    int t = threadIdx.x, b = blockIdx.x, i = b * 256 + t;
    int v = (i < N) ? counts[i] : 0;
    tmp[t] = v;
    __syncthreads();
    for (int o = 1; o < 256; o <<= 1) {
        int u = (t >= o) ? tmp[t - o] : 0;
        __syncthreads();
        tmp[t] += u;
        __syncthreads();
    }
    if (i < N) excl[i] = tmp[t] - v;
    if (t == 255) bsum[b] = tmp[255];
}

__global__ __launch_bounds__(256) void scan_p2(const int* __restrict__ bsum, int nb,
                                               int* __restrict__ bbase, int* __restrict__ total) {
    __shared__ int tmp[256];
    int t = threadIdx.x;
    int run = 0;
    for (int base = 0; base < nb; base += 256) {
        int idx = base + t;
        int v = (idx < nb) ? bsum[idx] : 0;
        tmp[t] = v;
        __syncthreads();
        for (int o = 1; o < 256; o <<= 1) {
            int u = (t >= o) ? tmp[t - o] : 0;
            __syncthreads();
            tmp[t] += u;
            __syncthreads();
        }
        if (idx < nb) bbase[idx] = run + tmp[t] - v;
        run += tmp[255];
        __syncthreads();
    }
    if (t == 0) *total = run;
}

__global__ __launch_bounds__(256) void scan_p3(const int* __restrict__ excl, const int* __restrict__ bbase,
                                               const int* __restrict__ total, int N,
                                               int* __restrict__ offs, int* __restrict__ cursor) {
    int t = threadIdx.x, b = blockIdx.x, i = b * 256 + t;
    if (i < N) {
        int o = excl[i] + bbase[b];
        offs[i] = o;
        cursor[i] = o;
    }
    if (i == 0) offs[N] = *total;
}

__global__ __launch_bounds__(256) void scatter_kernel(const int* __restrict__ ei, int E, int N,
                                                      int* __restrict__ cursor, int* __restrict__ csr) {
    int i = blockIdx.x * 256 + threadIdx.x;
    if (i < E) {
        int d = ei[E + i];
        int p = atomicAdd(&cursor[d], 1);
        csr[p] = ei[i];
    } else if (i < E + N) {
        int n = i - E;
        int p = atomicAdd(&cursor[n], 1);
        csr[p] = n;
    }
}

// ---------------- f32 -> bf16 convert (vectorized) ----------------------------
__global__ __launch_bounds__(256) void cvt_bf16_kernel(const float* __restrict__ in,
                                                       u16* __restrict__ out, int n4) {
    int i = blockIdx.x * 256 + threadIdx.x;
    if (i >= n4) return;
    float4 v = ((const float4*)in)[i];
    ushort4 o;
    o.x = f2bf(v.x); o.y = f2bf(v.y); o.z = f2bf(v.z); o.w = f2bf(v.w);
    ((ushort4*)out)[i] = o;
}

// ---------------- pack W [K,256] f32 into MFMA B-fragment order (bf16) --------
__global__ __launch_bounds__(256) void packW_kernel(const float* __restrict__ W, int KS,
                                                    u16* __restrict__ out) {
    int idx = blockIdx.x * 256 + threadIdx.x;
    int total = 16 * KS * 512;
    if (idx >= total) return;
    int j = idx & 7;
    int lane = (idx >> 3) & 63;
    int rest = idx >> 9;        // ct*KS + ks
    int ks = rest % KS;
    int ct = rest / KS;
    int k = ks * 32 + (lane >> 4) * 8 + j;
    int n = ct * 16 + (lane & 15);
    out[idx] = f2bf(W[k * 256 + n]);
}

// ---------------- MFMA GEMM (32 rows/wave) + fused attention-logit epilogue ---
// Two 16-row tiles per wave share each B fragment -> half the B traffic and
// 4 independent MFMA chains (2 tiles x 2 col-chunks). Epilogue: LDS transpose
// -> coalesced bf16 store AND per-row al_s/al_d dot products.
template <int K, int H>
__global__ __launch_bounds__(256) void gemm_mfma(const u16* __restrict__ A,
                                                 const u16* __restrict__ Bp,
                                                 u16* __restrict__ O,
                                                 const float* __restrict__ as_,
                                                 const float* __restrict__ ad_,
                                                 float* __restrict__ als,
                                                 float* __restrict__ ald, int Nrows) {
    constexpr int KS = K / 32;
    __shared__ u16 lds[4][32 * 256];   // 64 KB/block
    int wave = threadIdx.x >> 6, lane = threadIdx.x & 63;
    int tile = blockIdx.x * 4 + wave;
    int row0 = tile * 32;
    if (row0 >= Nrows) return;
    int m = lane & 15, q = lane >> 4;

    bf16x8 af0[KS], af1[KS];
    const u16* ar0 = A + (size_t)(row0 + m) * K + q * 8;
    const u16* ar1 = A + (size_t)(row0 + 16 + m) * K + q * 8;  // tail OOB-read stays in ws
#pragma unroll
    for (int ks = 0; ks < KS; ks++) {
        af0[ks] = *(const bf16x8*)(ar0 + ks * 32);
        af1[ks] = *(const bf16x8*)(ar1 + ks * 32);
    }

    u16* myl = lds[wave];
#pragma unroll
    for (int ct2 = 0; ct2 < 8; ct2++) {
        int ct0 = ct2 * 2;
        f32x4 a00 = {0.f, 0.f, 0.f, 0.f}, a01 = {0.f, 0.f, 0.f, 0.f};
        f32x4 a10 = {0.f, 0.f, 0.f, 0.f}, a11 = {0.f, 0.f, 0.f, 0.f};
        const u16* bp0 = Bp + ((size_t)(ct0 * KS) * 64 + lane) * 8;
        const u16* bp1 = bp0 + (size_t)KS * 512;
#pragma unroll
        for (int ks = 0; ks < KS; ks++) {   // 4 independent chains per B pair
            bf16x8 b0 = *(const bf16x8*)(bp0 + (size_t)ks * 512);
            bf16x8 b1 = *(const bf16x8*)(bp1 + (size_t)ks * 512);
            a00 = __builtin_amdgcn_mfma_f32_16x16x32_bf16(af0[ks], b0, a00, 0, 0, 0);
            a01 = __builtin_amdgcn_mfma_f32_16x16x32_bf16(af0[ks], b1, a01, 0, 0, 0);
            a10 = __builtin_amdgcn_mfma_f32_16x16x32_bf16(af1[ks], b0, a10, 0, 0, 0);
            a11 = __builtin_amdgcn_mfma_f32_16x16x32_bf16(af1[ks], b1, a11, 0, 0, 0);
        }
        // C/D layout: col = lane&15, row = (lane>>4)*4 + r   [verified m89]
#pragma unroll
        for (int r = 0; r < 4; r++) {
            myl[(q * 4 + r) * 256 + ct0 * 16 + m] = f2bf(a00[r]);
            myl[(q * 4 + r) * 256 + ct0 * 16 + 16 + m] = f2bf(a01[r]);
            myl[(16 + q * 4 + r) * 256 + ct0 * 16 + m] = f2bf(a10[r]);
            myl[(16 + q * 4 + r) * 256 + ct0 * 16 + 16 + m] = f2bf(a11[r]);
        }
    }
    // epilogue: coalesced store + al dot (same-wave LDS, no barrier needed)
    int c8 = (lane & 31) * 8;
    float4 s0 = *(const float4*)(as_ + c8);
    float4 s1 = *(const float4*)(as_ + c8 + 4);
    float4 d0 = *(const float4*)(ad_ + c8);
    float4 d1 = *(const float4*)(ad_ + c8 + 4);
#pragma unroll
    for (int p = 0; p < 16; p++) {
        int row = p * 2 + (lane >> 5);
        if (row0 + row >= Nrows) continue;
        int4 v = *(const int4*)&myl[row * 256 + c8];
        *(int4*)&O[(size_t)(row0 + row) * 256 + c8] = v;
        float f0 = bf2f((u16)(v.x & 0xffff)), f1 = bf2f((u16)((unsigned)v.x >> 16));
        float f2 = bf2f((u16)(v.y & 0xffff)), f3 = bf2f((u16)((unsigned)v.y >> 16));
        float f4 = bf2f((u16)(v.z & 0xffff)), f5 = bf2f((u16)((unsigned)v.z >> 16));
        float f6 = bf2f((u16)(v.w & 0xffff)), f7 = bf2f((u16)((unsigned)v.w >> 16));
        float ps = f0 * s0.x + f1 * s0.y + f2 * s0.z + f3 * s0.w +
                   f4 * s1.x + f5 * s1.y + f6 * s1.z + f7 * s1.w;
        float pd = f0 * d0.x + f1 * d0.y + f2 * d0.z + f3 * d0.w +
                   f4 * d1.x + f5 * d1.y + f6 * d1.z + f7 * d1.w;
        const int W = (H == 4) ? 8 : 32;
#pragma unroll
        for (int o = 1; o < W; o <<= 1) {
            ps += __shfl_xor(ps, o);
            pd += __shfl_xor(pd, o);
        }
        if (H == 4) {
            if ((lane & 7) == 0) {
                int head = (lane & 31) >> 3;
                als[(row0 + row) * 4 + head] = ps;
                ald[(row0 + row) * 4 + head] = pd;
            }
        } else {
            if ((lane & 31) == 0) {
                als[row0 + row] = ps;
                ald[row0 + row] = pd;
            }
        }
    }
}

// ---------------- fused GAT softmax + accumulate (one wave per dst) -----------
// Lane-parallel softmax over the node's edges; per-edge alpha + src parked in
// per-wave LDS (same-wave DS write->read, in-order); then lanes cover the 256
// cols (4 each) in a 4-wide unrolled gather loop. Output bf16.
template <int H>
__global__ __launch_bounds__(256) void gat_fused_kernel(const int* __restrict__ offs,
                                                        const int* __restrict__ csr,
                                                        const float* __restrict__ als,
                                                        const float* __restrict__ ald,
                                                        const u16* __restrict__ h,
                                                        u16* __restrict__ out, int N) {
    __shared__ float lalpha[4][64 * H];
    __shared__ int lsrc[4][64];
    int wave = threadIdx.x >> 6, lane = threadIdx.x & 63;
    int w = (blockIdx.x * 256 + threadIdx.x) >> 6;
    if (w >= N) return;
    int s0 = offs[w], s1 = offs[w + 1];
    float adl[H], e0[H], m[H], den[H];
#pragma unroll
    for (int hh = 0; hh < H; hh++) { adl[hh] = ald[w * H + hh]; m[hh] = -1e30f; }
    int i0 = s0 + lane;
    bool have = (i0 < s1);
    int src0 = 0;
    if (have) {
        src0 = csr[i0];
        if (H == 4) {
            float4 av = ((const float4*)als)[src0];
            float tmp[4] = {av.x, av.y, av.z, av.w};
#pragma unroll
            for (int hh = 0; hh < 4; hh++) {
                float e = tmp[hh] + adl[hh];
                e = e > 0.f ? e : 0.2f * e;
                e0[hh] = e; m[hh] = e;
            }
        } else {
            float e = als[src0] + adl[0];
            e = e > 0.f ? e : 0.2f * e;
            e0[0] = e; m[0] = e;
        }
    }
    for (int i = i0 + 64; i < s1; i += 64) {  // rare: deg > 64
        int s = csr[i];
#pragma unroll
        for (int hh = 0; hh < H; hh++) {
            float e = als[s * H + hh] + adl[hh];
            e = e > 0.f ? e : 0.2f * e;
            m[hh] = fmaxf(m[hh], e);
        }
    }
#pragma unroll
    for (int hh = 0; hh < H; hh++)
        for (int o = 32; o; o >>= 1) m[hh] = fmaxf(m[hh], __shfl_xor(m[hh], o));
#pragma unroll
    for (int hh = 0; hh < H; hh++) den[hh] = have ? __expf(e0[hh] - m[hh]) : 0.f;
    for (int i = i0 + 64; i < s1; i += 64) {
        int s = csr[i];
#pragma unroll
        for (int hh = 0; hh < H; hh++) {
            float e = als[s * H + hh] + adl[hh];
            e = e > 0.f ? e : 0.2f * e;
            den[hh] += __expf(e - m[hh]);
        }
    }
#pragma unroll
    for (int hh = 0; hh < H; hh++)
        for (int o = 32; o; o >>= 1) den[hh] += __shfl_xor(den[hh], o);
    float rden[H];
#pragma unroll
    for (int hh = 0; hh < H; hh++) rden[hh] = 1.f / (den[hh] + 1e-16f);
    // park chunk-0 alpha/src in per-wave LDS (same-wave write->read, in order)
    if (have) {
        lsrc[wave][lane] = src0;
#pragma unroll
        for (int hh = 0; hh < H; hh++)
            lalpha[wave][lane * H + hh] = __expf(e0[hh] - m[hh]) * rden[hh];
    }
    int deg = s1 - s0;
    int cend = min(deg, 64);
    int myh = (H == 4) ? (lane >> 4) : 0;
    const ushort4* h4 = (const ushort4*)h;
    const float* la = lalpha[wave];
    const int* ls = lsrc[wave];
    float4 acc = make_float4(0.f, 0.f, 0.f, 0.f);
    int i = 0;
    for (; i + 4 <= cend; i += 4) {
        int sa = ls[i], sb = ls[i + 1], sc = ls[i + 2], sd = ls[i + 3];
        float aa = la[i * H + myh];
        float ab = la[(i + 1) * H + myh];
        float ac = la[(i + 2) * H + myh];
        float ad = la[(i + 3) * H + myh];
        ushort4 ha = h4[(size_t)sa * 64 + lane];
        ushort4 hb = h4[(size_t)sb * 64 + lane];
        ushort4 hc = h4[(size_t)sc * 64 + lane];
        ushort4 hd = h4[(size_t)sd * 64 + lane];
        acc.x = fmaf(aa, bf2f(ha.x), acc.x); acc.y = fmaf(aa, bf2f(ha.y), acc.y);
        acc.z = fmaf(aa, bf2f(ha.z), acc.z); acc.w = fmaf(aa, bf2f(ha.w), acc.w);
        acc.x = fmaf(ab, bf2f(hb.x), acc.x); acc.y = fmaf(ab, bf2f(hb.y), acc.y);
        acc.z = fmaf(ab, bf2f(hb.z), acc.z); acc.w = fmaf(ab, bf2f(hb.w), acc.w);
        acc.x = fmaf(ac, bf2f(hc.x), acc.x); acc.y = fmaf(ac, bf2f(hc.y), acc.y);
        acc.z = fmaf(ac, bf2f(hc.z), acc.z); acc.w = fmaf(ac, bf2f(hc.w), acc.w);
        acc.x = fmaf(ad, bf2f(hd.x), acc.x); acc.y = fmaf(ad, bf2f(hd.y), acc.y);
        acc.z = fmaf(ad, bf2f(hd.z), acc.z); acc.w = fmaf(ad, bf2f(hd.w), acc.w);
    }
    for (; i < cend; i++) {
        int s = ls[i];
        float a = la[i * H + myh];
        ushort4 hv = h4[(size_t)s * 64 + lane];
        acc.x = fmaf(a, bf2f(hv.x), acc.x); acc.y = fmaf(a, bf2f(hv.y), acc.y);
        acc.z = fmaf(a, bf2f(hv.z), acc.z); acc.w = fmaf(a, bf2f(hv.w), acc.w);
    }
    for (int j = s0 + 64; j < s1; j++) {  // rare deg>64 tail: recompute alpha
        int s = csr[j];
        float e = als[s * H + myh] + adl[myh];
        e = e > 0.f ? e : 0.2f * e;
        float a = __expf(e - m[myh]) * rden[myh];
        ushort4 hv = h4[(size_t)s * 64 + lane];
        acc.x = fmaf(a, bf2f(hv.x), acc.x); acc.y = fmaf(a, bf2f(hv.y), acc.y);
        acc.z = fmaf(a, bf2f(hv.z), acc.z); acc.w = fmaf(a, bf2f(hv.w), acc.w);
    }
    ushort4 o;
    o.x = f2bf(acc.x); o.y = f2bf(acc.y); o.z = f2bf(acc.z); o.w = f2bf(acc.w);
    ((ushort4*)out)[(size_t)w * 64 + lane] = o;
}

// ---------------- BatchNorm stats (bf16 input; register acc) ------------------
__global__ __launch_bounds__(256) void bn_stats(const u16* __restrict__ agg, int N,
                                                float* __restrict__ sum, float* __restrict__ sq) {
    int t = threadIdx.x;
    int rows = (N + gridDim.x - 1) / gridDim.x;
    int r0 = blockIdx.x * rows, r1 = min(r0 + rows, N);
    if (r0 >= r1) return;
    float s = 0.f, q = 0.f;
    for (int r = r0; r < r1; r++) {
        float v = bf2f(agg[(size_t)r * 256 + t]);
        s += v;
        q = fmaf(v, v, q);
    }
    atomicAdd(&sum[t], s);
    atomicAdd(&sq[t], q);
}

// bn scale/shift folded; bf16 -> bf16 + relu (layer 1)
__global__ __launch_bounds__(256) void bn_apply_relu(const u16* __restrict__ agg,
                                                     const float* __restrict__ sum,
                                                     const float* __restrict__ sq,
                                                     const float* __restrict__ g,
                                                     const float* __restrict__ be,
                                                     u16* __restrict__ out, int N) {
    __shared__ float sc_s[256], sh_s[256];
    int t = threadIdx.x;
    float inv = 1.f / (float)N;
    float mm = sum[t] * inv;
    float vv = fmaxf(sq[t] * inv - mm * mm, 0.f);
    float sc = rsqrtf(vv + 1e-5f) * g[t];
    sc_s[t] = sc;
    sh_s[t] = be[t] - mm * sc;
    __syncthreads();
    int total = N * 64;
    for (int i = blockIdx.x * 256 + t; i < total; i += gridDim.x * 256) {
        ushort4 v = ((const ushort4*)agg)[i];
        int c4 = i & 63;
        float4 scv = ((const float4*)sc_s)[c4];
        float4 shv = ((const float4*)sh_s)[c4];
        ushort4 o;
        o.x = f2bf(fmaxf(fmaf(bf2f(v.x), scv.x, shv.x), 0.f));
        o.y = f2bf(fmaxf(fmaf(bf2f(v.y), scv.y, shv.y), 0.f));
        o.z = f2bf(fmaxf(fmaf(bf2f(v.z), scv.z, shv.z), 0.f));
        o.w = f2bf(fmaxf(fmaf(bf2f(v.w), scv.w, shv.w), 0.f));
        ((ushort4*)out)[i] = o;
    }
}

// layer 2: bn-apply + relu + fused global-mean-pool (batch sorted)
__global__ __launch_bounds__(256) void bn_apply_pool(const u16* __restrict__ agg,
                                                     const float* __restrict__ sum,
                                                     const float* __restrict__ sq,
                                                     const float* __restrict__ g,
                                                     const float* __restrict__ be,
                                                     const int* __restrict__ batch,
                                                     u16* __restrict__ out,
                                                     float* __restrict__ pools,
                                                     int* __restrict__ cnt, int N) {
    int t = threadIdx.x;
    float inv = 1.f / (float)N;
    float mm = sum[t] * inv;
    float vv = fmaxf(sq[t] * inv - mm * mm, 0.f);
    float sc = rsqrtf(vv + 1e-5f) * g[t];
    float sh = be[t] - mm * sc;
    int rows = (N + gridDim.x - 1) / gridDim.x;
    int r0 = blockIdx.x * rows, r1 = min(r0 + rows, N);
    if (r0 >= r1) return;
    float acc = 0.f;
    int cur = batch[r0], c0 = 0;
    for (int r = r0; r < r1; r++) {
        int b = batch[r];  // wave-uniform scalar load
        if (b != cur) {
            atomicAdd(&pools[cur * 256 + t], acc);
            if (t == 0) atomicAdd(&cnt[cur], c0);
            acc = 0.f; c0 = 0; cur = b;
        }
        float v = bf2f(agg[(size_t)r * 256 + t]);
        float y = fmaxf(fmaf(v, sc, sh), 0.f);
        out[(size_t)r * 256 + t] = f2bf(y);
        acc += y; c0++;
    }
    atomicAdd(&pools[cur * 256 + t], acc);
    if (t == 0) atomicAdd(&cnt[cur], c0);
}

// shared = relu(gf @ W_sh + b_sh) fused with heads; one block per graph
__global__ __launch_bounds__(256) void shared_head_kernel(const float* __restrict__ pools,
                                                          const int* __restrict__ cnt,
                                                          const float* __restrict__ Wsh,
                                                          const float* __restrict__ bsh,
                                                          const float* __restrict__ Wnode,
                                                          const float* __restrict__ Wcrit,
                                                          const float* __restrict__ bcrit,
                                                          const float* __restrict__ Wtype,
                                                          const float* __restrict__ btype,
                                                          const u16* __restrict__ xn,
                                                          const int* __restrict__ tgt,
                                                          float* __restrict__ gdot,
                                                          float* __restrict__ out_tail) {
    __shared__ float gf[256], red[256];
    int b = blockIdx.x, t = threadIdx.x;
    gf[t] = pools[b * 256 + t] / fmaxf((float)cnt[b], 1.f);
    __syncthreads();
    float acc = bsh[t];
    for (int k = 0; k < 256; k++) acc = fmaf(gf[k], Wsh[k * 256 + t], acc);
    float s = fmaxf(acc, 0.f);
    int tn = tgt[b];
    float xnt = bf2f(xn[(size_t)tn * 256 + t]);
    float pg = s * Wnode[256 + t];
    float pv = s * Wcrit[t];
    float pt0 = s * Wtype[t * 4 + 0] + xnt * Wtype[(256 + t) * 4 + 0];
    float pt1 = s * Wtype[t * 4 + 1] + xnt * Wtype[(256 + t) * 4 + 1];
    float pt2 = s * Wtype[t * 4 + 2] + xnt * Wtype[(256 + t) * 4 + 2];
    float pt3 = s * Wtype[t * 4 + 3] + xnt * Wtype[(256 + t) * 4 + 3];
    auto bred = [&](float v) -> float {
        __syncthreads();
        red[t] = v;
        __syncthreads();
        for (int o = 128; o; o >>= 1) {
            if (t < o) red[t] += red[t + o];
            __syncthreads();
        }
        return red[0];
    };
    float rg = bred(pg);
    float rv = bred(pv);
    float r0 = bred(pt0);
    float r1 = bred(pt1);
    float r2 = bred(pt2);
    float r3 = bred(pt3);
    if (t == 0) {
        gdot[b] = rg;
        out_tail[32 + b] = rv + bcrit[0];
        out_tail[b * 4 + 0] = r0 + btype[0];
        out_tail[b * 4 + 1] = r1 + btype[1];
        out_tail[b * 4 + 2] = r2 + btype[2];
        out_tail[b * 4 + 3] = r3 + btype[3];
    }
}

// node_scores: one wave per node (bf16 x_nodes)
__global__ __launch_bounds__(256) void node_scores_kernel(const u16* __restrict__ xn,
                                                          const float* __restrict__ Wnode, const float* __restrict__ bnode,
                                                          const int* __restrict__ batch, const float* __restrict__ gdot,
                                                          float* __restrict__ out, int N) {
    int w = (blockIdx.x * 256 + threadIdx.x) >> 6;
    int lane = threadIdx.x & 63;
    if (w >= N) return;
    ushort4 xv = ((const ushort4*)(xn + (size_t)w * 256))[lane];
    float4 wv = ((const float4*)Wnode)[lane];
    float p = bf2f(xv.x) * wv.x + bf2f(xv.y) * wv.y + bf2f(xv.z) * wv.z + bf2f(xv.w) * wv.w;
    for (int o = 32; o; o >>= 1) p += __shfl_xor(p, o);
    if (lane == 0) out[w] = p + gdot[batch[w]] + bnode[0];
}

extern "C" void kernel_launch(void* const* d_in, const int* in_sizes, int n_in,
                              void* d_out, int out_size, void* d_ws, size_t ws_size,
                              hipStream_t stream) {
    const float* x = (const float*)d_in[0];
    const int* ei = (const int*)d_in[1];
    const int* batch = (const int*)d_in[2];
    const int* tgt = (const int*)d_in[3];
    const float* W1 = (const float*)d_in[4];
    const float* a1s = (const float*)d_in[5];
    const float* a1d = (const float*)d_in[6];
    // b1 (d_in[7]) / b2 (d_in[11]): constant column shifts cancel exactly in BatchNorm
    const float* W2 = (const float*)d_in[8];
    const float* a2s = (const float*)d_in[9];
    const float* a2d = (const float*)d_in[10];
    const float* g1 = (const float*)d_in[12];
    const float* be1 = (const float*)d_in[13];
    const float* g2 = (const float*)d_in[14];
    const float* be2 = (const float*)d_in[15];
    const float* Wsh = (const float*)d_in[16];
    const float* bsh = (const float*)d_in[17];
    const float* Wnode = (const float*)d_in[18];
    const float* bnode = (const float*)d_in[19];
    const float* Wtype = (const float*)d_in[20];
    const float* btype = (const float*)d_in[21];
    const float* Wcrit = (const float*)d_in[22];
    const float* bcrit = (const float*)d_in[23];

    const int N = in_sizes[2];
    const int E = in_sizes[1] / 2;
    const int Et = E + N;
    const int nb = (N + 255) / 256;   // scan blocks

    // ---- workspace carve (~90 MB) ----
    char* w = (char*)d_ws;
    size_t off = 0;
    auto carve = [&](size_t bytes) -> char* {
        char* p = w + off;
        off = (off + bytes + 255) & ~(size_t)255;
        return p;
    };
    u16* agg_bf = (u16*)carve((size_t)N * 256 * 2);    // bf16 aggregation (both layers)
    u16* h_bf = (u16*)carve((size_t)N * 256 * 2);      // h1 -> h2 (gemm outputs)
    u16* y_bf = (u16*)carve((size_t)N * 256 * 2);      // y1 (bn1 out) -> x_nodes
    u16* x_bf = (u16*)carve((size_t)N * 64 * 2);       // x in bf16
    u16* W1p = (u16*)carve(16 * 2 * 512 * 2);          // packed W1 frags
    u16* W2p = (u16*)carve(16 * 8 * 512 * 2);          // packed W2 frags
    float* al1s = (float*)carve((size_t)N * 4 * 4);
    float* al1d = (float*)carve((size_t)N * 4 * 4);
    float* al2s = (float*)carve((size_t)N * 4);
    float* al2d = (float*)carve((size_t)N * 4);
    int* offs = (int*)carve((size_t)(N + 1) * 4);
    int* cursor = (int*)carve((size_t)N * 4);
    int* csr = (int*)carve((size_t)Et * 4);
    int* excl = (int*)carve((size_t)N * 4);
    int* bsum = (int*)carve((size_t)nb * 4);
    int* bbase = (int*)carve((size_t)nb * 4);
    int* stotal = (int*)carve(64);
    float* gdot = (float*)carve(64);
    char* zero0 = w + off;
    int* counts = (int*)carve((size_t)N * 4);
    float* bn1s = (float*)carve(1024);
    float* bn1q = (float*)carve(1024);
    float* bn2s = (float*)carve(1024);
    float* bn2q = (float*)carve(1024);
    float* pools = (float*)carve(8 * 256 * 4);
    int* cnt = (int*)carve(64);
    size_t zbytes = (size_t)((w + off) - zero0);
    hipMemsetAsync(zero0, 0, zbytes, stream);

    int wavesPerGrid = (N + 3) / 4;                  // 4 node-waves per 256-thread block
    int mfmaGrid = (((N + 31) / 32) + 3) / 4;        // 4 32-row tiles (waves) per block

    // ---- CSR build (3-phase parallel scan) + dtype prep ----
    hist_kernel<<<(Et + 255) / 256, 256, 0, stream>>>(ei, E, N, counts);
    scan_p1<<<nb, 256, 0, stream>>>(counts, N, excl, bsum);
    scan_p2<<<1, 256, 0, stream>>>(bsum, nb, bbase, stotal);
    scan_p3<<<nb, 256, 0, stream>>>(excl, bbase, stotal, N, offs, cursor);
    scatter_kernel<<<(Et + 255) / 256, 256, 0, stream>>>(ei, E, N, cursor, csr);
    cvt_bf16_kernel<<<(N * 16 + 255) / 256, 256, 0, stream>>>(x, x_bf, N * 16);
    packW_kernel<<<(16 * 2 * 512 + 255) / 256, 256, 0, stream>>>(W1, 2, W1p);
    packW_kernel<<<(16 * 8 * 512 + 255) / 256, 256, 0, stream>>>(W2, 8, W2p);

    // ---- layer 1: GAT(4 heads) + BN + ReLU ----
    gemm_mfma<64, 4><<<mfmaGrid, 256, 0, stream>>>(x_bf, W1p, h_bf, a1s, a1d, al1s, al1d, N);
    gat_fused_kernel<4><<<wavesPerGrid, 256, 0, stream>>>(offs, csr, al1s, al1d, h_bf, agg_bf, N);
    bn_stats<<<1024, 256, 0, stream>>>(agg_bf, N, bn1s, bn1q);
    bn_apply_relu<<<2048, 256, 0, stream>>>(agg_bf, bn1s, bn1q, g1, be1, y_bf, N);

    // ---- layer 2: GAT(1 head) + BN + ReLU + pool ----
    gemm_mfma<256, 1><<<mfmaGrid, 256, 0, stream>>>(y_bf, W2p, h_bf, a2s, a2d, al2s, al2d, N);
    gat_fused_kernel<1><<<wavesPerGrid, 256, 0, stream>>>(offs, csr, al2s, al2d, h_bf, agg_bf, N);
    bn_stats<<<1024, 256, 0, stream>>>(agg_bf, N, bn2s, bn2q);
    bn_apply_pool<<<1024, 256, 0, stream>>>(agg_bf, bn2s, bn2q, g2, be2, batch, y_bf, pools, cnt, N);

    // ---- heads ----
    shared_head_kernel<<<8, 256, 0, stream>>>(pools, cnt, Wsh, bsh, Wnode, Wcrit, bcrit,
                                              Wtype, btype, y_bf, tgt, gdot, (float*)d_out + N);
    node_scores_kernel<<<wavesPerGrid, 256, 0, stream>>>(y_bf, Wnode, bnode, batch, gdot,
                                                         (float*)d_out, N);
}

// Round 10
// 410.858 us; speedup vs baseline: 3.1724x; 1.0099x over previous
//
#include <hip/hip_runtime.h>

typedef unsigned short u16;
typedef __attribute__((ext_vector_type(8))) short bf16x8;   // 8 bf16 = 4 VGPRs
typedef __attribute__((ext_vector_type(4))) float f32x4;

__device__ __forceinline__ float bf2f(u16 u) {
    return __uint_as_float(((unsigned int)u) << 16);
}
__device__ __forceinline__ u16 f2bf(float f) {
    unsigned int u = __float_as_uint(f);
    u += 0x7fffu + ((u >> 16) & 1u);
    return (u16)(u >> 16);
}
__device__ __forceinline__ bf16x8 pack8(float4 a, float4 b) {
    bf16x8 r;
    r[0] = (short)f2bf(a.x); r[1] = (short)f2bf(a.y);
    r[2] = (short)f2bf(a.z); r[3] = (short)f2bf(a.w);
    r[4] = (short)f2bf(b.x); r[5] = (short)f2bf(b.y);
    r[6] = (short)f2bf(b.z); r[7] = (short)f2bf(b.w);
    return r;
}

// ---------------- CSR build (dst-indexed), reused by both GAT layers ----------
__global__ __launch_bounds__(256) void hist_kernel(const int* __restrict__ ei, int E, int N,
                                                   int* __restrict__ counts) {
    int i = blockIdx.x * 256 + threadIdx.x;
    if (i < E) atomicAdd(&counts[ei[E + i]], 1);
    else if (i < E + N) atomicAdd(&counts[i - E], 1);
}

// ---- 3-phase parallel exclusive scan over counts[N] -> offs[N+1], cursor[N] --
__global__ __launch_bounds__(256) void scan_p1(const int* __restrict__ counts, int N,
                                               int* __restrict__ excl, int* __restrict__ bsum) {
    __shared__ int tmp[256];
    int t = threadIdx.x, b = blockIdx.x, i = b * 256 + t;
    int v = (i < N) ? counts[i] : 0;
    tmp[t] = v;
    __syncthreads();
    for (int o = 1; o < 256; o <<= 1) {
        int u = (t >= o) ? tmp[t - o] : 0;
        __syncthreads();
        tmp[t] += u;
        __syncthreads();
    }
    if (i < N) excl[i] = tmp[t] - v;
    if (t == 255) bsum[b] = tmp[255];
}

__global__ __launch_bounds__(256) void scan_p2(const int* __restrict__ bsum, int nb,
                                               int* __restrict__ bbase, int* __restrict__ total) {
    __shared__ int tmp[256];
    int t = threadIdx.x;
    int run = 0;
    for (int base = 0; base < nb; base += 256) {
        int idx = base + t;
        int v = (idx < nb) ? bsum[idx] : 0;
        tmp[t] = v;
        __syncthreads();
        for (int o = 1; o < 256; o <<= 1) {
            int u = (t >= o) ? tmp[t - o] : 0;
            __syncthreads();
            tmp[t] += u;
            __syncthreads();
        }
        if (idx < nb) bbase[idx] = run + tmp[t] - v;
        run += tmp[255];
        __syncthreads();
    }
    if (t == 0) *total = run;
}

__global__ __launch_bounds__(256) void scan_p3(const int* __restrict__ excl, const int* __restrict__ bbase,
                                               const int* __restrict__ total, int N,
                                               int* __restrict__ offs, int* __restrict__ cursor) {
    int t = threadIdx.x, b = blockIdx.x, i = b * 256 + t;
    if (i < N) {
        int o = excl[i] + bbase[b];
        offs[i] = o;
        cursor[i] = o;
    }
    if (i == 0) offs[N] = *total;
}

__global__ __launch_bounds__(256) void scatter_kernel(const int* __restrict__ ei, int E, int N,
                                                      int* __restrict__ cursor, int* __restrict__ csr) {
    int i = blockIdx.x * 256 + threadIdx.x;
    if (i < E) {
        int d = ei[E + i];
        int p = atomicAdd(&cursor[d], 1);
        csr[p] = ei[i];
    } else if (i < E + N) {
        int n = i - E;
        int p = atomicAdd(&cursor[n], 1);
        csr[p] = n;
    }
}

// ---------------- pack W [K,256] f32 into MFMA B-fragment order (bf16) --------
__global__ __launch_bounds__(256) void packW_kernel(const float* __restrict__ W, int KS,
                                                    u16* __restrict__ out) {
    int idx = blockIdx.x * 256 + threadIdx.x;
    int total = 16 * KS * 512;
    if (idx >= total) return;
    int j = idx & 7;
    int lane = (idx >> 3) & 63;
    int rest = idx >> 9;        // ct*KS + ks
    int ks = rest % KS;
    int ct = rest / KS;
    int k = ks * 32 + (lane >> 4) * 8 + j;
    int n = ct * 16 + (lane & 15);
    out[idx] = f2bf(W[k * 256 + n]);
}

// ---------------- MFMA GEMM (32 rows/wave) + fused epilogue --------------------
// MODE 0: A = raw f32 [N,K] (layer 1 input x; converts to bf16 in-register)
// MODE 1: A = bf16 agg [N,256] with fused bn1-apply + relu (y1 never hits HBM)
// Epilogue: LDS transpose -> coalesced bf16 store + per-row al_s/al_d dots.
template <int K, int H, int MODE>
__global__ __launch_bounds__(256) void gemm_mfma(const void* __restrict__ Ain,
                                                 const u16* __restrict__ Bp,
                                                 u16* __restrict__ O,
                                                 const float* __restrict__ as_,
                                                 const float* __restrict__ ad_,
                                                 float* __restrict__ als,
                                                 float* __restrict__ ald,
                                                 const float* __restrict__ bsum,
                                                 const float* __restrict__ bsq,
                                                 const float* __restrict__ g,
                                                 const float* __restrict__ be,
                                                 int Nrows) {
    constexpr int KS = K / 32;
    __shared__ u16 lds[4][32 * 256];   // 64 KB/block
    __shared__ float sc_s[256], sh_s[256];
    if (MODE == 1) {  // bn1 scale/shift table (all threads reach the barrier)
        int t = threadIdx.x;
        float inv = 1.f / (float)Nrows;
        float mm = bsum[t] * inv;
        float vv = fmaxf(bsq[t] * inv - mm * mm, 0.f);
        float sc = rsqrtf(vv + 1e-5f) * g[t];
        sc_s[t] = sc;
        sh_s[t] = be[t] - mm * sc;
        __syncthreads();
    }
    int wave = threadIdx.x >> 6, lane = threadIdx.x & 63;
    int tile = blockIdx.x * 4 + wave;
    int row0 = tile * 32;
    if (row0 >= Nrows) return;
    int m = lane & 15, q = lane >> 4;
    int r0c = min(row0 + m, Nrows - 1);
    int r1c = min(row0 + 16 + m, Nrows - 1);

    bf16x8 af0[KS], af1[KS];
    if (MODE == 0) {
        const float* A = (const float*)Ain;
        const float* a0 = A + (size_t)r0c * K + q * 8;
        const float* a1 = A + (size_t)r1c * K + q * 8;
#pragma unroll
        for (int ks = 0; ks < KS; ks++) {
            af0[ks] = pack8(*(const float4*)(a0 + ks * 32), *(const float4*)(a0 + ks * 32 + 4));
            af1[ks] = pack8(*(const float4*)(a1 + ks * 32), *(const float4*)(a1 + ks * 32 + 4));
        }
    } else {
        const u16* A = (const u16*)Ain;
        const u16* a0 = A + (size_t)r0c * K + q * 8;
        const u16* a1 = A + (size_t)r1c * K + q * 8;
#pragma unroll
        for (int ks = 0; ks < KS; ks++) {
            int cb = ks * 32 + q * 8;
            float4 sc0 = *(const float4*)&sc_s[cb];
            float4 sc1 = *(const float4*)&sc_s[cb + 4];
            float4 sh0 = *(const float4*)&sh_s[cb];
            float4 sh1 = *(const float4*)&sh_s[cb + 4];
            ushort4 u0 = *(const ushort4*)(a0 + ks * 32);
            ushort4 u1 = *(const ushort4*)(a0 + ks * 32 + 4);
            float4 v0 = make_float4(fmaxf(fmaf(bf2f(u0.x), sc0.x, sh0.x), 0.f),
                                    fmaxf(fmaf(bf2f(u0.y), sc0.y, sh0.y), 0.f),
                                    fmaxf(fmaf(bf2f(u0.z), sc0.z, sh0.z), 0.f),
                                    fmaxf(fmaf(bf2f(u0.w), sc0.w, sh0.w), 0.f));
            float4 v1 = make_float4(fmaxf(fmaf(bf2f(u1.x), sc1.x, sh1.x), 0.f),
                                    fmaxf(fmaf(bf2f(u1.y), sc1.y, sh1.y), 0.f),
                                    fmaxf(fmaf(bf2f(u1.z), sc1.z, sh1.z), 0.f),
                                    fmaxf(fmaf(bf2f(u1.w), sc1.w, sh1.w), 0.f));
            af0[ks] = pack8(v0, v1);
            ushort4 w0 = *(const ushort4*)(a1 + ks * 32);
            ushort4 w1 = *(const ushort4*)(a1 + ks * 32 + 4);
            float4 x0 = make_float4(fmaxf(fmaf(bf2f(w0.x), sc0.x, sh0.x), 0.f),
                                    fmaxf(fmaf(bf2f(w0.y), sc0.y, sh0.y), 0.f),
                                    fmaxf(fmaf(bf2f(w0.z), sc0.z, sh0.z), 0.f),
                                    fmaxf(fmaf(bf2f(w0.w), sc0.w, sh0.w), 0.f));
            float4 x1 = make_float4(fmaxf(fmaf(bf2f(w1.x), sc1.x, sh1.x), 0.f),
                                    fmaxf(fmaf(bf2f(w1.y), sc1.y, sh1.y), 0.f),
                                    fmaxf(fmaf(bf2f(w1.z), sc1.z, sh1.z), 0.f),
                                    fmaxf(fmaf(bf2f(w1.w), sc1.w, sh1.w), 0.f));
            af1[ks] = pack8(x0, x1);
        }
    }

    u16* myl = lds[wave];
#pragma unroll
    for (int ct2 = 0; ct2 < 8; ct2++) {
        int ct0 = ct2 * 2;
        f32x4 a00 = {0.f, 0.f, 0.f, 0.f}, a01 = {0.f, 0.f, 0.f, 0.f};
        f32x4 a10 = {0.f, 0.f, 0.f, 0.f}, a11 = {0.f, 0.f, 0.f, 0.f};
        const u16* bp0 = Bp + ((size_t)(ct0 * KS) * 64 + lane) * 8;
        const u16* bp1 = bp0 + (size_t)KS * 512;
#pragma unroll
        for (int ks = 0; ks < KS; ks++) {   // 4 independent chains per B pair
            bf16x8 b0 = *(const bf16x8*)(bp0 + (size_t)ks * 512);
            bf16x8 b1 = *(const bf16x8*)(bp1 + (size_t)ks * 512);
            a00 = __builtin_amdgcn_mfma_f32_16x16x32_bf16(af0[ks], b0, a00, 0, 0, 0);
            a01 = __builtin_amdgcn_mfma_f32_16x16x32_bf16(af0[ks], b1, a01, 0, 0, 0);
            a10 = __builtin_amdgcn_mfma_f32_16x16x32_bf16(af1[ks], b0, a10, 0, 0, 0);
            a11 = __builtin_amdgcn_mfma_f32_16x16x32_bf16(af1[ks], b1, a11, 0, 0, 0);
        }
        // C/D layout: col = lane&15, row = (lane>>4)*4 + r   [verified m89]
#pragma unroll
        for (int r = 0; r < 4; r++) {
            myl[(q * 4 + r) * 256 + ct0 * 16 + m] = f2bf(a00[r]);
            myl[(q * 4 + r) * 256 + ct0 * 16 + 16 + m] = f2bf(a01[r]);
            myl[(16 + q * 4 + r) * 256 + ct0 * 16 + m] = f2bf(a10[r]);
            myl[(16 + q * 4 + r) * 256 + ct0 * 16 + 16 + m] = f2bf(a11[r]);
        }
    }
    // epilogue: coalesced store + al dot (same-wave LDS, no barrier needed)
    int c8 = (lane & 31) * 8;
    float4 s0 = *(const float4*)(as_ + c8);
    float4 s1 = *(const float4*)(as_ + c8 + 4);
    float4 d0 = *(const float4*)(ad_ + c8);
    float4 d1 = *(const float4*)(ad_ + c8 + 4);
#pragma unroll
    for (int p = 0; p < 16; p++) {
        int row = p * 2 + (lane >> 5);
        if (row0 + row >= Nrows) continue;
        int4 v = *(const int4*)&myl[row * 256 + c8];
        *(int4*)&O[(size_t)(row0 + row) * 256 + c8] = v;
        float f0 = bf2f((u16)(v.x & 0xffff)), f1 = bf2f((u16)((unsigned)v.x >> 16));
        float f2 = bf2f((u16)(v.y & 0xffff)), f3 = bf2f((u16)((unsigned)v.y >> 16));
        float f4 = bf2f((u16)(v.z & 0xffff)), f5 = bf2f((u16)((unsigned)v.z >> 16));
        float f6 = bf2f((u16)(v.w & 0xffff)), f7 = bf2f((u16)((unsigned)v.w >> 16));
        float ps = f0 * s0.x + f1 * s0.y + f2 * s0.z + f3 * s0.w +
                   f4 * s1.x + f5 * s1.y + f6 * s1.z + f7 * s1.w;
        float pd = f0 * d0.x + f1 * d0.y + f2 * d0.z + f3 * d0.w +
                   f4 * d1.x + f5 * d1.y + f6 * d1.z + f7 * d1.w;
        const int W = (H == 4) ? 8 : 32;
#pragma unroll
        for (int o = 1; o < W; o <<= 1) {
            ps += __shfl_xor(ps, o);
            pd += __shfl_xor(pd, o);
        }
        if (H == 4) {
            if ((lane & 7) == 0) {
                int head = (lane & 31) >> 3;
                als[(row0 + row) * 4 + head] = ps;
                ald[(row0 + row) * 4 + head] = pd;
            }
        } else {
            if ((lane & 31) == 0) {
                als[row0 + row] = ps;
                ald[row0 + row] = pd;
            }
        }
    }
}

// ---------------- fused GAT softmax + accumulate (one wave per dst) -----------
// Lane-parallel softmax; alpha/src parked in per-wave LDS; gather loop 8-wide
// unrolled (8 outstanding 512B row-gathers). Output bf16.
template <int H>
__global__ __launch_bounds__(256) void gat_fused_kernel(const int* __restrict__ offs,
                                                        const int* __restrict__ csr,
                                                        const float* __restrict__ als,
                                                        const float* __restrict__ ald,
                                                        const u16* __restrict__ h,
                                                        u16* __restrict__ out, int N) {
    __shared__ float lalpha[4][64 * H];
    __shared__ int lsrc[4][64];
    int wave = threadIdx.x >> 6, lane = threadIdx.x & 63;
    int w = (blockIdx.x * 256 + threadIdx.x) >> 6;
    if (w >= N) return;
    int s0 = offs[w], s1 = offs[w + 1];
    float adl[H], e0[H], m[H], den[H];
#pragma unroll
    for (int hh = 0; hh < H; hh++) { adl[hh] = ald[w * H + hh]; m[hh] = -1e30f; }
    int i0 = s0 + lane;
    bool have = (i0 < s1);
    int src0 = 0;
    if (have) {
        src0 = csr[i0];
        if (H == 4) {
            float4 av = ((const float4*)als)[src0];
            float tmp[4] = {av.x, av.y, av.z, av.w};
#pragma unroll
            for (int hh = 0; hh < 4; hh++) {
                float e = tmp[hh] + adl[hh];
                e = e > 0.f ? e : 0.2f * e;
                e0[hh] = e; m[hh] = e;
            }
        } else {
            float e = als[src0] + adl[0];
            e = e > 0.f ? e : 0.2f * e;
            e0[0] = e; m[0] = e;
        }
    }
    for (int i = i0 + 64; i < s1; i += 64) {  // rare: deg > 64
        int s = csr[i];
#pragma unroll
        for (int hh = 0; hh < H; hh++) {
            float e = als[s * H + hh] + adl[hh];
            e = e > 0.f ? e : 0.2f * e;
            m[hh] = fmaxf(m[hh], e);
        }
    }
#pragma unroll
    for (int hh = 0; hh < H; hh++)
        for (int o = 32; o; o >>= 1) m[hh] = fmaxf(m[hh], __shfl_xor(m[hh], o));
#pragma unroll
    for (int hh = 0; hh < H; hh++) den[hh] = have ? __expf(e0[hh] - m[hh]) : 0.f;
    for (int i = i0 + 64; i < s1; i += 64) {
        int s = csr[i];
#pragma unroll
        for (int hh = 0; hh < H; hh++) {
            float e = als[s * H + hh] + adl[hh];
            e = e > 0.f ? e : 0.2f * e;
            den[hh] += __expf(e - m[hh]);
        }
    }
#pragma unroll
    for (int hh = 0; hh < H; hh++)
        for (int o = 32; o; o >>= 1) den[hh] += __shfl_xor(den[hh], o);
    float rden[H];
#pragma unroll
    for (int hh = 0; hh < H; hh++) rden[hh] = 1.f / (den[hh] + 1e-16f);
    // park chunk-0 alpha/src in per-wave LDS (same-wave write->read, in order)
    if (have) {
        lsrc[wave][lane] = src0;
#pragma unroll
        for (int hh = 0; hh < H; hh++)
            lalpha[wave][lane * H + hh] = __expf(e0[hh] - m[hh]) * rden[hh];
    }
    int deg = s1 - s0;
    int cend = min(deg, 64);
    int myh = (H == 4) ? (lane >> 4) : 0;
    const ushort4* h4 = (const ushort4*)h;
    const float* la = lalpha[wave];
    const int* ls = lsrc[wave];
    float4 acc = make_float4(0.f, 0.f, 0.f, 0.f);
    int i = 0;
    for (; i + 8 <= cend; i += 8) {
        int ss[8]; float av[8]; ushort4 hv[8];
#pragma unroll
        for (int k2 = 0; k2 < 8; k2++) {
            ss[k2] = ls[i + k2];
            av[k2] = la[(i + k2) * H + myh];
        }
#pragma unroll
        for (int k2 = 0; k2 < 8; k2++) hv[k2] = h4[(size_t)ss[k2] * 64 + lane];
#pragma unroll
        for (int k2 = 0; k2 < 8; k2++) {
            acc.x = fmaf(av[k2], bf2f(hv[k2].x), acc.x);
            acc.y = fmaf(av[k2], bf2f(hv[k2].y), acc.y);
            acc.z = fmaf(av[k2], bf2f(hv[k2].z), acc.z);
            acc.w = fmaf(av[k2], bf2f(hv[k2].w), acc.w);
        }
    }
    for (; i + 4 <= cend; i += 4) {
        int ss[4]; float av[4]; ushort4 hv[4];
#pragma unroll
        for (int k2 = 0; k2 < 4; k2++) {
            ss[k2] = ls[i + k2];
            av[k2] = la[(i + k2) * H + myh];
        }
#pragma unroll
        for (int k2 = 0; k2 < 4; k2++) hv[k2] = h4[(size_t)ss[k2] * 64 + lane];
#pragma unroll
        for (int k2 = 0; k2 < 4; k2++) {
            acc.x = fmaf(av[k2], bf2f(hv[k2].x), acc.x);
            acc.y = fmaf(av[k2], bf2f(hv[k2].y), acc.y);
            acc.z = fmaf(av[k2], bf2f(hv[k2].z), acc.z);
            acc.w = fmaf(av[k2], bf2f(hv[k2].w), acc.w);
        }
    }
    for (; i < cend; i++) {
        int s = ls[i];
        float a = la[i * H + myh];
        ushort4 hv = h4[(size_t)s * 64 + lane];
        acc.x = fmaf(a, bf2f(hv.x), acc.x); acc.y = fmaf(a, bf2f(hv.y), acc.y);
        acc.z = fmaf(a, bf2f(hv.z), acc.z); acc.w = fmaf(a, bf2f(hv.w), acc.w);
    }
    for (int j = s0 + 64; j < s1; j++) {  // rare deg>64 tail: recompute alpha
        int s = csr[j];
        float e = als[s * H + myh] + adl[myh];
        e = e > 0.f ? e : 0.2f * e;
        float a = __expf(e - m[myh]) * rden[myh];
        ushort4 hv = h4[(size_t)s * 64 + lane];
        acc.x = fmaf(a, bf2f(hv.x), acc.x); acc.y = fmaf(a, bf2f(hv.y), acc.y);
        acc.z = fmaf(a, bf2f(hv.z), acc.z); acc.w = fmaf(a, bf2f(hv.w), acc.w);
    }
    ushort4 o;
    o.x = f2bf(acc.x); o.y = f2bf(acc.y); o.z = f2bf(acc.z); o.w = f2bf(acc.w);
    ((ushort4*)out)[(size_t)w * 64 + lane] = o;
}

// ---------------- BatchNorm stats (bf16 input; register acc) ------------------
__global__ __launch_bounds__(256) void bn_stats(const u16* __restrict__ agg, int N,
                                                float* __restrict__ sum, float* __restrict__ sq) {
    int t = threadIdx.x;
    int rows = (N + gridDim.x - 1) / gridDim.x;
    int r0 = blockIdx.x * rows, r1 = min(r0 + rows, N);
    if (r0 >= r1) return;
    float s = 0.f, q = 0.f;
    for (int r = r0; r < r1; r++) {
        float v = bf2f(agg[(size_t)r * 256 + t]);
        s += v;
        q = fmaf(v, v, q);
    }
    atomicAdd(&sum[t], s);
    atomicAdd(&sq[t], q);
}

// layer 2: bn-apply + relu + fused global-mean-pool (batch sorted)
__global__ __launch_bounds__(256) void bn_apply_pool(const u16* __restrict__ agg,
                                                     const float* __restrict__ sum,
                                                     const float* __restrict__ sq,
                                                     const float* __restrict__ g,
                                                     const float* __restrict__ be,
                                                     const int* __restrict__ batch,
                                                     u16* __restrict__ out,
                                                     float* __restrict__ pools,
                                                     int* __restrict__ cnt, int N) {
    int t = threadIdx.x;
    float inv = 1.f / (float)N;
    float mm = sum[t] * inv;
    float vv = fmaxf(sq[t] * inv - mm * mm, 0.f);
    float sc = rsqrtf(vv + 1e-5f) * g[t];
    float sh = be[t] - mm * sc;
    int rows = (N + gridDim.x - 1) / gridDim.x;
    int r0 = blockIdx.x * rows, r1 = min(r0 + rows, N);
    if (r0 >= r1) return;
    float acc = 0.f;
    int cur = batch[r0], c0 = 0;
    for (int r = r0; r < r1; r++) {
        int b = batch[r];  // wave-uniform scalar load
        if (b != cur) {
            atomicAdd(&pools[cur * 256 + t], acc);
            if (t == 0) atomicAdd(&cnt[cur], c0);
            acc = 0.f; c0 = 0; cur = b;
        }
        float v = bf2f(agg[(size_t)r * 256 + t]);
        float y = fmaxf(fmaf(v, sc, sh), 0.f);
        out[(size_t)r * 256 + t] = f2bf(y);
        acc += y; c0++;
    }
    atomicAdd(&pools[cur * 256 + t], acc);
    if (t == 0) atomicAdd(&cnt[cur], c0);
}

// shared = relu(gf @ W_sh + b_sh) fused with heads; one block per graph
__global__ __launch_bounds__(256) void shared_head_kernel(const float* __restrict__ pools,
                                                          const int* __restrict__ cnt,
                                                          const float* __restrict__ Wsh,
                                                          const float* __restrict__ bsh,
                                                          const float* __restrict__ Wnode,
                                                          const float* __restrict__ Wcrit,
                                                          const float* __restrict__ bcrit,
                                                          const float* __restrict__ Wtype,
                                                          const float* __restrict__ btype,
                                                          const u16* __restrict__ xn,
                                                          const int* __restrict__ tgt,
                                                          float* __restrict__ gdot,
                                                          float* __restrict__ out_tail) {
    __shared__ float gf[256], red[256];
    int b = blockIdx.x, t = threadIdx.x;
    gf[t] = pools[b * 256 + t] / fmaxf((float)cnt[b], 1.f);
    __syncthreads();
    float acc = bsh[t];
    for (int k = 0; k < 256; k++) acc = fmaf(gf[k], Wsh[k * 256 + t], acc);
    float s = fmaxf(acc, 0.f);
    int tn = tgt[b];
    float xnt = bf2f(xn[(size_t)tn * 256 + t]);
    float pg = s * Wnode[256 + t];
    float pv = s * Wcrit[t];
    float pt0 = s * Wtype[t * 4 + 0] + xnt * Wtype[(256 + t) * 4 + 0];
    float pt1 = s * Wtype[t * 4 + 1] + xnt * Wtype[(256 + t) * 4 + 1];
    float pt2 = s * Wtype[t * 4 + 2] + xnt * Wtype[(256 + t) * 4 + 2];
    float pt3 = s * Wtype[t * 4 + 3] + xnt * Wtype[(256 + t) * 4 + 3];
    auto bred = [&](float v) -> float {
        __syncthreads();
        red[t] = v;
        __syncthreads();
        for (int o = 128; o; o >>= 1) {
            if (t < o) red[t] += red[t + o];
            __syncthreads();
        }
        return red[0];
    };
    float rg = bred(pg);
    float rv = bred(pv);
    float r0 = bred(pt0);
    float r1 = bred(pt1);
    float r2 = bred(pt2);
    float r3 = bred(pt3);
    if (t == 0) {
        gdot[b] = rg;
        out_tail[32 + b] = rv + bcrit[0];
        out_tail[b * 4 + 0] = r0 + btype[0];
        out_tail[b * 4 + 1] = r1 + btype[1];
        out_tail[b * 4 + 2] = r2 + btype[2];
        out_tail[b * 4 + 3] = r3 + btype[3];
    }
}

// node_scores: one wave per node (bf16 x_nodes)
__global__ __launch_bounds__(256) void node_scores_kernel(const u16* __restrict__ xn,
                                                          const float* __restrict__ Wnode, const float* __restrict__ bnode,
                                                          const int* __restrict__ batch, const float* __restrict__ gdot,
                                                          float* __restrict__ out, int N) {
    int w = (blockIdx.x * 256 + threadIdx.x) >> 6;
    int lane = threadIdx.x & 63;
    if (w >= N) return;
    ushort4 xv = ((const ushort4*)(xn + (size_t)w * 256))[lane];
    float4 wv = ((const float4*)Wnode)[lane];
    float p = bf2f(xv.x) * wv.x + bf2f(xv.y) * wv.y + bf2f(xv.z) * wv.z + bf2f(xv.w) * wv.w;
    for (int o = 32; o; o >>= 1) p += __shfl_xor(p, o);
    if (lane == 0) out[w] = p + gdot[batch[w]] + bnode[0];
}

extern "C" void kernel_launch(void* const* d_in, const int* in_sizes, int n_in,
                              void* d_out, int out_size, void* d_ws, size_t ws_size,
                              hipStream_t stream) {
    const float* x = (const float*)d_in[0];
    const int* ei = (const int*)d_in[1];
    const int* batch = (const int*)d_in[2];
    const int* tgt = (const int*)d_in[3];
    const float* W1 = (const float*)d_in[4];
    const float* a1s = (const float*)d_in[5];
    const float* a1d = (const float*)d_in[6];
    // b1 (d_in[7]) / b2 (d_in[11]): constant column shifts cancel exactly in BatchNorm
    const float* W2 = (const float*)d_in[8];
    const float* a2s = (const float*)d_in[9];
    const float* a2d = (const float*)d_in[10];
    const float* g1 = (const float*)d_in[12];
    const float* be1 = (const float*)d_in[13];
    const float* g2 = (const float*)d_in[14];
    const float* be2 = (const float*)d_in[15];
    const float* Wsh = (const float*)d_in[16];
    const float* bsh = (const float*)d_in[17];
    const float* Wnode = (const float*)d_in[18];
    const float* bnode = (const float*)d_in[19];
    const float* Wtype = (const float*)d_in[20];
    const float* btype = (const float*)d_in[21];
    const float* Wcrit = (const float*)d_in[22];
    const float* bcrit = (const float*)d_in[23];

    const int N = in_sizes[2];
    const int E = in_sizes[1] / 2;
    const int Et = E + N;
    const int nb = (N + 255) / 256;   // scan blocks

    // ---- workspace carve (~85 MB) ----
    char* w = (char*)d_ws;
    size_t off = 0;
    auto carve = [&](size_t bytes) -> char* {
        char* p = w + off;
        off = (off + bytes + 255) & ~(size_t)255;
        return p;
    };
    u16* agg_bf = (u16*)carve((size_t)N * 256 * 2);    // bf16 aggregation (both layers)
    u16* h_bf = (u16*)carve((size_t)N * 256 * 2);      // h1 -> h2 (gemm outputs)
    u16* y_bf = (u16*)carve((size_t)N * 256 * 2);      // x_nodes (bn2 out)
    u16* W1p = (u16*)carve(16 * 2 * 512 * 2);          // packed W1 frags
    u16* W2p = (u16*)carve(16 * 8 * 512 * 2);          // packed W2 frags
    float* al1s = (float*)carve((size_t)N * 4 * 4);
    float* al1d = (float*)carve((size_t)N * 4 * 4);
    float* al2s = (float*)carve((size_t)N * 4);
    float* al2d = (float*)carve((size_t)N * 4);
    int* offs = (int*)carve((size_t)(N + 1) * 4);
    int* cursor = (int*)carve((size_t)N * 4);
    int* csr = (int*)carve((size_t)Et * 4);
    int* excl = (int*)carve((size_t)N * 4);
    int* bsum = (int*)carve((size_t)nb * 4);
    int* bbase = (int*)carve((size_t)nb * 4);
    int* stotal = (int*)carve(64);
    float* gdot = (float*)carve(64);
    char* zero0 = w + off;
    int* counts = (int*)carve((size_t)N * 4);
    float* bn1s = (float*)carve(1024);
    float* bn1q = (float*)carve(1024);
    float* bn2s = (float*)carve(1024);
    float* bn2q = (float*)carve(1024);
    float* pools = (float*)carve(8 * 256 * 4);
    int* cnt = (int*)carve(64);
    size_t zbytes = (size_t)((w + off) - zero0);
    hipMemsetAsync(zero0, 0, zbytes, stream);

    int wavesPerGrid = (N + 3) / 4;                  // 4 node-waves per 256-thread block
    int mfmaGrid = (((N + 31) / 32) + 3) / 4;        // 4 32-row tiles (waves) per block

    // ---- CSR build (3-phase parallel scan) + weight prep ----
    hist_kernel<<<(Et + 255) / 256, 256, 0, stream>>>(ei, E, N, counts);
    scan_p1<<<nb, 256, 0, stream>>>(counts, N, excl, bsum);
    scan_p2<<<1, 256, 0, stream>>>(bsum, nb, bbase, stotal);
    scan_p3<<<nb, 256, 0, stream>>>(excl, bbase, stotal, N, offs, cursor);
    scatter_kernel<<<(Et + 255) / 256, 256, 0, stream>>>(ei, E, N, cursor, csr);
    packW_kernel<<<(16 * 2 * 512 + 255) / 256, 256, 0, stream>>>(W1, 2, W1p);
    packW_kernel<<<(16 * 8 * 512 + 255) / 256, 256, 0, stream>>>(W2, 8, W2p);

    // ---- layer 1: GAT(4 heads); x converted to bf16 in gemm A-load ----
    gemm_mfma<64, 4, 0><<<mfmaGrid, 256, 0, stream>>>(x, W1p, h_bf, a1s, a1d, al1s, al1d,
                                                      bn1s, bn1q, g1, be1, N);
    gat_fused_kernel<4><<<wavesPerGrid, 256, 0, stream>>>(offs, csr, al1s, al1d, h_bf, agg_bf, N);
    bn_stats<<<1024, 256, 0, stream>>>(agg_bf, N, bn1s, bn1q);

    // ---- layer 2: bn1-apply fused into gemm A-load; GAT(1) + BN2 + pool ----
    gemm_mfma<256, 1, 1><<<mfmaGrid, 256, 0, stream>>>(agg_bf, W2p, h_bf, a2s, a2d, al2s, al2d,
                                                       bn1s, bn1q, g1, be1, N);
    gat_fused_kernel<1><<<wavesPerGrid, 256, 0, stream>>>(offs, csr, al2s, al2d, h_bf, agg_bf, N);
    bn_stats<<<1024, 256, 0, stream>>>(agg_bf, N, bn2s, bn2q);
    bn_apply_pool<<<1024, 256, 0, stream>>>(agg_bf, bn2s, bn2q, g2, be2, batch, y_bf, pools, cnt, N);

    // ---- heads ----
    shared_head_kernel<<<8, 256, 0, stream>>>(pools, cnt, Wsh, bsh, Wnode, Wcrit, bcrit,
                                              Wtype, btype, y_bf, tgt, gdot, (float*)d_out + N);
    node_scores_kernel<<<wavesPerGrid, 256, 0, stream>>>(y_bf, Wnode, bnode, batch, gdot,
                                                         (float*)d_out, N);
}

// Round 11
// 399.334 us; speedup vs baseline: 3.2640x; 1.0289x over previous
//
#include <hip/hip_runtime.h>

typedef unsigned short u16;
typedef __attribute__((ext_vector_type(8))) short bf16x8;   // 8 bf16 = 4 VGPRs
typedef __attribute__((ext_vector_type(4))) float f32x4;

__device__ __forceinline__ float bf2f(u16 u) {
    return __uint_as_float(((unsigned int)u) << 16);
}
__device__ __forceinline__ u16 f2bf(float f) {
    unsigned int u = __float_as_uint(f);
    u += 0x7fffu + ((u >> 16) & 1u);
    return (u16)(u >> 16);
}
__device__ __forceinline__ bf16x8 pack8(float4 a, float4 b) {
    bf16x8 r;
    r[0] = (short)f2bf(a.x); r[1] = (short)f2bf(a.y);
    r[2] = (short)f2bf(a.z); r[3] = (short)f2bf(a.w);
    r[4] = (short)f2bf(b.x); r[5] = (short)f2bf(b.y);
    r[6] = (short)f2bf(b.z); r[7] = (short)f2bf(b.w);
    return r;
}

// ---------------- CSR build (dst-indexed), reused by both GAT layers ----------
__global__ __launch_bounds__(256) void hist_kernel(const int* __restrict__ ei, int E, int N,
                                                   int* __restrict__ counts) {
    int i = blockIdx.x * 256 + threadIdx.x;
    if (i < E) atomicAdd(&counts[ei[E + i]], 1);
    else if (i < E + N) atomicAdd(&counts[i - E], 1);
}

// ---- 3-phase parallel exclusive scan over counts[N] -> offs[N+1], cursor[N] --
__global__ __launch_bounds__(256) void scan_p1(const int* __restrict__ counts, int N,
                                               int* __restrict__ excl, int* __restrict__ bsum) {
    __shared__ int tmp[256];
    int t = threadIdx.x, b = blockIdx.x, i = b * 256 + t;
    int v = (i < N) ? counts[i] : 0;
    tmp[t] = v;
    __syncthreads();
    for (int o = 1; o < 256; o <<= 1) {
        int u = (t >= o) ? tmp[t - o] : 0;
        __syncthreads();
        tmp[t] += u;
        __syncthreads();
    }
    if (i < N) excl[i] = tmp[t] - v;
    if (t == 255) bsum[b] = tmp[255];
}

__global__ __launch_bounds__(256) void scan_p2(const int* __restrict__ bsum, int nb,
                                               int* __restrict__ bbase, int* __restrict__ total) {
    __shared__ int tmp[256];
    int t = threadIdx.x;
    int run = 0;
    for (int base = 0; base < nb; base += 256) {
        int idx = base + t;
        int v = (idx < nb) ? bsum[idx] : 0;
        tmp[t] = v;
        __syncthreads();
        for (int o = 1; o < 256; o <<= 1) {
            int u = (t >= o) ? tmp[t - o] : 0;
            __syncthreads();
            tmp[t] += u;
            __syncthreads();
        }
        if (idx < nb) bbase[idx] = run + tmp[t] - v;
        run += tmp[255];
        __syncthreads();
    }
    if (t == 0) *total = run;
}

__global__ __launch_bounds__(256) void scan_p3(const int* __restrict__ excl, const int* __restrict__ bbase,
                                               const int* __restrict__ total, int N,
                                               int* __restrict__ offs, int* __restrict__ cursor) {
    int t = threadIdx.x, b = blockIdx.x, i = b * 256 + t;
    if (i < N) {
        int o = excl[i] + bbase[b];
        offs[i] = o;
        cursor[i] = o;
    }
    if (i == 0) offs[N] = *total;
}

__global__ __launch_bounds__(256) void scatter_kernel(const int* __restrict__ ei, int E, int N,
                                                      int* __restrict__ cursor, int* __restrict__ csr) {
    int i = blockIdx.x * 256 + threadIdx.x;
    if (i < E) {
        int d = ei[E + i];
        int p = atomicAdd(&cursor[d], 1);
        csr[p] = ei[i];
    } else if (i < E + N) {
        int n = i - E;
        int p = atomicAdd(&cursor[n], 1);
        csr[p] = n;
    }
}

// ---------------- pack W [K,256] f32 into MFMA B-fragment order (bf16) --------
__global__ __launch_bounds__(256) void packW_kernel(const float* __restrict__ W, int KS,
                                                    u16* __restrict__ out) {
    int idx = blockIdx.x * 256 + threadIdx.x;
    int total = 16 * KS * 512;
    if (idx >= total) return;
    int j = idx & 7;
    int lane = (idx >> 3) & 63;
    int rest = idx >> 9;        // ct*KS + ks
    int ks = rest % KS;
    int ct = rest / KS;
    int k = ks * 32 + (lane >> 4) * 8 + j;
    int n = ct * 16 + (lane & 15);
    out[idx] = f2bf(W[k * 256 + n]);
}

// ---------------- MFMA GEMM (32 rows/wave) + fused epilogue --------------------
// MODE 0: A = raw f32 [N,K] (layer 1 input x; converts to bf16 in-register)
// MODE 1: A = bf16 agg [N,256] with fused bn1-apply + relu (y1 never hits HBM)
// Epilogue: LDS transpose -> coalesced bf16 store + per-row al_s/al_d dots.
template <int K, int H, int MODE>
__global__ __launch_bounds__(256) void gemm_mfma(const void* __restrict__ Ain,
                                                 const u16* __restrict__ Bp,
                                                 u16* __restrict__ O,
                                                 const float* __restrict__ as_,
                                                 const float* __restrict__ ad_,
                                                 float* __restrict__ als,
                                                 float* __restrict__ ald,
                                                 const float* __restrict__ bsum,
                                                 const float* __restrict__ bsq,
                                                 const float* __restrict__ g,
                                                 const float* __restrict__ be,
                                                 int Nrows) {
    constexpr int KS = K / 32;
    __shared__ u16 lds[4][32 * 256];   // 64 KB/block
    __shared__ float sc_s[256], sh_s[256];
    if (MODE == 1) {  // bn1 scale/shift table (all threads reach the barrier)
        int t = threadIdx.x;
        float inv = 1.f / (float)Nrows;
        float mm = bsum[t] * inv;
        float vv = fmaxf(bsq[t] * inv - mm * mm, 0.f);
        float sc = rsqrtf(vv + 1e-5f) * g[t];
        sc_s[t] = sc;
        sh_s[t] = be[t] - mm * sc;
        __syncthreads();
    }
    int wave = threadIdx.x >> 6, lane = threadIdx.x & 63;
    int tile = blockIdx.x * 4 + wave;
    int row0 = tile * 32;
    if (row0 >= Nrows) return;
    int m = lane & 15, q = lane >> 4;
    int r0c = min(row0 + m, Nrows - 1);
    int r1c = min(row0 + 16 + m, Nrows - 1);

    bf16x8 af0[KS], af1[KS];
    if (MODE == 0) {
        const float* A = (const float*)Ain;
        const float* a0 = A + (size_t)r0c * K + q * 8;
        const float* a1 = A + (size_t)r1c * K + q * 8;
#pragma unroll
        for (int ks = 0; ks < KS; ks++) {
            af0[ks] = pack8(*(const float4*)(a0 + ks * 32), *(const float4*)(a0 + ks * 32 + 4));
            af1[ks] = pack8(*(const float4*)(a1 + ks * 32), *(const float4*)(a1 + ks * 32 + 4));
        }
    } else {
        const u16* A = (const u16*)Ain;
        const u16* a0 = A + (size_t)r0c * K + q * 8;
        const u16* a1 = A + (size_t)r1c * K + q * 8;
#pragma unroll
        for (int ks = 0; ks < KS; ks++) {
            int cb = ks * 32 + q * 8;
            float4 sc0 = *(const float4*)&sc_s[cb];
            float4 sc1 = *(const float4*)&sc_s[cb + 4];
            float4 sh0 = *(const float4*)&sh_s[cb];
            float4 sh1 = *(const float4*)&sh_s[cb + 4];
            ushort4 u0 = *(const ushort4*)(a0 + ks * 32);
            ushort4 u1 = *(const ushort4*)(a0 + ks * 32 + 4);
            float4 v0 = make_float4(fmaxf(fmaf(bf2f(u0.x), sc0.x, sh0.x), 0.f),
                                    fmaxf(fmaf(bf2f(u0.y), sc0.y, sh0.y), 0.f),
                                    fmaxf(fmaf(bf2f(u0.z), sc0.z, sh0.z), 0.f),
                                    fmaxf(fmaf(bf2f(u0.w), sc0.w, sh0.w), 0.f));
            float4 v1 = make_float4(fmaxf(fmaf(bf2f(u1.x), sc1.x, sh1.x), 0.f),
                                    fmaxf(fmaf(bf2f(u1.y), sc1.y, sh1.y), 0.f),
                                    fmaxf(fmaf(bf2f(u1.z), sc1.z, sh1.z), 0.f),
                                    fmaxf(fmaf(bf2f(u1.w), sc1.w, sh1.w), 0.f));
            af0[ks] = pack8(v0, v1);
            ushort4 w0 = *(const ushort4*)(a1 + ks * 32);
            ushort4 w1 = *(const ushort4*)(a1 + ks * 32 + 4);
            float4 x0 = make_float4(fmaxf(fmaf(bf2f(w0.x), sc0.x, sh0.x), 0.f),
                                    fmaxf(fmaf(bf2f(w0.y), sc0.y, sh0.y), 0.f),
                                    fmaxf(fmaf(bf2f(w0.z), sc0.z, sh0.z), 0.f),
                                    fmaxf(fmaf(bf2f(w0.w), sc0.w, sh0.w), 0.f));
            float4 x1 = make_float4(fmaxf(fmaf(bf2f(w1.x), sc1.x, sh1.x), 0.f),
                                    fmaxf(fmaf(bf2f(w1.y), sc1.y, sh1.y), 0.f),
                                    fmaxf(fmaf(bf2f(w1.z), sc1.z, sh1.z), 0.f),
                                    fmaxf(fmaf(bf2f(w1.w), sc1.w, sh1.w), 0.f));
            af1[ks] = pack8(x0, x1);
        }
    }

    u16* myl = lds[wave];
#pragma unroll
    for (int ct2 = 0; ct2 < 8; ct2++) {
        int ct0 = ct2 * 2;
        f32x4 a00 = {0.f, 0.f, 0.f, 0.f}, a01 = {0.f, 0.f, 0.f, 0.f};
        f32x4 a10 = {0.f, 0.f, 0.f, 0.f}, a11 = {0.f, 0.f, 0.f, 0.f};
        const u16* bp0 = Bp + ((size_t)(ct0 * KS) * 64 + lane) * 8;
        const u16* bp1 = bp0 + (size_t)KS * 512;
#pragma unroll
        for (int ks = 0; ks < KS; ks++) {   // 4 independent chains per B pair
            bf16x8 b0 = *(const bf16x8*)(bp0 + (size_t)ks * 512);
            bf16x8 b1 = *(const bf16x8*)(bp1 + (size_t)ks * 512);
            a00 = __builtin_amdgcn_mfma_f32_16x16x32_bf16(af0[ks], b0, a00, 0, 0, 0);
            a01 = __builtin_amdgcn_mfma_f32_16x16x32_bf16(af0[ks], b1, a01, 0, 0, 0);
            a10 = __builtin_amdgcn_mfma_f32_16x16x32_bf16(af1[ks], b0, a10, 0, 0, 0);
            a11 = __builtin_amdgcn_mfma_f32_16x16x32_bf16(af1[ks], b1, a11, 0, 0, 0);
        }
        // C/D layout: col = lane&15, row = (lane>>4)*4 + r   [verified m89]
#pragma unroll
        for (int r = 0; r < 4; r++) {
            myl[(q * 4 + r) * 256 + ct0 * 16 + m] = f2bf(a00[r]);
            myl[(q * 4 + r) * 256 + ct0 * 16 + 16 + m] = f2bf(a01[r]);
            myl[(16 + q * 4 + r) * 256 + ct0 * 16 + m] = f2bf(a10[r]);
            myl[(16 + q * 4 + r) * 256 + ct0 * 16 + 16 + m] = f2bf(a11[r]);
        }
    }
    // epilogue: coalesced store + al dot (same-wave LDS, no barrier needed)
    int c8 = (lane & 31) * 8;
    float4 s0 = *(const float4*)(as_ + c8);
    float4 s1 = *(const float4*)(as_ + c8 + 4);
    float4 d0 = *(const float4*)(ad_ + c8);
    float4 d1 = *(const float4*)(ad_ + c8 + 4);
#pragma unroll
    for (int p = 0; p < 16; p++) {
        int row = p * 2 + (lane >> 5);
        if (row0 + row >= Nrows) continue;
        int4 v = *(const int4*)&myl[row * 256 + c8];
        *(int4*)&O[(size_t)(row0 + row) * 256 + c8] = v;
        float f0 = bf2f((u16)(v.x & 0xffff)), f1 = bf2f((u16)((unsigned)v.x >> 16));
        float f2 = bf2f((u16)(v.y & 0xffff)), f3 = bf2f((u16)((unsigned)v.y >> 16));
        float f4 = bf2f((u16)(v.z & 0xffff)), f5 = bf2f((u16)((unsigned)v.z >> 16));
        float f6 = bf2f((u16)(v.w & 0xffff)), f7 = bf2f((u16)((unsigned)v.w >> 16));
        float ps = f0 * s0.x + f1 * s0.y + f2 * s0.z + f3 * s0.w +
                   f4 * s1.x + f5 * s1.y + f6 * s1.z + f7 * s1.w;
        float pd = f0 * d0.x + f1 * d0.y + f2 * d0.z + f3 * d0.w +
                   f4 * d1.x + f5 * d1.y + f6 * d1.z + f7 * d1.w;
        const int W = (H == 4) ? 8 : 32;
#pragma unroll
        for (int o = 1; o < W; o <<= 1) {
            ps += __shfl_xor(ps, o);
            pd += __shfl_xor(pd, o);
        }
        if (H == 4) {
            if ((lane & 7) == 0) {
                int head = (lane & 31) >> 3;
                als[(row0 + row) * 4 + head] = ps;
                ald[(row0 + row) * 4 + head] = pd;
            }
        } else {
            if ((lane & 31) == 0) {
                als[row0 + row] = ps;
                ald[row0 + row] = pd;
            }
        }
    }
}

// ---------------- fused GAT softmax + accumulate (one wave per dst) -----------
// Lane-parallel softmax; alpha/src parked in per-wave LDS; gather loop 4-wide
// unrolled (4 outstanding 512B row-gathers; 8-wide regressed: VGPR 28->44,
// occupancy 64->44%, 44->53us — wave-parallelism beats per-wave ILP here).
template <int H>
__global__ __launch_bounds__(256) void gat_fused_kernel(const int* __restrict__ offs,
                                                        const int* __restrict__ csr,
                                                        const float* __restrict__ als,
                                                        const float* __restrict__ ald,
                                                        const u16* __restrict__ h,
                                                        u16* __restrict__ out, int N) {
    __shared__ float lalpha[4][64 * H];
    __shared__ int lsrc[4][64];
    int wave = threadIdx.x >> 6, lane = threadIdx.x & 63;
    int w = (blockIdx.x * 256 + threadIdx.x) >> 6;
    if (w >= N) return;
    int s0 = offs[w], s1 = offs[w + 1];
    float adl[H], e0[H], m[H], den[H];
#pragma unroll
    for (int hh = 0; hh < H; hh++) { adl[hh] = ald[w * H + hh]; m[hh] = -1e30f; }
    int i0 = s0 + lane;
    bool have = (i0 < s1);
    int src0 = 0;
    if (have) {
        src0 = csr[i0];
        if (H == 4) {
            float4 av = ((const float4*)als)[src0];
            float tmp[4] = {av.x, av.y, av.z, av.w};
#pragma unroll
            for (int hh = 0; hh < 4; hh++) {
                float e = tmp[hh] + adl[hh];
                e = e > 0.f ? e : 0.2f * e;
                e0[hh] = e; m[hh] = e;
            }
        } else {
            float e = als[src0] + adl[0];
            e = e > 0.f ? e : 0.2f * e;
            e0[0] = e; m[0] = e;
        }
    }
    for (int i = i0 + 64; i < s1; i += 64) {  // rare: deg > 64
        int s = csr[i];
#pragma unroll
        for (int hh = 0; hh < H; hh++) {
            float e = als[s * H + hh] + adl[hh];
            e = e > 0.f ? e : 0.2f * e;
            m[hh] = fmaxf(m[hh], e);
        }
    }
#pragma unroll
    for (int hh = 0; hh < H; hh++)
        for (int o = 32; o; o >>= 1) m[hh] = fmaxf(m[hh], __shfl_xor(m[hh], o));
#pragma unroll
    for (int hh = 0; hh < H; hh++) den[hh] = have ? __expf(e0[hh] - m[hh]) : 0.f;
    for (int i = i0 + 64; i < s1; i += 64) {
        int s = csr[i];
#pragma unroll
        for (int hh = 0; hh < H; hh++) {
            float e = als[s * H + hh] + adl[hh];
            e = e > 0.f ? e : 0.2f * e;
            den[hh] += __expf(e - m[hh]);
        }
    }
#pragma unroll
    for (int hh = 0; hh < H; hh++)
        for (int o = 32; o; o >>= 1) den[hh] += __shfl_xor(den[hh], o);
    float rden[H];
#pragma unroll
    for (int hh = 0; hh < H; hh++) rden[hh] = 1.f / (den[hh] + 1e-16f);
    // park chunk-0 alpha/src in per-wave LDS (same-wave write->read, in order)
    if (have) {
        lsrc[wave][lane] = src0;
#pragma unroll
        for (int hh = 0; hh < H; hh++)
            lalpha[wave][lane * H + hh] = __expf(e0[hh] - m[hh]) * rden[hh];
    }
    int deg = s1 - s0;
    int cend = min(deg, 64);
    int myh = (H == 4) ? (lane >> 4) : 0;
    const ushort4* h4 = (const ushort4*)h;
    const float* la = lalpha[wave];
    const int* ls = lsrc[wave];
    float4 acc = make_float4(0.f, 0.f, 0.f, 0.f);
    int i = 0;
    for (; i + 4 <= cend; i += 4) {
        int sa = ls[i], sb = ls[i + 1], sc = ls[i + 2], sd = ls[i + 3];
        float aa = la[i * H + myh];
        float ab = la[(i + 1) * H + myh];
        float ac = la[(i + 2) * H + myh];
        float ad = la[(i + 3) * H + myh];
        ushort4 ha = h4[(size_t)sa * 64 + lane];
        ushort4 hb = h4[(size_t)sb * 64 + lane];
        ushort4 hc = h4[(size_t)sc * 64 + lane];
        ushort4 hd = h4[(size_t)sd * 64 + lane];
        acc.x = fmaf(aa, bf2f(ha.x), acc.x); acc.y = fmaf(aa, bf2f(ha.y), acc.y);
        acc.z = fmaf(aa, bf2f(ha.z), acc.z); acc.w = fmaf(aa, bf2f(ha.w), acc.w);
        acc.x = fmaf(ab, bf2f(hb.x), acc.x); acc.y = fmaf(ab, bf2f(hb.y), acc.y);
        acc.z = fmaf(ab, bf2f(hb.z), acc.z); acc.w = fmaf(ab, bf2f(hb.w), acc.w);
        acc.x = fmaf(ac, bf2f(hc.x), acc.x); acc.y = fmaf(ac, bf2f(hc.y), acc.y);
        acc.z = fmaf(ac, bf2f(hc.z), acc.z); acc.w = fmaf(ac, bf2f(hc.w), acc.w);
        acc.x = fmaf(ad, bf2f(hd.x), acc.x); acc.y = fmaf(ad, bf2f(hd.y), acc.y);
        acc.z = fmaf(ad, bf2f(hd.z), acc.z); acc.w = fmaf(ad, bf2f(hd.w), acc.w);
    }
    for (; i < cend; i++) {
        int s = ls[i];
        float a = la[i * H + myh];
        ushort4 hv = h4[(size_t)s * 64 + lane];
        acc.x = fmaf(a, bf2f(hv.x), acc.x); acc.y = fmaf(a, bf2f(hv.y), acc.y);
        acc.z = fmaf(a, bf2f(hv.z), acc.z); acc.w = fmaf(a, bf2f(hv.w), acc.w);
    }
    for (int j = s0 + 64; j < s1; j++) {  // rare deg>64 tail: recompute alpha
        int s = csr[j];
        float e = als[s * H + myh] + adl[myh];
        e = e > 0.f ? e : 0.2f * e;
        float a = __expf(e - m[myh]) * rden[myh];
        ushort4 hv = h4[(size_t)s * 64 + lane];
        acc.x = fmaf(a, bf2f(hv.x), acc.x); acc.y = fmaf(a, bf2f(hv.y), acc.y);
        acc.z = fmaf(a, bf2f(hv.z), acc.z); acc.w = fmaf(a, bf2f(hv.w), acc.w);
    }
    ushort4 o;
    o.x = f2bf(acc.x); o.y = f2bf(acc.y); o.z = f2bf(acc.z); o.w = f2bf(acc.w);
    ((ushort4*)out)[(size_t)w * 64 + lane] = o;
}

// ---------------- BatchNorm stats (bf16 input; register acc) ------------------
__global__ __launch_bounds__(256) void bn_stats(const u16* __restrict__ agg, int N,
                                                float* __restrict__ sum, float* __restrict__ sq) {
    int t = threadIdx.x;
    int rows = (N + gridDim.x - 1) / gridDim.x;
    int r0 = blockIdx.x * rows, r1 = min(r0 + rows, N);
    if (r0 >= r1) return;
    float s = 0.f, q = 0.f;
    for (int r = r0; r < r1; r++) {
        float v = bf2f(agg[(size_t)r * 256 + t]);
        s += v;
        q = fmaf(v, v, q);
    }
    atomicAdd(&sum[t], s);
    atomicAdd(&sq[t], q);
}

// layer 2: bn-apply + relu + fused global-mean-pool (batch sorted)
__global__ __launch_bounds__(256) void bn_apply_pool(const u16* __restrict__ agg,
                                                     const float* __restrict__ sum,
                                                     const float* __restrict__ sq,
                                                     const float* __restrict__ g,
                                                     const float* __restrict__ be,
                                                     const int* __restrict__ batch,
                                                     u16* __restrict__ out,
                                                     float* __restrict__ pools,
                                                     int* __restrict__ cnt, int N) {
    int t = threadIdx.x;
    float inv = 1.f / (float)N;
    float mm = sum[t] * inv;
    float vv = fmaxf(sq[t] * inv - mm * mm, 0.f);
    float sc = rsqrtf(vv + 1e-5f) * g[t];
    float sh = be[t] - mm * sc;
    int rows = (N + gridDim.x - 1) / gridDim.x;
    int r0 = blockIdx.x * rows, r1 = min(r0 + rows, N);
    if (r0 >= r1) return;
    float acc = 0.f;
    int cur = batch[r0], c0 = 0;
    for (int r = r0; r < r1; r++) {
        int b = batch[r];  // wave-uniform scalar load
        if (b != cur) {
            atomicAdd(&pools[cur * 256 + t], acc);
            if (t == 0) atomicAdd(&cnt[cur], c0);
            acc = 0.f; c0 = 0; cur = b;
        }
        float v = bf2f(agg[(size_t)r * 256 + t]);
        float y = fmaxf(fmaf(v, sc, sh), 0.f);
        out[(size_t)r * 256 + t] = f2bf(y);
        acc += y; c0++;
    }
    atomicAdd(&pools[cur * 256 + t], acc);
    if (t == 0) atomicAdd(&cnt[cur], c0);
}

// shared = relu(gf @ W_sh + b_sh) fused with heads; one block per graph
__global__ __launch_bounds__(256) void shared_head_kernel(const float* __restrict__ pools,
                                                          const int* __restrict__ cnt,
                                                          const float* __restrict__ Wsh,
                                                          const float* __restrict__ bsh,
                                                          const float* __restrict__ Wnode,
                                                          const float* __restrict__ Wcrit,
                                                          const float* __restrict__ bcrit,
                                                          const float* __restrict__ Wtype,
                                                          const float* __restrict__ btype,
                                                          const u16* __restrict__ xn,
                                                          const int* __restrict__ tgt,
                                                          float* __restrict__ gdot,
                                                          float* __restrict__ out_tail) {
    __shared__ float gf[256], red[256];
    int b = blockIdx.x, t = threadIdx.x;
    gf[t] = pools[b * 256 + t] / fmaxf((float)cnt[b], 1.f);
    __syncthreads();
    float acc = bsh[t];
    for (int k = 0; k < 256; k++) acc = fmaf(gf[k], Wsh[k * 256 + t], acc);
    float s = fmaxf(acc, 0.f);
    int tn = tgt[b];
    float xnt = bf2f(xn[(size_t)tn * 256 + t]);
    float pg = s * Wnode[256 + t];
    float pv = s * Wcrit[t];
    float pt0 = s * Wtype[t * 4 + 0] + xnt * Wtype[(256 + t) * 4 + 0];
    float pt1 = s * Wtype[t * 4 + 1] + xnt * Wtype[(256 + t) * 4 + 1];
    float pt2 = s * Wtype[t * 4 + 2] + xnt * Wtype[(256 + t) * 4 + 2];
    float pt3 = s * Wtype[t * 4 + 3] + xnt * Wtype[(256 + t) * 4 + 3];
    auto bred = [&](float v) -> float {
        __syncthreads();
        red[t] = v;
        __syncthreads();
        for (int o = 128; o; o >>= 1) {
            if (t < o) red[t] += red[t + o];
            __syncthreads();
        }
        return red[0];
    };
    float rg = bred(pg);
    float rv = bred(pv);
    float r0 = bred(pt0);
    float r1 = bred(pt1);
    float r2 = bred(pt2);
    float r3 = bred(pt3);
    if (t == 0) {
        gdot[b] = rg;
        out_tail[32 + b] = rv + bcrit[0];
        out_tail[b * 4 + 0] = r0 + btype[0];
        out_tail[b * 4 + 1] = r1 + btype[1];
        out_tail[b * 4 + 2] = r2 + btype[2];
        out_tail[b * 4 + 3] = r3 + btype[3];
    }
}

// node_scores: one wave per node (bf16 x_nodes)
__global__ __launch_bounds__(256) void node_scores_kernel(const u16* __restrict__ xn,
                                                          const float* __restrict__ Wnode, const float* __restrict__ bnode,
                                                          const int* __restrict__ batch, const float* __restrict__ gdot,
                                                          float* __restrict__ out, int N) {
    int w = (blockIdx.x * 256 + threadIdx.x) >> 6;
    int lane = threadIdx.x & 63;
    if (w >= N) return;
    ushort4 xv = ((const ushort4*)(xn + (size_t)w * 256))[lane];
    float4 wv = ((const float4*)Wnode)[lane];
    float p = bf2f(xv.x) * wv.x + bf2f(xv.y) * wv.y + bf2f(xv.z) * wv.z + bf2f(xv.w) * wv.w;
    for (int o = 32; o; o >>= 1) p += __shfl_xor(p, o);
    if (lane == 0) out[w] = p + gdot[batch[w]] + bnode[0];
}

extern "C" void kernel_launch(void* const* d_in, const int* in_sizes, int n_in,
                              void* d_out, int out_size, void* d_ws, size_t ws_size,
                              hipStream_t stream) {
    const float* x = (const float*)d_in[0];
    const int* ei = (const int*)d_in[1];
    const int* batch = (const int*)d_in[2];
    const int* tgt = (const int*)d_in[3];
    const float* W1 = (const float*)d_in[4];
    const float* a1s = (const float*)d_in[5];
    const float* a1d = (const float*)d_in[6];
    // b1 (d_in[7]) / b2 (d_in[11]): constant column shifts cancel exactly in BatchNorm
    const float* W2 = (const float*)d_in[8];
    const float* a2s = (const float*)d_in[9];
    const float* a2d = (const float*)d_in[10];
    const float* g1 = (const float*)d_in[12];
    const float* be1 = (const float*)d_in[13];
    const float* g2 = (const float*)d_in[14];
    const float* be2 = (const float*)d_in[15];
    const float* Wsh = (const float*)d_in[16];
    const float* bsh = (const float*)d_in[17];
    const float* Wnode = (const float*)d_in[18];
    const float* bnode = (const float*)d_in[19];
    const float* Wtype = (const float*)d_in[20];
    const float* btype = (const float*)d_in[21];
    const float* Wcrit = (const float*)d_in[22];
    const float* bcrit = (const float*)d_in[23];

    const int N = in_sizes[2];
    const int E = in_sizes[1] / 2;
    const int Et = E + N;
    const int nb = (N + 255) / 256;   // scan blocks

    // ---- workspace carve (~85 MB) ----
    char* w = (char*)d_ws;
    size_t off = 0;
    auto carve = [&](size_t bytes) -> char* {
        char* p = w + off;
        off = (off + bytes + 255) & ~(size_t)255;
        return p;
    };
    u16* agg_bf = (u16*)carve((size_t)N * 256 * 2);    // bf16 aggregation (both layers)
    u16* h_bf = (u16*)carve((size_t)N * 256 * 2);      // h1 -> h2 (gemm outputs)
    u16* y_bf = (u16*)carve((size_t)N * 256 * 2);      // x_nodes (bn2 out)
    u16* W1p = (u16*)carve(16 * 2 * 512 * 2);          // packed W1 frags
    u16* W2p = (u16*)carve(16 * 8 * 512 * 2);          // packed W2 frags
    float* al1s = (float*)carve((size_t)N * 4 * 4);
    float* al1d = (float*)carve((size_t)N * 4 * 4);
    float* al2s = (float*)carve((size_t)N * 4);
    float* al2d = (float*)carve((size_t)N * 4);
    int* offs = (int*)carve((size_t)(N + 1) * 4);
    int* cursor = (int*)carve((size_t)N * 4);
    int* csr = (int*)carve((size_t)Et * 4);
    int* excl = (int*)carve((size_t)N * 4);
    int* bsum = (int*)carve((size_t)nb * 4);
    int* bbase = (int*)carve((size_t)nb * 4);
    int* stotal = (int*)carve(64);
    float* gdot = (float*)carve(64);
    char* zero0 = w + off;
    int* counts = (int*)carve((size_t)N * 4);
    float* bn1s = (float*)carve(1024);
    float* bn1q = (float*)carve(1024);
    float* bn2s = (float*)carve(1024);
    float* bn2q = (float*)carve(1024);
    float* pools = (float*)carve(8 * 256 * 4);
    int* cnt = (int*)carve(64);
    size_t zbytes = (size_t)((w + off) - zero0);
    hipMemsetAsync(zero0, 0, zbytes, stream);

    int wavesPerGrid = (N + 3) / 4;                  // 4 node-waves per 256-thread block
    int mfmaGrid = (((N + 31) / 32) + 3) / 4;        // 4 32-row tiles (waves) per block

    // ---- CSR build (3-phase parallel scan) + weight prep ----
    hist_kernel<<<(Et + 255) / 256, 256, 0, stream>>>(ei, E, N, counts);
    scan_p1<<<nb, 256, 0, stream>>>(counts, N, excl, bsum);
    scan_p2<<<1, 256, 0, stream>>>(bsum, nb, bbase, stotal);
    scan_p3<<<nb, 256, 0, stream>>>(excl, bbase, stotal, N, offs, cursor);
    scatter_kernel<<<(Et + 255) / 256, 256, 0, stream>>>(ei, E, N, cursor, csr);
    packW_kernel<<<(16 * 2 * 512 + 255) / 256, 256, 0, stream>>>(W1, 2, W1p);
    packW_kernel<<<(16 * 8 * 512 + 255) / 256, 256, 0, stream>>>(W2, 8, W2p);

    // ---- layer 1: GAT(4 heads); x converted to bf16 in gemm A-load ----
    gemm_mfma<64, 4, 0><<<mfmaGrid, 256, 0, stream>>>(x, W1p, h_bf, a1s, a1d, al1s, al1d,
                                                      bn1s, bn1q, g1, be1, N);
    gat_fused_kernel<4><<<wavesPerGrid, 256, 0, stream>>>(offs, csr, al1s, al1d, h_bf, agg_bf, N);
    bn_stats<<<1024, 256, 0, stream>>>(agg_bf, N, bn1s, bn1q);

    // ---- layer 2: bn1-apply fused into gemm A-load; GAT(1) + BN2 + pool ----
    gemm_mfma<256, 1, 1><<<mfmaGrid, 256, 0, stream>>>(agg_bf, W2p, h_bf, a2s, a2d, al2s, al2d,
                                                       bn1s, bn1q, g1, be1, N);
    gat_fused_kernel<1><<<wavesPerGrid, 256, 0, stream>>>(offs, csr, al2s, al2d, h_bf, agg_bf, N);
    bn_stats<<<1024, 256, 0, stream>>>(agg_bf, N, bn2s, bn2q);
    bn_apply_pool<<<1024, 256, 0, stream>>>(agg_bf, bn2s, bn2q, g2, be2, batch, y_bf, pools, cnt, N);

    // ---- heads ----
    shared_head_kernel<<<8, 256, 0, stream>>>(pools, cnt, Wsh, bsh, Wnode, Wcrit, bcrit,
                                              Wtype, btype, y_bf, tgt, gdot, (float*)d_out + N);
    node_scores_kernel<<<wavesPerGrid, 256, 0, stream>>>(y_bf, Wnode, bnode, batch, gdot,
                                                         (float*)d_out, N);
}

// Round 12
// 397.800 us; speedup vs baseline: 3.2766x; 1.0039x over previous
//
#include <hip/hip_runtime.h>

typedef unsigned short u16;
typedef __attribute__((ext_vector_type(8))) short bf16x8;   // 8 bf16 = 4 VGPRs
typedef __attribute__((ext_vector_type(4))) float f32x4;

__device__ __forceinline__ float bf2f(u16 u) {
    return __uint_as_float(((unsigned int)u) << 16);
}
__device__ __forceinline__ u16 f2bf(float f) {
    unsigned int u = __float_as_uint(f);
    u += 0x7fffu + ((u >> 16) & 1u);
    return (u16)(u >> 16);
}
__device__ __forceinline__ bf16x8 pack8(float4 a, float4 b) {
    bf16x8 r;
    r[0] = (short)f2bf(a.x); r[1] = (short)f2bf(a.y);
    r[2] = (short)f2bf(a.z); r[3] = (short)f2bf(a.w);
    r[4] = (short)f2bf(b.x); r[5] = (short)f2bf(b.y);
    r[6] = (short)f2bf(b.z); r[7] = (short)f2bf(b.w);
    return r;
}
// fma 8 bf16 lanes (packed in int4) into acc[8]
__device__ __forceinline__ void fma8(float* acc, float a, int4 v) {
    unsigned vx = (unsigned)v.x, vy = (unsigned)v.y, vz = (unsigned)v.z, vw = (unsigned)v.w;
    acc[0] = fmaf(a, bf2f((u16)(vx & 0xffff)), acc[0]);
    acc[1] = fmaf(a, bf2f((u16)(vx >> 16)), acc[1]);
    acc[2] = fmaf(a, bf2f((u16)(vy & 0xffff)), acc[2]);
    acc[3] = fmaf(a, bf2f((u16)(vy >> 16)), acc[3]);
    acc[4] = fmaf(a, bf2f((u16)(vz & 0xffff)), acc[4]);
    acc[5] = fmaf(a, bf2f((u16)(vz >> 16)), acc[5]);
    acc[6] = fmaf(a, bf2f((u16)(vw & 0xffff)), acc[6]);
    acc[7] = fmaf(a, bf2f((u16)(vw >> 16)), acc[7]);
}

// ---------------- CSR build (dst-indexed), reused by both GAT layers ----------
__global__ __launch_bounds__(256) void hist_kernel(const int* __restrict__ ei, int E, int N,
                                                   int* __restrict__ counts) {
    int i = blockIdx.x * 256 + threadIdx.x;
    if (i < E) atomicAdd(&counts[ei[E + i]], 1);
    else if (i < E + N) atomicAdd(&counts[i - E], 1);
}

// ---- 3-phase parallel exclusive scan over counts[N] -> offs[N+1], cursor[N] --
__global__ __launch_bounds__(256) void scan_p1(const int* __restrict__ counts, int N,
                                               int* __restrict__ excl, int* __restrict__ bsum) {
    __shared__ int tmp[256];
    int t = threadIdx.x, b = blockIdx.x, i = b * 256 + t;
    int v = (i < N) ? counts[i] : 0;
    tmp[t] = v;
    __syncthreads();
    for (int o = 1; o < 256; o <<= 1) {
        int u = (t >= o) ? tmp[t - o] : 0;
        __syncthreads();
        tmp[t] += u;
        __syncthreads();
    }
    if (i < N) excl[i] = tmp[t] - v;
    if (t == 255) bsum[b] = tmp[255];
}

__global__ __launch_bounds__(256) void scan_p2(const int* __restrict__ bsum, int nb,
                                               int* __restrict__ bbase, int* __restrict__ total) {
    __shared__ int tmp[256];
    int t = threadIdx.x;
    int run = 0;
    for (int base = 0; base < nb; base += 256) {
        int idx = base + t;
        int v = (idx < nb) ? bsum[idx] : 0;
        tmp[t] = v;
        __syncthreads();
        for (int o = 1; o < 256; o <<= 1) {
            int u = (t >= o) ? tmp[t - o] : 0;
            __syncthreads();
            tmp[t] += u;
            __syncthreads();
        }
        if (idx < nb) bbase[idx] = run + tmp[t] - v;
        run += tmp[255];
        __syncthreads();
    }
    if (t == 0) *total = run;
}

__global__ __launch_bounds__(256) void scan_p3(const int* __restrict__ excl, const int* __restrict__ bbase,
                                               const int* __restrict__ total, int N,
                                               int* __restrict__ offs, int* __restrict__ cursor) {
    int t = threadIdx.x, b = blockIdx.x, i = b * 256 + t;
    if (i < N) {
        int o = excl[i] + bbase[b];
        offs[i] = o;
        cursor[i] = o;
    }
    if (i == 0) offs[N] = *total;
}

__global__ __launch_bounds__(256) void scatter_kernel(const int* __restrict__ ei, int E, int N,
                                                      int* __restrict__ cursor, int* __restrict__ csr) {
    int i = blockIdx.x * 256 + threadIdx.x;
    if (i < E) {
        int d = ei[E + i];
        int p = atomicAdd(&cursor[d], 1);
        csr[p] = ei[i];
    } else if (i < E + N) {
        int n = i - E;
        int p = atomicAdd(&cursor[n], 1);
        csr[p] = n;
    }
}

// ---------------- pack W [K,256] f32 into MFMA B-fragment order (bf16) --------
__global__ __launch_bounds__(256) void packW_kernel(const float* __restrict__ W, int KS,
                                                    u16* __restrict__ out) {
    int idx = blockIdx.x * 256 + threadIdx.x;
    int total = 16 * KS * 512;
    if (idx >= total) return;
    int j = idx & 7;
    int lane = (idx >> 3) & 63;
    int rest = idx >> 9;        // ct*KS + ks
    int ks = rest % KS;
    int ct = rest / KS;
    int k = ks * 32 + (lane >> 4) * 8 + j;
    int n = ct * 16 + (lane & 15);
    out[idx] = f2bf(W[k * 256 + n]);
}

// ---------------- MFMA GEMM (32 rows/wave) + fused epilogue --------------------
// MODE 0: A = raw f32 [N,K] (layer 1 input x; converts to bf16 in-register)
// MODE 1: A = bf16 agg [N,256] with fused bn1-apply + relu (y1 never hits HBM)
// Epilogue: LDS transpose -> coalesced bf16 store + per-row al_s/al_d dots.
template <int K, int H, int MODE>
__global__ __launch_bounds__(256) void gemm_mfma(const void* __restrict__ Ain,
                                                 const u16* __restrict__ Bp,
                                                 u16* __restrict__ O,
                                                 const float* __restrict__ as_,
                                                 const float* __restrict__ ad_,
                                                 float* __restrict__ als,
                                                 float* __restrict__ ald,
                                                 const float* __restrict__ bsum,
                                                 const float* __restrict__ bsq,
                                                 const float* __restrict__ g,
                                                 const float* __restrict__ be,
                                                 int Nrows) {
    constexpr int KS = K / 32;
    __shared__ u16 lds[4][32 * 256];   // 64 KB/block
    __shared__ float sc_s[256], sh_s[256];
    if (MODE == 1) {  // bn1 scale/shift table (all threads reach the barrier)
        int t = threadIdx.x;
        float inv = 1.f / (float)Nrows;
        float mm = bsum[t] * inv;
        float vv = fmaxf(bsq[t] * inv - mm * mm, 0.f);
        float sc = rsqrtf(vv + 1e-5f) * g[t];
        sc_s[t] = sc;
        sh_s[t] = be[t] - mm * sc;
        __syncthreads();
    }
    int wave = threadIdx.x >> 6, lane = threadIdx.x & 63;
    int tile = blockIdx.x * 4 + wave;
    int row0 = tile * 32;
    if (row0 >= Nrows) return;
    int m = lane & 15, q = lane >> 4;
    int r0c = min(row0 + m, Nrows - 1);
    int r1c = min(row0 + 16 + m, Nrows - 1);

    bf16x8 af0[KS], af1[KS];
    if (MODE == 0) {
        const float* A = (const float*)Ain;
        const float* a0 = A + (size_t)r0c * K + q * 8;
        const float* a1 = A + (size_t)r1c * K + q * 8;
#pragma unroll
        for (int ks = 0; ks < KS; ks++) {
            af0[ks] = pack8(*(const float4*)(a0 + ks * 32), *(const float4*)(a0 + ks * 32 + 4));
            af1[ks] = pack8(*(const float4*)(a1 + ks * 32), *(const float4*)(a1 + ks * 32 + 4));
        }
    } else {
        const u16* A = (const u16*)Ain;
        const u16* a0 = A + (size_t)r0c * K + q * 8;
        const u16* a1 = A + (size_t)r1c * K + q * 8;
#pragma unroll
        for (int ks = 0; ks < KS; ks++) {
            int cb = ks * 32 + q * 8;
            float4 sc0 = *(const float4*)&sc_s[cb];
            float4 sc1 = *(const float4*)&sc_s[cb + 4];
            float4 sh0 = *(const float4*)&sh_s[cb];
            float4 sh1 = *(const float4*)&sh_s[cb + 4];
            ushort4 u0 = *(const ushort4*)(a0 + ks * 32);
            ushort4 u1 = *(const ushort4*)(a0 + ks * 32 + 4);
            float4 v0 = make_float4(fmaxf(fmaf(bf2f(u0.x), sc0.x, sh0.x), 0.f),
                                    fmaxf(fmaf(bf2f(u0.y), sc0.y, sh0.y), 0.f),
                                    fmaxf(fmaf(bf2f(u0.z), sc0.z, sh0.z), 0.f),
                                    fmaxf(fmaf(bf2f(u0.w), sc0.w, sh0.w), 0.f));
            float4 v1 = make_float4(fmaxf(fmaf(bf2f(u1.x), sc1.x, sh1.x), 0.f),
                                    fmaxf(fmaf(bf2f(u1.y), sc1.y, sh1.y), 0.f),
                                    fmaxf(fmaf(bf2f(u1.z), sc1.z, sh1.z), 0.f),
                                    fmaxf(fmaf(bf2f(u1.w), sc1.w, sh1.w), 0.f));
            af0[ks] = pack8(v0, v1);
            ushort4 w0 = *(const ushort4*)(a1 + ks * 32);
            ushort4 w1 = *(const ushort4*)(a1 + ks * 32 + 4);
            float4 x0 = make_float4(fmaxf(fmaf(bf2f(w0.x), sc0.x, sh0.x), 0.f),
                                    fmaxf(fmaf(bf2f(w0.y), sc0.y, sh0.y), 0.f),
                                    fmaxf(fmaf(bf2f(w0.z), sc0.z, sh0.z), 0.f),
                                    fmaxf(fmaf(bf2f(w0.w), sc0.w, sh0.w), 0.f));
            float4 x1 = make_float4(fmaxf(fmaf(bf2f(w1.x), sc1.x, sh1.x), 0.f),
                                    fmaxf(fmaf(bf2f(w1.y), sc1.y, sh1.y), 0.f),
                                    fmaxf(fmaf(bf2f(w1.z), sc1.z, sh1.z), 0.f),
                                    fmaxf(fmaf(bf2f(w1.w), sc1.w, sh1.w), 0.f));
            af1[ks] = pack8(x0, x1);
        }
    }

    u16* myl = lds[wave];
#pragma unroll
    for (int ct2 = 0; ct2 < 8; ct2++) {
        int ct0 = ct2 * 2;
        f32x4 a00 = {0.f, 0.f, 0.f, 0.f}, a01 = {0.f, 0.f, 0.f, 0.f};
        f32x4 a10 = {0.f, 0.f, 0.f, 0.f}, a11 = {0.f, 0.f, 0.f, 0.f};
        const u16* bp0 = Bp + ((size_t)(ct0 * KS) * 64 + lane) * 8;
        const u16* bp1 = bp0 + (size_t)KS * 512;
#pragma unroll
        for (int ks = 0; ks < KS; ks++) {   // 4 independent chains per B pair
            bf16x8 b0 = *(const bf16x8*)(bp0 + (size_t)ks * 512);
            bf16x8 b1 = *(const bf16x8*)(bp1 + (size_t)ks * 512);
            a00 = __builtin_amdgcn_mfma_f32_16x16x32_bf16(af0[ks], b0, a00, 0, 0, 0);
            a01 = __builtin_amdgcn_mfma_f32_16x16x32_bf16(af0[ks], b1, a01, 0, 0, 0);
            a10 = __builtin_amdgcn_mfma_f32_16x16x32_bf16(af1[ks], b0, a10, 0, 0, 0);
            a11 = __builtin_amdgcn_mfma_f32_16x16x32_bf16(af1[ks], b1, a11, 0, 0, 0);
        }
        // C/D layout: col = lane&15, row = (lane>>4)*4 + r   [verified m89]
#pragma unroll
        for (int r = 0; r < 4; r++) {
            myl[(q * 4 + r) * 256 + ct0 * 16 + m] = f2bf(a00[r]);
            myl[(q * 4 + r) * 256 + ct0 * 16 + 16 + m] = f2bf(a01[r]);
            myl[(16 + q * 4 + r) * 256 + ct0 * 16 + m] = f2bf(a10[r]);
            myl[(16 + q * 4 + r) * 256 + ct0 * 16 + 16 + m] = f2bf(a11[r]);
        }
    }
    // epilogue: coalesced store + al dot (same-wave LDS, no barrier needed)
    int c8 = (lane & 31) * 8;
    float4 s0 = *(const float4*)(as_ + c8);
    float4 s1 = *(const float4*)(as_ + c8 + 4);
    float4 d0 = *(const float4*)(ad_ + c8);
    float4 d1 = *(const float4*)(ad_ + c8 + 4);
#pragma unroll
    for (int p = 0; p < 16; p++) {
        int row = p * 2 + (lane >> 5);
        if (row0 + row >= Nrows) continue;
        int4 v = *(const int4*)&myl[row * 256 + c8];
        *(int4*)&O[(size_t)(row0 + row) * 256 + c8] = v;
        float f0 = bf2f((u16)(v.x & 0xffff)), f1 = bf2f((u16)((unsigned)v.x >> 16));
        float f2 = bf2f((u16)(v.y & 0xffff)), f3 = bf2f((u16)((unsigned)v.y >> 16));
        float f4 = bf2f((u16)(v.z & 0xffff)), f5 = bf2f((u16)((unsigned)v.z >> 16));
        float f6 = bf2f((u16)(v.w & 0xffff)), f7 = bf2f((u16)((unsigned)v.w >> 16));
        float ps = f0 * s0.x + f1 * s0.y + f2 * s0.z + f3 * s0.w +
                   f4 * s1.x + f5 * s1.y + f6 * s1.z + f7 * s1.w;
        float pd = f0 * d0.x + f1 * d0.y + f2 * d0.z + f3 * d0.w +
                   f4 * d1.x + f5 * d1.y + f6 * d1.z + f7 * d1.w;
        const int W = (H == 4) ? 8 : 32;
#pragma unroll
        for (int o = 1; o < W; o <<= 1) {
            ps += __shfl_xor(ps, o);
            pd += __shfl_xor(pd, o);
        }
        if (H == 4) {
            if ((lane & 7) == 0) {
                int head = (lane & 31) >> 3;
                als[(row0 + row) * 4 + head] = ps;
                ald[(row0 + row) * 4 + head] = pd;
            }
        } else {
            if ((lane & 31) == 0) {
                als[row0 + row] = ps;
                ald[row0 + row] = pd;
            }
        }
    }
}

// ---------------- fused GAT softmax + accumulate (HALF-wave per dst) ----------
// 2 nodes per wave: 32 lanes per node, each lane covers 8 cols via one int4
// (16B) load -> one 512B row-gather per instruction, 8 rows in flight per
// wave at 4-wide unroll. Wave count halves vs 64-lane/node; per-CU in-flight
// gather bytes ~doubles. Softmax reductions are width-32 (masks<=16).
template <int H>
__global__ __launch_bounds__(256) void gat_fused_kernel(const int* __restrict__ offs,
                                                        const int* __restrict__ csr,
                                                        const float* __restrict__ als,
                                                        const float* __restrict__ ald,
                                                        const u16* __restrict__ h,
                                                        u16* __restrict__ out, int N) {
    __shared__ float lalpha[8][32 * H];
    __shared__ int lsrc[8][32];
    int hw = threadIdx.x >> 5;          // half-wave in block (0..7)
    int lane = threadIdx.x & 31;        // lane within half-wave
    int w = (blockIdx.x * 256 + threadIdx.x) >> 5;
    if (w >= N) return;
    int s0 = offs[w], s1 = offs[w + 1];
    float adl[H], e0[H], m[H], den[H];
#pragma unroll
    for (int hh = 0; hh < H; hh++) { adl[hh] = ald[w * H + hh]; m[hh] = -1e30f; }
    int i0 = s0 + lane;
    bool have = (i0 < s1);
    int src0 = 0;
    if (have) {
        src0 = csr[i0];
        if (H == 4) {
            float4 av = ((const float4*)als)[src0];
            float tmp[4] = {av.x, av.y, av.z, av.w};
#pragma unroll
            for (int hh = 0; hh < 4; hh++) {
                float e = tmp[hh] + adl[hh];
                e = e > 0.f ? e : 0.2f * e;
                e0[hh] = e; m[hh] = e;
            }
        } else {
            float e = als[src0] + adl[0];
            e = e > 0.f ? e : 0.2f * e;
            e0[0] = e; m[0] = e;
        }
    }
    for (int i = i0 + 32; i < s1; i += 32) {  // rare: deg > 32
        int s = csr[i];
#pragma unroll
        for (int hh = 0; hh < H; hh++) {
            float e = als[s * H + hh] + adl[hh];
            e = e > 0.f ? e : 0.2f * e;
            m[hh] = fmaxf(m[hh], e);
        }
    }
#pragma unroll
    for (int hh = 0; hh < H; hh++)
        for (int o = 16; o; o >>= 1) m[hh] = fmaxf(m[hh], __shfl_xor(m[hh], o));
#pragma unroll
    for (int hh = 0; hh < H; hh++) den[hh] = have ? __expf(e0[hh] - m[hh]) : 0.f;
    for (int i = i0 + 32; i < s1; i += 32) {
        int s = csr[i];
#pragma unroll
        for (int hh = 0; hh < H; hh++) {
            float e = als[s * H + hh] + adl[hh];
            e = e > 0.f ? e : 0.2f * e;
            den[hh] += __expf(e - m[hh]);
        }
    }
#pragma unroll
    for (int hh = 0; hh < H; hh++)
        for (int o = 16; o; o >>= 1) den[hh] += __shfl_xor(den[hh], o);
    float rden[H];
#pragma unroll
    for (int hh = 0; hh < H; hh++) rden[hh] = 1.f / (den[hh] + 1e-16f);
    // park chunk-0 alpha/src in per-half-wave LDS (same-wave DS order)
    if (have) {
        lsrc[hw][lane] = src0;
#pragma unroll
        for (int hh = 0; hh < H; hh++)
            lalpha[hw][lane * H + hh] = __expf(e0[hh] - m[hh]) * rden[hh];
    }
    int deg = s1 - s0;
    int cend = min(deg, 32);
    int myh = (H == 4) ? (lane >> 3) : 0;   // head = (lane*8)/64
    const int4* h16 = (const int4*)h;       // 32 int4 per 256-col row
    const float* la = lalpha[hw];
    const int* ls = lsrc[hw];
    float acc[8];
#pragma unroll
    for (int k2 = 0; k2 < 8; k2++) acc[k2] = 0.f;
    int i = 0;
    for (; i + 4 <= cend; i += 4) {
        int sa = ls[i], sb = ls[i + 1], sc = ls[i + 2], sd = ls[i + 3];
        float aa = la[i * H + myh];
        float ab = la[(i + 1) * H + myh];
        float ac = la[(i + 2) * H + myh];
        float ad = la[(i + 3) * H + myh];
        int4 ha = h16[(size_t)sa * 32 + lane];
        int4 hb = h16[(size_t)sb * 32 + lane];
        int4 hc = h16[(size_t)sc * 32 + lane];
        int4 hd = h16[(size_t)sd * 32 + lane];
        fma8(acc, aa, ha);
        fma8(acc, ab, hb);
        fma8(acc, ac, hc);
        fma8(acc, ad, hd);
    }
    for (; i < cend; i++) {
        int s = ls[i];
        float a = la[i * H + myh];
        fma8(acc, a, h16[(size_t)s * 32 + lane]);
    }
    for (int j = s0 + 32; j < s1; j++) {  // rare deg>32 tail: recompute alpha
        int s = csr[j];
        float e = als[s * H + myh] + adl[myh];
        e = e > 0.f ? e : 0.2f * e;
        float a = __expf(e - m[myh]) * rden[myh];
        fma8(acc, a, h16[(size_t)s * 32 + lane]);
    }
    int4 o;
    o.x = (int)((unsigned)f2bf(acc[0]) | ((unsigned)f2bf(acc[1]) << 16));
    o.y = (int)((unsigned)f2bf(acc[2]) | ((unsigned)f2bf(acc[3]) << 16));
    o.z = (int)((unsigned)f2bf(acc[4]) | ((unsigned)f2bf(acc[5]) << 16));
    o.w = (int)((unsigned)f2bf(acc[6]) | ((unsigned)f2bf(acc[7]) << 16));
    ((int4*)out)[(size_t)w * 32 + lane] = o;
}

// ---------------- BatchNorm stats (bf16 input; register acc) ------------------
__global__ __launch_bounds__(256) void bn_stats(const u16* __restrict__ agg, int N,
                                                float* __restrict__ sum, float* __restrict__ sq) {
    int t = threadIdx.x;
    int rows = (N + gridDim.x - 1) / gridDim.x;
    int r0 = blockIdx.x * rows, r1 = min(r0 + rows, N);
    if (r0 >= r1) return;
    float s = 0.f, q = 0.f;
    for (int r = r0; r < r1; r++) {
        float v = bf2f(agg[(size_t)r * 256 + t]);
        s += v;
        q = fmaf(v, v, q);
    }
    atomicAdd(&sum[t], s);
    atomicAdd(&sq[t], q);
}

// layer 2: bn-apply + relu + fused global-mean-pool (batch sorted)
__global__ __launch_bounds__(256) void bn_apply_pool(const u16* __restrict__ agg,
                                                     const float* __restrict__ sum,
                                                     const float* __restrict__ sq,
                                                     const float* __restrict__ g,
                                                     const float* __restrict__ be,
                                                     const int* __restrict__ batch,
                                                     u16* __restrict__ out,
                                                     float* __restrict__ pools,
                                                     int* __restrict__ cnt, int N) {
    int t = threadIdx.x;
    float inv = 1.f / (float)N;
    float mm = sum[t] * inv;
    float vv = fmaxf(sq[t] * inv - mm * mm, 0.f);
    float sc = rsqrtf(vv + 1e-5f) * g[t];
    float sh = be[t] - mm * sc;
    int rows = (N + gridDim.x - 1) / gridDim.x;
    int r0 = blockIdx.x * rows, r1 = min(r0 + rows, N);
    if (r0 >= r1) return;
    float acc = 0.f;
    int cur = batch[r0], c0 = 0;
    for (int r = r0; r < r1; r++) {
        int b = batch[r];  // wave-uniform scalar load
        if (b != cur) {
            atomicAdd(&pools[cur * 256 + t], acc);
            if (t == 0) atomicAdd(&cnt[cur], c0);
            acc = 0.f; c0 = 0; cur = b;
        }
        float v = bf2f(agg[(size_t)r * 256 + t]);
        float y = fmaxf(fmaf(v, sc, sh), 0.f);
        out[(size_t)r * 256 + t] = f2bf(y);
        acc += y; c0++;
    }
    atomicAdd(&pools[cur * 256 + t], acc);
    if (t == 0) atomicAdd(&cnt[cur], c0);
}

// shared = relu(gf @ W_sh + b_sh) fused with heads; one block per graph
__global__ __launch_bounds__(256) void shared_head_kernel(const float* __restrict__ pools,
                                                          const int* __restrict__ cnt,
                                                          const float* __restrict__ Wsh,
                                                          const float* __restrict__ bsh,
                                                          const float* __restrict__ Wnode,
                                                          const float* __restrict__ Wcrit,
                                                          const float* __restrict__ bcrit,
                                                          const float* __restrict__ Wtype,
                                                          const float* __restrict__ btype,
                                                          const u16* __restrict__ xn,
                                                          const int* __restrict__ tgt,
                                                          float* __restrict__ gdot,
                                                          float* __restrict__ out_tail) {
    __shared__ float gf[256], red[256];
    int b = blockIdx.x, t = threadIdx.x;
    gf[t] = pools[b * 256 + t] / fmaxf((float)cnt[b], 1.f);
    __syncthreads();
    float acc = bsh[t];
    for (int k = 0; k < 256; k++) acc = fmaf(gf[k], Wsh[k * 256 + t], acc);
    float s = fmaxf(acc, 0.f);
    int tn = tgt[b];
    float xnt = bf2f(xn[(size_t)tn * 256 + t]);
    float pg = s * Wnode[256 + t];
    float pv = s * Wcrit[t];
    float pt0 = s * Wtype[t * 4 + 0] + xnt * Wtype[(256 + t) * 4 + 0];
    float pt1 = s * Wtype[t * 4 + 1] + xnt * Wtype[(256 + t) * 4 + 1];
    float pt2 = s * Wtype[t * 4 + 2] + xnt * Wtype[(256 + t) * 4 + 2];
    float pt3 = s * Wtype[t * 4 + 3] + xnt * Wtype[(256 + t) * 4 + 3];
    auto bred = [&](float v) -> float {
        __syncthreads();
        red[t] = v;
        __syncthreads();
        for (int o = 128; o; o >>= 1) {
            if (t < o) red[t] += red[t + o];
            __syncthreads();
        }
        return red[0];
    };
    float rg = bred(pg);
    float rv = bred(pv);
    float r0 = bred(pt0);
    float r1 = bred(pt1);
    float r2 = bred(pt2);
    float r3 = bred(pt3);
    if (t == 0) {
        gdot[b] = rg;
        out_tail[32 + b] = rv + bcrit[0];
        out_tail[b * 4 + 0] = r0 + btype[0];
        out_tail[b * 4 + 1] = r1 + btype[1];
        out_tail[b * 4 + 2] = r2 + btype[2];
        out_tail[b * 4 + 3] = r3 + btype[3];
    }
}

// node_scores: one wave per node (bf16 x_nodes)
__global__ __launch_bounds__(256) void node_scores_kernel(const u16* __restrict__ xn,
                                                          const float* __restrict__ Wnode, const float* __restrict__ bnode,
                                                          const int* __restrict__ batch, const float* __restrict__ gdot,
                                                          float* __restrict__ out, int N) {
    int w = (blockIdx.x * 256 + threadIdx.x) >> 6;
    int lane = threadIdx.x & 63;
    if (w >= N) return;
    ushort4 xv = ((const ushort4*)(xn + (size_t)w * 256))[lane];
    float4 wv = ((const float4*)Wnode)[lane];
    float p = bf2f(xv.x) * wv.x + bf2f(xv.y) * wv.y + bf2f(xv.z) * wv.z + bf2f(xv.w) * wv.w;
    for (int o = 32; o; o >>= 1) p += __shfl_xor(p, o);
    if (lane == 0) out[w] = p + gdot[batch[w]] + bnode[0];
}

extern "C" void kernel_launch(void* const* d_in, const int* in_sizes, int n_in,
                              void* d_out, int out_size, void* d_ws, size_t ws_size,
                              hipStream_t stream) {
    const float* x = (const float*)d_in[0];
    const int* ei = (const int*)d_in[1];
    const int* batch = (const int*)d_in[2];
    const int* tgt = (const int*)d_in[3];
    const float* W1 = (const float*)d_in[4];
    const float* a1s = (const float*)d_in[5];
    const float* a1d = (const float*)d_in[6];
    // b1 (d_in[7]) / b2 (d_in[11]): constant column shifts cancel exactly in BatchNorm
    const float* W2 = (const float*)d_in[8];
    const float* a2s = (const float*)d_in[9];
    const float* a2d = (const float*)d_in[10];
    const float* g1 = (const float*)d_in[12];
    const float* be1 = (const float*)d_in[13];
    const float* g2 = (const float*)d_in[14];
    const float* be2 = (const float*)d_in[15];
    const float* Wsh = (const float*)d_in[16];
    const float* bsh = (const float*)d_in[17];
    const float* Wnode = (const float*)d_in[18];
    const float* bnode = (const float*)d_in[19];
    const float* Wtype = (const float*)d_in[20];
    const float* btype = (const float*)d_in[21];
    const float* Wcrit = (const float*)d_in[22];
    const float* bcrit = (const float*)d_in[23];

    const int N = in_sizes[2];
    const int E = in_sizes[1] / 2;
    const int Et = E + N;
    const int nb = (N + 255) / 256;   // scan blocks

    // ---- workspace carve (~85 MB) ----
    char* w = (char*)d_ws;
    size_t off = 0;
    auto carve = [&](size_t bytes) -> char* {
        char* p = w + off;
        off = (off + bytes + 255) & ~(size_t)255;
        return p;
    };
    u16* agg_bf = (u16*)carve((size_t)N * 256 * 2);    // bf16 aggregation (both layers)
    u16* h_bf = (u16*)carve((size_t)N * 256 * 2);      // h1 -> h2 (gemm outputs)
    u16* y_bf = (u16*)carve((size_t)N * 256 * 2);      // x_nodes (bn2 out)
    u16* W1p = (u16*)carve(16 * 2 * 512 * 2);          // packed W1 frags
    u16* W2p = (u16*)carve(16 * 8 * 512 * 2);          // packed W2 frags
    float* al1s = (float*)carve((size_t)N * 4 * 4);
    float* al1d = (float*)carve((size_t)N * 4 * 4);
    float* al2s = (float*)carve((size_t)N * 4);
    float* al2d = (float*)carve((size_t)N * 4);
    int* offs = (int*)carve((size_t)(N + 1) * 4);
    int* cursor = (int*)carve((size_t)N * 4);
    int* csr = (int*)carve((size_t)Et * 4);
    int* excl = (int*)carve((size_t)N * 4);
    int* bsum = (int*)carve((size_t)nb * 4);
    int* bbase = (int*)carve((size_t)nb * 4);
    int* stotal = (int*)carve(64);
    float* gdot = (float*)carve(64);
    char* zero0 = w + off;
    int* counts = (int*)carve((size_t)N * 4);
    float* bn1s = (float*)carve(1024);
    float* bn1q = (float*)carve(1024);
    float* bn2s = (float*)carve(1024);
    float* bn2q = (float*)carve(1024);
    float* pools = (float*)carve(8 * 256 * 4);
    int* cnt = (int*)carve(64);
    size_t zbytes = (size_t)((w + off) - zero0);
    hipMemsetAsync(zero0, 0, zbytes, stream);

    int wavesPerGrid = (N + 3) / 4;                  // 4 node-waves per 256-thread block
    int halfGrid = (N + 7) / 8;                      // 8 node-half-waves per block
    int mfmaGrid = (((N + 31) / 32) + 3) / 4;        // 4 32-row tiles (waves) per block

    // ---- CSR build (3-phase parallel scan) + weight prep ----
    hist_kernel<<<(Et + 255) / 256, 256, 0, stream>>>(ei, E, N, counts);
    scan_p1<<<nb, 256, 0, stream>>>(counts, N, excl, bsum);
    scan_p2<<<1, 256, 0, stream>>>(bsum, nb, bbase, stotal);
    scan_p3<<<nb, 256, 0, stream>>>(excl, bbase, stotal, N, offs, cursor);
    scatter_kernel<<<(Et + 255) / 256, 256, 0, stream>>>(ei, E, N, cursor, csr);
    packW_kernel<<<(16 * 2 * 512 + 255) / 256, 256, 0, stream>>>(W1, 2, W1p);
    packW_kernel<<<(16 * 8 * 512 + 255) / 256, 256, 0, stream>>>(W2, 8, W2p);

    // ---- layer 1: GAT(4 heads); x converted to bf16 in gemm A-load ----
    gemm_mfma<64, 4, 0><<<mfmaGrid, 256, 0, stream>>>(x, W1p, h_bf, a1s, a1d, al1s, al1d,
                                                      bn1s, bn1q, g1, be1, N);
    gat_fused_kernel<4><<<halfGrid, 256, 0, stream>>>(offs, csr, al1s, al1d, h_bf, agg_bf, N);
    bn_stats<<<1024, 256, 0, stream>>>(agg_bf, N, bn1s, bn1q);

    // ---- layer 2: bn1-apply fused into gemm A-load; GAT(1) + BN2 + pool ----
    gemm_mfma<256, 1, 1><<<mfmaGrid, 256, 0, stream>>>(agg_bf, W2p, h_bf, a2s, a2d, al2s, al2d,
                                                       bn1s, bn1q, g1, be1, N);
    gat_fused_kernel<1><<<halfGrid, 256, 0, stream>>>(offs, csr, al2s, al2d, h_bf, agg_bf, N);
    bn_stats<<<1024, 256, 0, stream>>>(agg_bf, N, bn2s, bn2q);
    bn_apply_pool<<<1024, 256, 0, stream>>>(agg_bf, bn2s, bn2q, g2, be2, batch, y_bf, pools, cnt, N);

    // ---- heads ----
    shared_head_kernel<<<8, 256, 0, stream>>>(pools, cnt, Wsh, bsh, Wnode, Wcrit, bcrit,
                                              Wtype, btype, y_bf, tgt, gdot, (float*)d_out + N);
    node_scores_kernel<<<wavesPerGrid, 256, 0, stream>>>(y_bf, Wnode, bnode, batch, gdot,
                                                         (float*)d_out, N);
}